// Round 9
// baseline (303.932 us; speedup 1.0000x reference)
//
#include <hip/hip_runtime.h>

#define NB    16
#define CIN   64
#define TT    512
#define VV    22
#define COUT  256
#define TBK   4            // t per z tile
#define NTB   (TT / TBK)   // 128
#define ZROW  (TBK * VV)   // 88
#define ZS    92           // k2 Zs row stride
#define XPAD  28           // k1 xs/Ss/Ps row stride (float4-able)
#define AT    68           // A1t/A2t row stride [u][r]
#define PAD   24           // fallback kernel pads
#define OPAD  23

// ===================== Kernel 1: attention + aggregate =====================
__global__ __launch_bounds__(256, 3) void agcn_attn(
    const float* __restrict__ x, const float* __restrict__ A,
    const float* __restrict__ Wa, const float* __restrict__ ba,
    const float* __restrict__ Wb, const float* __restrict__ bb,
    float* __restrict__ z)
{
    const int bx = blockIdx.x;
    const int t  = (bx & 7) * 64 + (bx >> 3);   // XCD swizzle
    const int n  = blockIdx.y;
    const int tid = threadIdx.x;

    __shared__ __align__(16) float xs[CIN * XPAD];   // [c][v]
    __shared__ __align__(16) float A1t[VV * AT];     // [u][r]
    __shared__ __align__(16) float A2t[VV * AT];     // [v][r]
    __shared__ __align__(16) float Ss[VV * XPAD];    // [u][v]
    __shared__ __align__(16) float Ps[VV * XPAD];    // [u][v]

    // ---- P0: stage x tile and A tile; zero xs pads (P1 reads cols 16..23) ----
    for (int f = tid; f < CIN * VV; f += 256) {
        int c = f / VV, v = f - c * VV;
        xs[c * XPAD + v] = x[(((size_t)n * CIN + c) * TT + t) * VV + v];
    }
    for (int f = tid; f < CIN * (XPAD - VV); f += 256) {
        int c = f / (XPAD - VV), j = f - c * (XPAD - VV);
        xs[c * XPAD + VV + j] = 0.f;
    }
    {
        const float* Ag = A + (((size_t)n * TT + t) * VV) * VV;
        for (int f = tid; f < VV * VV; f += 256) {
            int u = f / VV, v = f - u * VV;
            Ps[u * XPAD + v] = Ag[f] + 1e-6f;
        }
    }
    __syncthreads();

    // ---- P1: A1t/A2t[u][r]. 48 threads; thread = (rg 0..15, ug 0..2):
    // 4 Wa rows + 4 Wb rows (r0..r0+3) x 8 u's (us..us+7). One X b128 feeds 32 FMA.
    if (tid < 48) {
        const int rg = tid / 3;            // 0..15
        const int ug = tid - rg * 3;       // 0..2
        const int us = ug * 8;             // 0, 8, 16
        const int r0 = rg * 4;
        const float* WaP = Wa + (size_t)r0 * CIN;
        const float* WbP = Wb + (size_t)r0 * CIN;
        float acca[4][8], accb[4][8];
        #pragma unroll
        for (int i = 0; i < 4; ++i) {
            const float bai = ba[r0 + i], bbi = bb[r0 + i];
            #pragma unroll
            for (int j = 0; j < 8; ++j) { acca[i][j] = bai; accb[i][j] = bbi; }
        }
        for (int cg = 0; cg < 16; ++cg) {
            float4 wa[4], wb[4];
            #pragma unroll
            for (int i = 0; i < 4; ++i) {
                wa[i] = *reinterpret_cast<const float4*>(WaP + (size_t)i * CIN + cg * 4);
                wb[i] = *reinterpret_cast<const float4*>(WbP + (size_t)i * CIN + cg * 4);
            }
            #pragma unroll
            for (int c = 0; c < 4; ++c) {
                const float4 xlo = *reinterpret_cast<const float4*>(&xs[(cg * 4 + c) * XPAD + us]);
                const float4 xhi = *reinterpret_cast<const float4*>(&xs[(cg * 4 + c) * XPAD + us + 4]);
                const float xj[8] = {xlo.x, xlo.y, xlo.z, xlo.w, xhi.x, xhi.y, xhi.z, xhi.w};
                #pragma unroll
                for (int i = 0; i < 4; ++i) {
                    const float wac = (c == 0) ? wa[i].x : (c == 1) ? wa[i].y : (c == 2) ? wa[i].z : wa[i].w;
                    const float wbc = (c == 0) ? wb[i].x : (c == 1) ? wb[i].y : (c == 2) ? wb[i].z : wb[i].w;
                    #pragma unroll
                    for (int j = 0; j < 8; ++j) {
                        acca[i][j] += wac * xj[j];
                        accb[i][j] += wbc * xj[j];
                    }
                }
            }
        }
        #pragma unroll
        for (int j = 0; j < 8; ++j) {
            if (us + j < VV) {   // discard overcomputed u >= 22 (fed by zeroed pads)
                float4 va = {acca[0][j], acca[1][j], acca[2][j], acca[3][j]};
                float4 vb = {accb[0][j], accb[1][j], accb[2][j], accb[3][j]};
                *reinterpret_cast<float4*>(&A1t[(us + j) * AT + r0]) = va;
                *reinterpret_cast<float4*>(&A2t[(us + j) * AT + r0]) = vb;
            }
        }
    }
    __syncthreads();

    // ---- P2: 2x2 register tiles. S[u][v] = (1/64) sum_i A1t[u][i]*A2t[v][i] ----
    if (tid < 121) {
        const int tu = tid / 11, tv = tid - tu * 11;
        const int u0 = tu * 2, v0 = tv * 2;
        const float4* a0 = reinterpret_cast<const float4*>(&A1t[u0 * AT]);
        const float4* a1 = reinterpret_cast<const float4*>(&A1t[(u0 + 1) * AT]);
        const float4* b0 = reinterpret_cast<const float4*>(&A2t[v0 * AT]);
        const float4* b1 = reinterpret_cast<const float4*>(&A2t[(v0 + 1) * AT]);
        float4 s00 = {0,0,0,0}, s01 = {0,0,0,0}, s10 = {0,0,0,0}, s11 = {0,0,0,0};
        #pragma unroll
        for (int ig = 0; ig < 16; ++ig) {
            float4 A0 = a0[ig], A1v = a1[ig], B0 = b0[ig], B1 = b1[ig];
            s00.x += A0.x*B0.x; s00.y += A0.y*B0.y; s00.z += A0.z*B0.z; s00.w += A0.w*B0.w;
            s01.x += A0.x*B1.x; s01.y += A0.y*B1.y; s01.z += A0.z*B1.z; s01.w += A0.w*B1.w;
            s10.x += A1v.x*B0.x; s10.y += A1v.y*B0.y; s10.z += A1v.z*B0.z; s10.w += A1v.w*B0.w;
            s11.x += A1v.x*B1.x; s11.y += A1v.y*B1.y; s11.z += A1v.z*B1.z; s11.w += A1v.w*B1.w;
        }
        const float k = 1.0f / 64.0f;
        Ss[u0 * XPAD + v0]           = ((s00.x+s00.y)+(s00.z+s00.w)) * k;
        Ss[u0 * XPAD + v0 + 1]       = ((s01.x+s01.y)+(s01.z+s01.w)) * k;
        Ss[(u0+1) * XPAD + v0]       = ((s10.x+s10.y)+(s10.z+s10.w)) * k;
        Ss[(u0+1) * XPAD + v0 + 1]   = ((s11.x+s11.y)+(s11.z+s11.w)) * k;
    }
    __syncthreads();

    // ---- P3: shuffle softmax over u, per column v. 22 columns x 8 lanes ----
    if (tid < VV * 8) {
        const int v = tid >> 3, p = tid & 7;
        const int u1 = p + 8, u2 = p + 16;
        float s0 = Ss[p * XPAD + v];
        float s1 = Ss[u1 * XPAD + v];
        float s2 = (u2 < VV) ? Ss[u2 * XPAD + v] : -1e30f;
        float m = fmaxf(s0, fmaxf(s1, s2));
        m = fmaxf(m, __shfl_xor(m, 1, 8));
        m = fmaxf(m, __shfl_xor(m, 2, 8));
        m = fmaxf(m, __shfl_xor(m, 4, 8));
        float e0 = __expf(s0 - m), e1 = __expf(s1 - m);
        float e2 = (u2 < VV) ? __expf(s2 - m) : 0.f;
        float sum = e0 + e1 + e2;
        sum += __shfl_xor(sum, 1, 8);
        sum += __shfl_xor(sum, 2, 8);
        sum += __shfl_xor(sum, 4, 8);
        const float inv = 1.0f / sum;
        Ps[p * XPAD + v]  += e0 * inv;
        Ps[u1 * XPAD + v] += e1 * inv;
        if (u2 < VV) Ps[u2 * XPAD + v] += e2 * inv;
    }
    __syncthreads();

    // ---- P4: 2x2 tiles (c-pair x u-pair). z[c][u] = sum_w Ps[u][w]*xs[c][w] ----
    {
        const int tb  = t >> 2;
        const int ttl = t & 3;
        float* zdst = z + (((size_t)n * NTB + tb) * CIN) * ZROW + ttl * VV;
        #pragma unroll
        for (int pass = 0; pass < 2; ++pass) {
            const int tt = pass * 256 + tid;
            if (tt < 352) {
                const int cp = tt / 11, up = tt - cp * 11;
                const int c0 = cp * 2, u0 = up * 2;
                const float4* x0 = reinterpret_cast<const float4*>(&xs[c0 * XPAD]);
                const float4* x1 = reinterpret_cast<const float4*>(&xs[(c0 + 1) * XPAD]);
                const float4* p0 = reinterpret_cast<const float4*>(&Ps[u0 * XPAD]);
                const float4* p1 = reinterpret_cast<const float4*>(&Ps[(u0 + 1) * XPAD]);
                float a00 = 0.f, a01 = 0.f, a10 = 0.f, a11 = 0.f;
                #pragma unroll
                for (int wg = 0; wg < 5; ++wg) {
                    float4 X0 = x0[wg], X1 = x1[wg], P0 = p0[wg], P1 = p1[wg];
                    a00 += P0.x*X0.x + P0.y*X0.y + P0.z*X0.z + P0.w*X0.w;
                    a01 += P1.x*X0.x + P1.y*X0.y + P1.z*X0.z + P1.w*X0.w;
                    a10 += P0.x*X1.x + P0.y*X1.y + P0.z*X1.z + P0.w*X1.w;
                    a11 += P1.x*X1.x + P1.y*X1.y + P1.z*X1.z + P1.w*X1.w;
                }
                {
                    float xa = xs[c0*XPAD+20], xb = xs[c0*XPAD+21];
                    float xc = xs[(c0+1)*XPAD+20], xd = xs[(c0+1)*XPAD+21];
                    float pa = Ps[u0*XPAD+20], pb = Ps[u0*XPAD+21];
                    float pc = Ps[(u0+1)*XPAD+20], pd = Ps[(u0+1)*XPAD+21];
                    a00 += pa*xa + pb*xb;  a01 += pc*xa + pd*xb;
                    a10 += pa*xc + pb*xd;  a11 += pc*xc + pd*xd;
                }
                float2 r0 = {a00, a01}, r1 = {a10, a11};
                *reinterpret_cast<float2*>(&zdst[(size_t)c0 * ZROW + u0]) = r0;
                *reinterpret_cast<float2*>(&zdst[(size_t)(c0 + 1) * ZROW + u0]) = r1;
            }
        }
    }
}

// ===================== Kernel 2 helpers =====================
__device__ __forceinline__ void k2_gemm(const float* Zbuf, const float* __restrict__ Wd,
                                        int o0, int col0, int kg0, int kg1,
                                        float (&acc)[8][6])
{
    for (int kg = kg0; kg < kg1; ++kg) {
        const int k = kg * 4;
        float4 w[8];
        #pragma unroll
        for (int j = 0; j < 8; ++j)
            w[j] = *reinterpret_cast<const float4*>(&Wd[(size_t)(o0 + j) * CIN + k]);
        #pragma unroll
        for (int kk = 0; kk < 4; ++kk) {
            const float* zr = &Zbuf[(k + kk) * ZS + col0];
            float2 za = *reinterpret_cast<const float2*>(zr);
            float2 zb = *reinterpret_cast<const float2*>(zr + 2);
            float2 zc = *reinterpret_cast<const float2*>(zr + 4);
            const float zv[6] = {za.x, za.y, zb.x, zb.y, zc.x, zc.y};
            #pragma unroll
            for (int j = 0; j < 8; ++j) {
                const float wj = (kk == 0) ? w[j].x : (kk == 1) ? w[j].y : (kk == 2) ? w[j].z : w[j].w;
                #pragma unroll
                for (int m = 0; m < 6; ++m)
                    acc[j][m] += wj * zv[m];
            }
        }
    }
}

__device__ __forceinline__ void k2_store(float* __restrict__ out, int n, int o0, int tb,
                                         int col0, float (&acc)[8][6])
{
    #pragma unroll
    for (int j = 0; j < 8; ++j) {
        float* op = out + ((size_t)(n * COUT + o0 + j)) * (TT * VV) + (size_t)tb * ZROW + col0;
        #pragma unroll
        for (int m = 0; m < 6; m += 2) {
            if (col0 + m < ZROW) {
                float2 sv = {fmaxf(acc[j][m], 0.f), fmaxf(acc[j][m + 1], 0.f)};
                *reinterpret_cast<float2*>(op + m) = sv;
            }
        }
    }
}

// ===================== Kernel 2: out = relu(Wd @ z + bd), 2 tb-tiles/block, dbuf staging =====================
__global__ __launch_bounds__(256, 3) void agcn_out(
    const float* __restrict__ z, const float* __restrict__ Wd,
    const float* __restrict__ bd, float* __restrict__ out)
{
    const int bxx = blockIdx.x;                  // 0..63
    const int tb0 = (bxx & 7) * 8 + (bxx >> 3);  // XCD swizzle aligned with k1
    const int tb  = tb0 * 2;
    const int ob  = blockIdx.y;                  // 0..1
    const int n   = blockIdx.z;
    const int tid = threadIdx.x;
    const int tx = tid & 15, ty = tid >> 4;
    const int o0 = ob * 128 + ty * 8;
    const int col0 = tx * 6;

    __shared__ __align__(16) float Zs[2][CIN * ZS + 8];

    const float* zsrc0 = z + (((size_t)n * NTB + tb) * CIN) * ZROW;
    const float* zsrc1 = zsrc0 + (size_t)CIN * ZROW;

    // stage tile 0
    #pragma unroll
    for (int it = 0; it < 6; ++it) {
        const int i4 = it * 256 + tid;
        if (i4 < (CIN * ZROW) / 4) {
            float4 val = *reinterpret_cast<const float4*>(zsrc0 + (size_t)i4 * 4);
            int c = i4 / (ZROW / 4), r4 = (i4 % (ZROW / 4)) * 4;
            *reinterpret_cast<float4*>(&Zs[0][c * ZS + r4]) = val;
        }
    }
    __syncthreads();

    // prefetch tile 1 into registers (loads in flight during first half of tile-0 compute)
    float4 pre[6];
    #pragma unroll
    for (int it = 0; it < 6; ++it) {
        const int i4 = it * 256 + tid;
        if (i4 < (CIN * ZROW) / 4)
            pre[it] = *reinterpret_cast<const float4*>(zsrc1 + (size_t)i4 * 4);
    }

    float acc[8][6];
    #pragma unroll
    for (int j = 0; j < 8; ++j) {
        const float b = bd[o0 + j];
        #pragma unroll
        for (int m = 0; m < 6; ++m) acc[j][m] = b;
    }

    k2_gemm(Zs[0], Wd, o0, col0, 0, 8, acc);

    // write prefetched tile 1 to LDS (no barrier needed: nobody reads Zs[1] yet)
    #pragma unroll
    for (int it = 0; it < 6; ++it) {
        const int i4 = it * 256 + tid;
        if (i4 < (CIN * ZROW) / 4) {
            int c = i4 / (ZROW / 4), r4 = (i4 % (ZROW / 4)) * 4;
            *reinterpret_cast<float4*>(&Zs[1][c * ZS + r4]) = pre[it];
        }
    }

    k2_gemm(Zs[0], Wd, o0, col0, 8, 16, acc);
    k2_store(out, n, o0, tb, col0, acc);
    __syncthreads();   // Zs[1] fully written; Zs[0] no longer needed

    #pragma unroll
    for (int j = 0; j < 8; ++j) {
        const float b = bd[o0 + j];
        #pragma unroll
        for (int m = 0; m < 6; ++m) acc[j][m] = b;
    }
    k2_gemm(Zs[1], Wd, o0, col0, 0, 16, acc);
    k2_store(out, n, o0, tb + 1, col0, acc);
}

// ===================== Fallback: verified R1 monolithic kernel =====================
__global__ __launch_bounds__(256, 4) void agcn_fused(
    const float* __restrict__ x, const float* __restrict__ A,
    const float* __restrict__ Wa, const float* __restrict__ ba,
    const float* __restrict__ Wb, const float* __restrict__ bb,
    const float* __restrict__ Wd, const float* __restrict__ bd,
    float* __restrict__ out)
{
    const int t   = blockIdx.x;
    const int n   = blockIdx.y;
    const int tid = threadIdx.x;
    __shared__ float smem[7424];
    float* xs   = smem;
    float* A1s  = smem + 1536;
    float* A2s  = smem + 3072;
    float* Ssf  = smem + 4608;
    float* Psf  = smem + 5136;
    float* outs = smem;
    float* zs   = smem + 5888;

    for (int f = tid; f < CIN * VV; f += 256) {
        int c = f / VV, v = f - c * VV;
        xs[c * PAD + v] = x[(((size_t)n * CIN + c) * TT + t) * VV + v];
    }
    {
        const float* Ag = A + (((size_t)n * TT + t) * VV) * VV;
        for (int f = tid; f < VV * VV; f += 256) {
            int u = f / VV, v = f - u * VV;
            Psf[u * PAD + v] = Ag[f] + 1e-6f;
        }
    }
    __syncthreads();
    {
        const int r  = tid & 63;
        const int q  = tid >> 6;
        const int us = (q * VV) >> 2;
        const int ue = ((q + 1) * VV) >> 2;
        const float* War = Wa + r * CIN;
        const float* Wbr = Wb + r * CIN;
        float acc1[6], acc2[6];
        const float b1 = ba[r], b2 = bb[r];
        #pragma unroll
        for (int u = 0; u < 6; ++u) { acc1[u] = b1; acc2[u] = b2; }
        for (int c = 0; c < CIN; c += 4) {
            float4 wa4 = *reinterpret_cast<const float4*>(War + c);
            float4 wb4 = *reinterpret_cast<const float4*>(Wbr + c);
            #pragma unroll
            for (int u = 0; u < 6; ++u) {
                float x0 = xs[(c + 0) * PAD + us + u];
                float x1 = xs[(c + 1) * PAD + us + u];
                float x2 = xs[(c + 2) * PAD + us + u];
                float x3 = xs[(c + 3) * PAD + us + u];
                acc1[u] += wa4.x * x0 + wa4.y * x1 + wa4.z * x2 + wa4.w * x3;
                acc2[u] += wb4.x * x0 + wb4.y * x1 + wb4.z * x2 + wb4.w * x3;
            }
        }
        #pragma unroll
        for (int u = 0; u < 6; ++u) {
            if (us + u < ue) {
                A1s[r * PAD + us + u] = acc1[u];
                A2s[r * PAD + us + u] = acc2[u];
            }
        }
    }
    __syncthreads();
    for (int f = tid; f < VV * VV; f += 256) {
        int u = f / VV, v = f - u * VV;
        float s = 0.f;
        for (int i = 0; i < CIN; ++i)
            s += A1s[i * PAD + u] * A2s[i * PAD + v];
        Ssf[u * PAD + v] = s * (1.0f / 64.0f);
    }
    __syncthreads();
    if (tid < VV) {
        const int v = tid;
        float m = -1e30f;
        #pragma unroll
        for (int u = 0; u < VV; ++u) m = fmaxf(m, Ssf[u * PAD + v]);
        float sum = 0.f;
        #pragma unroll
        for (int u = 0; u < VV; ++u) sum += __expf(Ssf[u * PAD + v] - m);
        const float inv = 1.0f / sum;
        #pragma unroll
        for (int u = 0; u < VV; ++u)
            Psf[u * PAD + v] += __expf(Ssf[u * PAD + v] - m) * inv;
    }
    __syncthreads();
    for (int f = tid; f < CIN * VV; f += 256) {
        int c = f / VV, u = f - c * VV;
        float s = 0.f;
        #pragma unroll
        for (int w = 0; w < VV; ++w)
            s += Psf[u * PAD + w] * xs[c * PAD + w];
        zs[c * PAD + u] = s;
    }
    __syncthreads();
    {
        const int o = tid;
        const float* Wr = Wd + o * CIN;
        float acc[VV];
        const float b = bd[o];
        #pragma unroll
        for (int u = 0; u < VV; ++u) acc[u] = b;
        for (int c = 0; c < CIN; c += 4) {
            float4 w4 = *reinterpret_cast<const float4*>(Wr + c);
            #pragma unroll
            for (int cc = 0; cc < 4; ++cc) {
                const float w = (cc == 0) ? w4.x : (cc == 1) ? w4.y : (cc == 2) ? w4.z : w4.w;
                const float* zr = zs + (c + cc) * PAD;
                #pragma unroll
                for (int uq = 0; uq < 5; ++uq) {
                    float4 zq = *reinterpret_cast<const float4*>(zr + uq * 4);
                    acc[uq * 4 + 0] += w * zq.x;
                    acc[uq * 4 + 1] += w * zq.y;
                    acc[uq * 4 + 2] += w * zq.z;
                    acc[uq * 4 + 3] += w * zq.w;
                }
                float2 zt = *reinterpret_cast<const float2*>(zr + 20);
                acc[20] += w * zt.x;
                acc[21] += w * zt.y;
            }
        }
        #pragma unroll
        for (int u = 0; u < VV; ++u)
            outs[o * OPAD + u] = fmaxf(acc[u], 0.f);
    }
    __syncthreads();
    {
        const size_t obase = (size_t)n * COUT * TT * VV + (size_t)t * VV;
        for (int f = tid; f < COUT * VV; f += 256) {
            int o = f / VV, u = f - o * VV;
            out[obase + (size_t)o * (TT * VV) + u] = outs[o * OPAD + u];
        }
    }
}

extern "C" void kernel_launch(void* const* d_in, const int* in_sizes, int n_in,
                              void* d_out, int out_size, void* d_ws, size_t ws_size,
                              hipStream_t stream) {
    const float* x  = (const float*)d_in[0];
    const float* A  = (const float*)d_in[1];
    const float* Wa = (const float*)d_in[2];
    const float* ba = (const float*)d_in[3];
    const float* Wb = (const float*)d_in[4];
    const float* bb = (const float*)d_in[5];
    const float* Wd = (const float*)d_in[6];
    const float* bd = (const float*)d_in[7];
    float* outp     = (float*)d_out;

    const size_t z_bytes = (size_t)NB * TT * CIN * VV * sizeof(float);  // 46.1 MB
    if (ws_size >= z_bytes) {
        float* zws = (float*)d_ws;
        dim3 g1(TT, NB);
        agcn_attn<<<g1, 256, 0, stream>>>(x, A, Wa, ba, Wb, bb, zws);
        dim3 g2(NTB / 2, COUT / 128, NB);
        agcn_out<<<g2, 256, 0, stream>>>(zws, Wd, bd, outp);
    } else {
        dim3 grid(TT, NB);
        agcn_fused<<<grid, 256, 0, stream>>>(x, A, Wa, ba, Wb, bb, Wd, bd, outp);
    }
}

// Round 10
// 241.363 us; speedup vs baseline: 1.2592x; 1.2592x over previous
//
#include <hip/hip_runtime.h>

#define NB    16
#define CIN   64
#define TT    512
#define VV    22
#define COUT  256
#define TBK   4            // t per z tile
#define NTB   (TT / TBK)   // 128
#define ZROW  (TBK * VV)   // 88
#define ZS    92           // k2 Zs row stride
#define XPAD  28           // k1 xs/Ss/Ps row stride (float4-able)
#define AT    68           // A1t/A2t row stride [u][r]
#define PAD   24           // fallback kernel pads
#define OPAD  23

// ===================== Kernel 1: attention + aggregate (R8-benched: 138us) =====================
__global__ __launch_bounds__(256, 6) void agcn_attn(
    const float* __restrict__ x, const float* __restrict__ A,
    const float* __restrict__ Wa, const float* __restrict__ ba,
    const float* __restrict__ Wb, const float* __restrict__ bb,
    float* __restrict__ z)
{
    const int bx = blockIdx.x;
    const int t  = (bx & 7) * 64 + (bx >> 3);   // XCD swizzle
    const int n  = blockIdx.y;
    const int tid = threadIdx.x;

    __shared__ __align__(16) float xs[CIN * XPAD];   // [c][v]
    __shared__ __align__(16) float A1t[VV * AT];     // [u][r]
    __shared__ __align__(16) float A2t[VV * AT];     // [v][r]
    __shared__ __align__(16) float Ss[VV * XPAD];    // [u][v]
    __shared__ __align__(16) float Ps[VV * XPAD];    // [u][v]

    // ---- P0: stage x tile and A tile ----
    for (int f = tid; f < CIN * VV; f += 256) {
        int c = f / VV, v = f - c * VV;
        xs[c * XPAD + v] = x[(((size_t)n * CIN + c) * TT + t) * VV + v];
    }
    {
        const float* Ag = A + (((size_t)n * TT + t) * VV) * VV;
        for (int f = tid; f < VV * VV; f += 256) {
            int u = f / VV, v = f - u * VV;
            Ps[u * XPAD + v] = Ag[f] + 1e-6f;
        }
    }
    __syncthreads();

    // ---- P1: A1t/A2t[u][r]. Thread (r2, q6): 4 W-rows (2 Wa + 2 Wb) x 4 u's. ----
    {
        const int r2 = tid >> 3;        // 0..31  -> rows r0 = 2*r2, 2*r2+1
        const int q6 = tid & 7;         // 0..7, active if < 6 -> us = 4*q6
        if (q6 < 6) {
            const int us = q6 * 4;
            const int r0 = r2 * 2;
            const float* Wa0 = Wa + (size_t)r0 * CIN;
            const float* Wa1 = Wa0 + CIN;
            const float* Wb0 = Wb + (size_t)r0 * CIN;
            const float* Wb1 = Wb0 + CIN;
            float acc[4][4];
            {
                const float ba0 = ba[r0], ba1 = ba[r0 + 1];
                const float bb0 = bb[r0], bb1 = bb[r0 + 1];
                #pragma unroll
                for (int j = 0; j < 4; ++j) {
                    acc[0][j] = ba0; acc[1][j] = ba1;
                    acc[2][j] = bb0; acc[3][j] = bb1;
                }
            }
            for (int cg = 0; cg < 16; ++cg) {
                float4 wa0 = *reinterpret_cast<const float4*>(Wa0 + cg * 4);
                float4 wa1 = *reinterpret_cast<const float4*>(Wa1 + cg * 4);
                float4 wb0 = *reinterpret_cast<const float4*>(Wb0 + cg * 4);
                float4 wb1 = *reinterpret_cast<const float4*>(Wb1 + cg * 4);
                const float wv0[4] = {wa0.x, wa0.y, wa0.z, wa0.w};
                const float wv1[4] = {wa1.x, wa1.y, wa1.z, wa1.w};
                const float wv2[4] = {wb0.x, wb0.y, wb0.z, wb0.w};
                const float wv3[4] = {wb1.x, wb1.y, wb1.z, wb1.w};
                #pragma unroll
                for (int c = 0; c < 4; ++c) {
                    // us % 4 == 0, XPAD % 4 == 0 -> 16B-aligned b128
                    float4 xv = *reinterpret_cast<const float4*>(&xs[(cg * 4 + c) * XPAD + us]);
                    const float xj[4] = {xv.x, xv.y, xv.z, xv.w};
                    #pragma unroll
                    for (int j = 0; j < 4; ++j) {
                        acc[0][j] += wv0[c] * xj[j];
                        acc[1][j] += wv1[c] * xj[j];
                        acc[2][j] += wv2[c] * xj[j];
                        acc[3][j] += wv3[c] * xj[j];
                    }
                }
            }
            #pragma unroll
            for (int j = 0; j < 4; ++j) {
                if (us + j < VV) {   // tail group (us=20) discards j=2,3
                    A1t[(us + j) * AT + r0]     = acc[0][j];
                    A1t[(us + j) * AT + r0 + 1] = acc[1][j];
                    A2t[(us + j) * AT + r0]     = acc[2][j];
                    A2t[(us + j) * AT + r0 + 1] = acc[3][j];
                }
            }
        }
    }
    __syncthreads();

    // ---- P2: 2x2 register tiles. S[u][v] = (1/64) sum_i A1t[u][i]*A2t[v][i] ----
    if (tid < 121) {
        const int tu = tid / 11, tv = tid - tu * 11;
        const int u0 = tu * 2, v0 = tv * 2;
        const float4* a0 = reinterpret_cast<const float4*>(&A1t[u0 * AT]);
        const float4* a1 = reinterpret_cast<const float4*>(&A1t[(u0 + 1) * AT]);
        const float4* b0 = reinterpret_cast<const float4*>(&A2t[v0 * AT]);
        const float4* b1 = reinterpret_cast<const float4*>(&A2t[(v0 + 1) * AT]);
        float4 s00 = {0,0,0,0}, s01 = {0,0,0,0}, s10 = {0,0,0,0}, s11 = {0,0,0,0};
        #pragma unroll
        for (int ig = 0; ig < 16; ++ig) {
            float4 A0 = a0[ig], A1v = a1[ig], B0 = b0[ig], B1 = b1[ig];
            s00.x += A0.x*B0.x; s00.y += A0.y*B0.y; s00.z += A0.z*B0.z; s00.w += A0.w*B0.w;
            s01.x += A0.x*B1.x; s01.y += A0.y*B1.y; s01.z += A0.z*B1.z; s01.w += A0.w*B1.w;
            s10.x += A1v.x*B0.x; s10.y += A1v.y*B0.y; s10.z += A1v.z*B0.z; s10.w += A1v.w*B0.w;
            s11.x += A1v.x*B1.x; s11.y += A1v.y*B1.y; s11.z += A1v.z*B1.z; s11.w += A1v.w*B1.w;
        }
        const float k = 1.0f / 64.0f;
        Ss[u0 * XPAD + v0]           = ((s00.x+s00.y)+(s00.z+s00.w)) * k;
        Ss[u0 * XPAD + v0 + 1]       = ((s01.x+s01.y)+(s01.z+s01.w)) * k;
        Ss[(u0+1) * XPAD + v0]       = ((s10.x+s10.y)+(s10.z+s10.w)) * k;
        Ss[(u0+1) * XPAD + v0 + 1]   = ((s11.x+s11.y)+(s11.z+s11.w)) * k;
    }
    __syncthreads();

    // ---- P3: shuffle softmax over u, per column v. 22 columns x 8 lanes ----
    if (tid < VV * 8) {
        const int v = tid >> 3, p = tid & 7;
        const int u1 = p + 8, u2 = p + 16;
        float s0 = Ss[p * XPAD + v];
        float s1 = Ss[u1 * XPAD + v];
        float s2 = (u2 < VV) ? Ss[u2 * XPAD + v] : -1e30f;
        float m = fmaxf(s0, fmaxf(s1, s2));
        m = fmaxf(m, __shfl_xor(m, 1, 8));
        m = fmaxf(m, __shfl_xor(m, 2, 8));
        m = fmaxf(m, __shfl_xor(m, 4, 8));
        float e0 = __expf(s0 - m), e1 = __expf(s1 - m);
        float e2 = (u2 < VV) ? __expf(s2 - m) : 0.f;
        float sum = e0 + e1 + e2;
        sum += __shfl_xor(sum, 1, 8);
        sum += __shfl_xor(sum, 2, 8);
        sum += __shfl_xor(sum, 4, 8);
        const float inv = 1.0f / sum;
        Ps[p * XPAD + v]  += e0 * inv;
        Ps[u1 * XPAD + v] += e1 * inv;
        if (u2 < VV) Ps[u2 * XPAD + v] += e2 * inv;
    }
    __syncthreads();

    // ---- P4: 2x2 tiles (c-pair x u-pair). z[c][u] = sum_w Ps[u][w]*xs[c][w] ----
    {
        const int tb  = t >> 2;
        const int ttl = t & 3;
        float* zdst = z + (((size_t)n * NTB + tb) * CIN) * ZROW + ttl * VV;
        #pragma unroll
        for (int pass = 0; pass < 2; ++pass) {
            const int tt = pass * 256 + tid;
            if (tt < 352) {
                const int cp = tt / 11, up = tt - cp * 11;
                const int c0 = cp * 2, u0 = up * 2;
                const float4* x0 = reinterpret_cast<const float4*>(&xs[c0 * XPAD]);
                const float4* x1 = reinterpret_cast<const float4*>(&xs[(c0 + 1) * XPAD]);
                const float4* p0 = reinterpret_cast<const float4*>(&Ps[u0 * XPAD]);
                const float4* p1 = reinterpret_cast<const float4*>(&Ps[(u0 + 1) * XPAD]);
                float a00 = 0.f, a01 = 0.f, a10 = 0.f, a11 = 0.f;
                #pragma unroll
                for (int wg = 0; wg < 5; ++wg) {
                    float4 X0 = x0[wg], X1 = x1[wg], P0 = p0[wg], P1 = p1[wg];
                    a00 += P0.x*X0.x + P0.y*X0.y + P0.z*X0.z + P0.w*X0.w;
                    a01 += P1.x*X0.x + P1.y*X0.y + P1.z*X0.z + P1.w*X0.w;
                    a10 += P0.x*X1.x + P0.y*X1.y + P0.z*X1.z + P0.w*X1.w;
                    a11 += P1.x*X1.x + P1.y*X1.y + P1.z*X1.z + P1.w*X1.w;
                }
                {
                    float xa = xs[c0*XPAD+20], xb = xs[c0*XPAD+21];
                    float xc = xs[(c0+1)*XPAD+20], xd = xs[(c0+1)*XPAD+21];
                    float pa = Ps[u0*XPAD+20], pb = Ps[u0*XPAD+21];
                    float pc = Ps[(u0+1)*XPAD+20], pd = Ps[(u0+1)*XPAD+21];
                    a00 += pa*xa + pb*xb;  a01 += pc*xa + pd*xb;
                    a10 += pa*xc + pb*xd;  a11 += pc*xc + pd*xd;
                }
                float2 r0 = {a00, a01}, r1 = {a10, a11};
                *reinterpret_cast<float2*>(&zdst[(size_t)c0 * ZROW + u0]) = r0;
                *reinterpret_cast<float2*>(&zdst[(size_t)(c0 + 1) * ZROW + u0]) = r1;
            }
        }
    }
}

// ===================== Kernel 2 helpers =====================
__device__ __forceinline__ void k2_gemm(const float* Zbuf, const float* __restrict__ Wd,
                                        int o0, int col0, int kg0, int kg1,
                                        float (&acc)[8][6])
{
    for (int kg = kg0; kg < kg1; ++kg) {
        const int k = kg * 4;
        float4 w[8];
        #pragma unroll
        for (int j = 0; j < 8; ++j)
            w[j] = *reinterpret_cast<const float4*>(&Wd[(size_t)(o0 + j) * CIN + k]);
        #pragma unroll
        for (int kk = 0; kk < 4; ++kk) {
            const float* zr = &Zbuf[(k + kk) * ZS + col0];
            float2 za = *reinterpret_cast<const float2*>(zr);
            float2 zb = *reinterpret_cast<const float2*>(zr + 2);
            float2 zc = *reinterpret_cast<const float2*>(zr + 4);
            const float zv[6] = {za.x, za.y, zb.x, zb.y, zc.x, zc.y};
            #pragma unroll
            for (int j = 0; j < 8; ++j) {
                const float wj = (kk == 0) ? w[j].x : (kk == 1) ? w[j].y : (kk == 2) ? w[j].z : w[j].w;
                #pragma unroll
                for (int m = 0; m < 6; ++m)
                    acc[j][m] += wj * zv[m];
            }
        }
    }
}

__device__ __forceinline__ void k2_store(float* __restrict__ out, int n, int o0, int tb,
                                         int col0, float (&acc)[8][6])
{
    #pragma unroll
    for (int j = 0; j < 8; ++j) {
        float* op = out + ((size_t)(n * COUT + o0 + j)) * (TT * VV) + (size_t)tb * ZROW + col0;
        #pragma unroll
        for (int m = 0; m < 6; m += 2) {
            if (col0 + m < ZROW) {
                float2 sv = {fmaxf(acc[j][m], 0.f), fmaxf(acc[j][m + 1], 0.f)};
                *reinterpret_cast<float2*>(op + m) = sv;
            }
        }
    }
}

// ===================== Kernel 2: out = relu(Wd @ z + bd), 2 tb-tiles/block, dbuf (R9-benched) =====================
__global__ __launch_bounds__(256, 3) void agcn_out(
    const float* __restrict__ z, const float* __restrict__ Wd,
    const float* __restrict__ bd, float* __restrict__ out)
{
    const int bxx = blockIdx.x;                  // 0..63
    const int tb0 = (bxx & 7) * 8 + (bxx >> 3);  // XCD swizzle aligned with k1
    const int tb  = tb0 * 2;
    const int ob  = blockIdx.y;                  // 0..1
    const int n   = blockIdx.z;
    const int tid = threadIdx.x;
    const int tx = tid & 15, ty = tid >> 4;
    const int o0 = ob * 128 + ty * 8;
    const int col0 = tx * 6;

    __shared__ __align__(16) float Zs[2][CIN * ZS + 8];

    const float* zsrc0 = z + (((size_t)n * NTB + tb) * CIN) * ZROW;
    const float* zsrc1 = zsrc0 + (size_t)CIN * ZROW;

    // stage tile 0
    #pragma unroll
    for (int it = 0; it < 6; ++it) {
        const int i4 = it * 256 + tid;
        if (i4 < (CIN * ZROW) / 4) {
            float4 val = *reinterpret_cast<const float4*>(zsrc0 + (size_t)i4 * 4);
            int c = i4 / (ZROW / 4), r4 = (i4 % (ZROW / 4)) * 4;
            *reinterpret_cast<float4*>(&Zs[0][c * ZS + r4]) = val;
        }
    }
    __syncthreads();

    // prefetch tile 1 into registers (loads in flight during first half of tile-0 compute)
    float4 pre[6];
    #pragma unroll
    for (int it = 0; it < 6; ++it) {
        const int i4 = it * 256 + tid;
        if (i4 < (CIN * ZROW) / 4)
            pre[it] = *reinterpret_cast<const float4*>(zsrc1 + (size_t)i4 * 4);
    }

    float acc[8][6];
    #pragma unroll
    for (int j = 0; j < 8; ++j) {
        const float b = bd[o0 + j];
        #pragma unroll
        for (int m = 0; m < 6; ++m) acc[j][m] = b;
    }

    k2_gemm(Zs[0], Wd, o0, col0, 0, 8, acc);

    // write prefetched tile 1 to LDS (no barrier needed: nobody reads Zs[1] yet)
    #pragma unroll
    for (int it = 0; it < 6; ++it) {
        const int i4 = it * 256 + tid;
        if (i4 < (CIN * ZROW) / 4) {
            int c = i4 / (ZROW / 4), r4 = (i4 % (ZROW / 4)) * 4;
            *reinterpret_cast<float4*>(&Zs[1][c * ZS + r4]) = pre[it];
        }
    }

    k2_gemm(Zs[0], Wd, o0, col0, 8, 16, acc);
    k2_store(out, n, o0, tb, col0, acc);
    __syncthreads();   // Zs[1] fully written; Zs[0] no longer needed

    #pragma unroll
    for (int j = 0; j < 8; ++j) {
        const float b = bd[o0 + j];
        #pragma unroll
        for (int m = 0; m < 6; ++m) acc[j][m] = b;
    }
    k2_gemm(Zs[1], Wd, o0, col0, 0, 16, acc);
    k2_store(out, n, o0, tb + 1, col0, acc);
}

// ===================== Fallback: verified R1 monolithic kernel =====================
__global__ __launch_bounds__(256, 4) void agcn_fused(
    const float* __restrict__ x, const float* __restrict__ A,
    const float* __restrict__ Wa, const float* __restrict__ ba,
    const float* __restrict__ Wb, const float* __restrict__ bb,
    const float* __restrict__ Wd, const float* __restrict__ bd,
    float* __restrict__ out)
{
    const int t   = blockIdx.x;
    const int n   = blockIdx.y;
    const int tid = threadIdx.x;
    __shared__ float smem[7424];
    float* xs   = smem;
    float* A1s  = smem + 1536;
    float* A2s  = smem + 3072;
    float* Ssf  = smem + 4608;
    float* Psf  = smem + 5136;
    float* outs = smem;
    float* zs   = smem + 5888;

    for (int f = tid; f < CIN * VV; f += 256) {
        int c = f / VV, v = f - c * VV;
        xs[c * PAD + v] = x[(((size_t)n * CIN + c) * TT + t) * VV + v];
    }
    {
        const float* Ag = A + (((size_t)n * TT + t) * VV) * VV;
        for (int f = tid; f < VV * VV; f += 256) {
            int u = f / VV, v = f - u * VV;
            Psf[u * PAD + v] = Ag[f] + 1e-6f;
        }
    }
    __syncthreads();
    {
        const int r  = tid & 63;
        const int q  = tid >> 6;
        const int us = (q * VV) >> 2;
        const int ue = ((q + 1) * VV) >> 2;
        const float* War = Wa + r * CIN;
        const float* Wbr = Wb + r * CIN;
        float acc1[6], acc2[6];
        const float b1 = ba[r], b2 = bb[r];
        #pragma unroll
        for (int u = 0; u < 6; ++u) { acc1[u] = b1; acc2[u] = b2; }
        for (int c = 0; c < CIN; c += 4) {
            float4 wa4 = *reinterpret_cast<const float4*>(War + c);
            float4 wb4 = *reinterpret_cast<const float4*>(Wbr + c);
            #pragma unroll
            for (int u = 0; u < 6; ++u) {
                float x0 = xs[(c + 0) * PAD + us + u];
                float x1 = xs[(c + 1) * PAD + us + u];
                float x2 = xs[(c + 2) * PAD + us + u];
                float x3 = xs[(c + 3) * PAD + us + u];
                acc1[u] += wa4.x * x0 + wa4.y * x1 + wa4.z * x2 + wa4.w * x3;
                acc2[u] += wb4.x * x0 + wb4.y * x1 + wb4.z * x2 + wb4.w * x3;
            }
        }
        #pragma unroll
        for (int u = 0; u < 6; ++u) {
            if (us + u < ue) {
                A1s[r * PAD + us + u] = acc1[u];
                A2s[r * PAD + us + u] = acc2[u];
            }
        }
    }
    __syncthreads();
    for (int f = tid; f < VV * VV; f += 256) {
        int u = f / VV, v = f - u * VV;
        float s = 0.f;
        for (int i = 0; i < CIN; ++i)
            s += A1s[i * PAD + u] * A2s[i * PAD + v];
        Ssf[u * PAD + v] = s * (1.0f / 64.0f);
    }
    __syncthreads();
    if (tid < VV) {
        const int v = tid;
        float m = -1e30f;
        #pragma unroll
        for (int u = 0; u < VV; ++u) m = fmaxf(m, Ssf[u * PAD + v]);
        float sum = 0.f;
        #pragma unroll
        for (int u = 0; u < VV; ++u) sum += __expf(Ssf[u * PAD + v] - m);
        const float inv = 1.0f / sum;
        #pragma unroll
        for (int u = 0; u < VV; ++u)
            Psf[u * PAD + v] += __expf(Ssf[u * PAD + v] - m) * inv;
    }
    __syncthreads();
    for (int f = tid; f < CIN * VV; f += 256) {
        int c = f / VV, u = f - c * VV;
        float s = 0.f;
        #pragma unroll
        for (int w = 0; w < VV; ++w)
            s += Psf[u * PAD + w] * xs[c * PAD + w];
        zs[c * PAD + u] = s;
    }
    __syncthreads();
    {
        const int o = tid;
        const float* Wr = Wd + o * CIN;
        float acc[VV];
        const float b = bd[o];
        #pragma unroll
        for (int u = 0; u < VV; ++u) acc[u] = b;
        for (int c = 0; c < CIN; c += 4) {
            float4 w4 = *reinterpret_cast<const float4*>(Wr + c);
            #pragma unroll
            for (int cc = 0; cc < 4; ++cc) {
                const float w = (cc == 0) ? w4.x : (cc == 1) ? w4.y : (cc == 2) ? w4.z : w4.w;
                const float* zr = zs + (c + cc) * PAD;
                #pragma unroll
                for (int uq = 0; uq < 5; ++uq) {
                    float4 zq = *reinterpret_cast<const float4*>(zr + uq * 4);
                    acc[uq * 4 + 0] += w * zq.x;
                    acc[uq * 4 + 1] += w * zq.y;
                    acc[uq * 4 + 2] += w * zq.z;
                    acc[uq * 4 + 3] += w * zq.w;
                }
                float2 zt = *reinterpret_cast<const float2*>(zr + 20);
                acc[20] += w * zt.x;
                acc[21] += w * zt.y;
            }
        }
        #pragma unroll
        for (int u = 0; u < VV; ++u)
            outs[o * OPAD + u] = fmaxf(acc[u], 0.f);
    }
    __syncthreads();
    {
        const size_t obase = (size_t)n * COUT * TT * VV + (size_t)t * VV;
        for (int f = tid; f < COUT * VV; f += 256) {
            int o = f / VV, u = f - o * VV;
            out[obase + (size_t)o * (TT * VV) + u] = outs[o * OPAD + u];
        }
    }
}

extern "C" void kernel_launch(void* const* d_in, const int* in_sizes, int n_in,
                              void* d_out, int out_size, void* d_ws, size_t ws_size,
                              hipStream_t stream) {
    const float* x  = (const float*)d_in[0];
    const float* A  = (const float*)d_in[1];
    const float* Wa = (const float*)d_in[2];
    const float* ba = (const float*)d_in[3];
    const float* Wb = (const float*)d_in[4];
    const float* bb = (const float*)d_in[5];
    const float* Wd = (const float*)d_in[6];
    const float* bd = (const float*)d_in[7];
    float* outp     = (float*)d_out;

    const size_t z_bytes = (size_t)NB * TT * CIN * VV * sizeof(float);  // 46.1 MB
    if (ws_size >= z_bytes) {
        float* zws = (float*)d_ws;
        dim3 g1(TT, NB);
        agcn_attn<<<g1, 256, 0, stream>>>(x, A, Wa, ba, Wb, bb, zws);
        dim3 g2(NTB / 2, COUT / 128, NB);
        agcn_out<<<g2, 256, 0, stream>>>(zws, Wd, bd, outp);
    } else {
        dim3 grid(TT, NB);
        agcn_fused<<<grid, 256, 0, stream>>>(x, A, Wa, ba, Wb, bb, Wd, bd, outp);
    }
}

// Round 11
// 241.318 us; speedup vs baseline: 1.2595x; 1.0002x over previous
//
#include <hip/hip_runtime.h>

#define NB    16
#define CIN   64
#define TT    512
#define VV    22
#define COUT  256
#define TBK   4            // t per z tile
#define NTB   (TT / TBK)   // 128
#define ZROW  (TBK * VV)   // 88
#define ZS    92           // k2 Zs row stride (mult of 4 -> b128-aligned rows)
#define XPAD  28           // k1 xs/Ss/Ps row stride (float4-able)
#define AT    68           // A1t/A2t row stride [u][r] (mult of 4: odd rows stay 16B-aligned)
#define PAD   24           // fallback kernel pads
#define OPAD  23

// ===================== Kernel 1: attention + aggregate (R8/R10-benched: 138us) =====================
__global__ __launch_bounds__(256, 6) void agcn_attn(
    const float* __restrict__ x, const float* __restrict__ A,
    const float* __restrict__ Wa, const float* __restrict__ ba,
    const float* __restrict__ Wb, const float* __restrict__ bb,
    float* __restrict__ z)
{
    const int bx = blockIdx.x;
    const int t  = (bx & 7) * 64 + (bx >> 3);   // XCD swizzle
    const int n  = blockIdx.y;
    const int tid = threadIdx.x;

    __shared__ __align__(16) float xs[CIN * XPAD];   // [c][v]
    __shared__ __align__(16) float A1t[VV * AT];     // [u][r]
    __shared__ __align__(16) float A2t[VV * AT];     // [v][r]
    __shared__ __align__(16) float Ss[VV * XPAD];    // [u][v]
    __shared__ __align__(16) float Ps[VV * XPAD];    // [u][v]

    // ---- P0: stage x tile and A tile ----
    for (int f = tid; f < CIN * VV; f += 256) {
        int c = f / VV, v = f - c * VV;
        xs[c * XPAD + v] = x[(((size_t)n * CIN + c) * TT + t) * VV + v];
    }
    {
        const float* Ag = A + (((size_t)n * TT + t) * VV) * VV;
        for (int f = tid; f < VV * VV; f += 256) {
            int u = f / VV, v = f - u * VV;
            Ps[u * XPAD + v] = Ag[f] + 1e-6f;
        }
    }
    __syncthreads();

    // ---- P1: A1t/A2t[u][r]. Thread (r2, q6): 4 W-rows (2 Wa + 2 Wb) x 4 u's. ----
    {
        const int r2 = tid >> 3;        // 0..31  -> rows r0 = 2*r2, 2*r2+1
        const int q6 = tid & 7;         // 0..7, active if < 6 -> us = 4*q6
        if (q6 < 6) {
            const int us = q6 * 4;
            const int r0 = r2 * 2;
            const float* Wa0 = Wa + (size_t)r0 * CIN;
            const float* Wa1 = Wa0 + CIN;
            const float* Wb0 = Wb + (size_t)r0 * CIN;
            const float* Wb1 = Wb0 + CIN;
            float acc[4][4];
            {
                const float ba0 = ba[r0], ba1 = ba[r0 + 1];
                const float bb0 = bb[r0], bb1 = bb[r0 + 1];
                #pragma unroll
                for (int j = 0; j < 4; ++j) {
                    acc[0][j] = ba0; acc[1][j] = ba1;
                    acc[2][j] = bb0; acc[3][j] = bb1;
                }
            }
            for (int cg = 0; cg < 16; ++cg) {
                float4 wa0 = *reinterpret_cast<const float4*>(Wa0 + cg * 4);
                float4 wa1 = *reinterpret_cast<const float4*>(Wa1 + cg * 4);
                float4 wb0 = *reinterpret_cast<const float4*>(Wb0 + cg * 4);
                float4 wb1 = *reinterpret_cast<const float4*>(Wb1 + cg * 4);
                const float wv0[4] = {wa0.x, wa0.y, wa0.z, wa0.w};
                const float wv1[4] = {wa1.x, wa1.y, wa1.z, wa1.w};
                const float wv2[4] = {wb0.x, wb0.y, wb0.z, wb0.w};
                const float wv3[4] = {wb1.x, wb1.y, wb1.z, wb1.w};
                #pragma unroll
                for (int c = 0; c < 4; ++c) {
                    float4 xv = *reinterpret_cast<const float4*>(&xs[(cg * 4 + c) * XPAD + us]);
                    const float xj[4] = {xv.x, xv.y, xv.z, xv.w};
                    #pragma unroll
                    for (int j = 0; j < 4; ++j) {
                        acc[0][j] += wv0[c] * xj[j];
                        acc[1][j] += wv1[c] * xj[j];
                        acc[2][j] += wv2[c] * xj[j];
                        acc[3][j] += wv3[c] * xj[j];
                    }
                }
            }
            #pragma unroll
            for (int j = 0; j < 4; ++j) {
                if (us + j < VV) {   // tail group (us=20) discards j=2,3
                    A1t[(us + j) * AT + r0]     = acc[0][j];
                    A1t[(us + j) * AT + r0 + 1] = acc[1][j];
                    A2t[(us + j) * AT + r0]     = acc[2][j];
                    A2t[(us + j) * AT + r0 + 1] = acc[3][j];
                }
            }
        }
    }
    __syncthreads();

    // ---- P2: 2x2 register tiles. S[u][v] = (1/64) sum_i A1t[u][i]*A2t[v][i] ----
    if (tid < 121) {
        const int tu = tid / 11, tv = tid - tu * 11;
        const int u0 = tu * 2, v0 = tv * 2;
        const float4* a0 = reinterpret_cast<const float4*>(&A1t[u0 * AT]);
        const float4* a1 = reinterpret_cast<const float4*>(&A1t[(u0 + 1) * AT]);
        const float4* b0 = reinterpret_cast<const float4*>(&A2t[v0 * AT]);
        const float4* b1 = reinterpret_cast<const float4*>(&A2t[(v0 + 1) * AT]);
        float4 s00 = {0,0,0,0}, s01 = {0,0,0,0}, s10 = {0,0,0,0}, s11 = {0,0,0,0};
        #pragma unroll
        for (int ig = 0; ig < 16; ++ig) {
            float4 A0 = a0[ig], A1v = a1[ig], B0 = b0[ig], B1 = b1[ig];
            s00.x += A0.x*B0.x; s00.y += A0.y*B0.y; s00.z += A0.z*B0.z; s00.w += A0.w*B0.w;
            s01.x += A0.x*B1.x; s01.y += A0.y*B1.y; s01.z += A0.z*B1.z; s01.w += A0.w*B1.w;
            s10.x += A1v.x*B0.x; s10.y += A1v.y*B0.y; s10.z += A1v.z*B0.z; s10.w += A1v.w*B0.w;
            s11.x += A1v.x*B1.x; s11.y += A1v.y*B1.y; s11.z += A1v.z*B1.z; s11.w += A1v.w*B1.w;
        }
        const float k = 1.0f / 64.0f;
        Ss[u0 * XPAD + v0]           = ((s00.x+s00.y)+(s00.z+s00.w)) * k;
        Ss[u0 * XPAD + v0 + 1]       = ((s01.x+s01.y)+(s01.z+s01.w)) * k;
        Ss[(u0+1) * XPAD + v0]       = ((s10.x+s10.y)+(s10.z+s10.w)) * k;
        Ss[(u0+1) * XPAD + v0 + 1]   = ((s11.x+s11.y)+(s11.z+s11.w)) * k;
    }
    __syncthreads();

    // ---- P3: shuffle softmax over u, per column v. 22 columns x 8 lanes ----
    if (tid < VV * 8) {
        const int v = tid >> 3, p = tid & 7;
        const int u1 = p + 8, u2 = p + 16;
        float s0 = Ss[p * XPAD + v];
        float s1 = Ss[u1 * XPAD + v];
        float s2 = (u2 < VV) ? Ss[u2 * XPAD + v] : -1e30f;
        float m = fmaxf(s0, fmaxf(s1, s2));
        m = fmaxf(m, __shfl_xor(m, 1, 8));
        m = fmaxf(m, __shfl_xor(m, 2, 8));
        m = fmaxf(m, __shfl_xor(m, 4, 8));
        float e0 = __expf(s0 - m), e1 = __expf(s1 - m);
        float e2 = (u2 < VV) ? __expf(s2 - m) : 0.f;
        float sum = e0 + e1 + e2;
        sum += __shfl_xor(sum, 1, 8);
        sum += __shfl_xor(sum, 2, 8);
        sum += __shfl_xor(sum, 4, 8);
        const float inv = 1.0f / sum;
        Ps[p * XPAD + v]  += e0 * inv;
        Ps[u1 * XPAD + v] += e1 * inv;
        if (u2 < VV) Ps[u2 * XPAD + v] += e2 * inv;
    }
    __syncthreads();

    // ---- P4: 2x2 tiles (c-pair x u-pair). z[c][u] = sum_w Ps[u][w]*xs[c][w] ----
    {
        const int tb  = t >> 2;
        const int ttl = t & 3;
        float* zdst = z + (((size_t)n * NTB + tb) * CIN) * ZROW + ttl * VV;
        #pragma unroll
        for (int pass = 0; pass < 2; ++pass) {
            const int tt = pass * 256 + tid;
            if (tt < 352) {
                const int cp = tt / 11, up = tt - cp * 11;
                const int c0 = cp * 2, u0 = up * 2;
                const float4* x0 = reinterpret_cast<const float4*>(&xs[c0 * XPAD]);
                const float4* x1 = reinterpret_cast<const float4*>(&xs[(c0 + 1) * XPAD]);
                const float4* p0 = reinterpret_cast<const float4*>(&Ps[u0 * XPAD]);
                const float4* p1 = reinterpret_cast<const float4*>(&Ps[(u0 + 1) * XPAD]);
                float a00 = 0.f, a01 = 0.f, a10 = 0.f, a11 = 0.f;
                #pragma unroll
                for (int wg = 0; wg < 5; ++wg) {
                    float4 X0 = x0[wg], X1 = x1[wg], P0 = p0[wg], P1 = p1[wg];
                    a00 += P0.x*X0.x + P0.y*X0.y + P0.z*X0.z + P0.w*X0.w;
                    a01 += P1.x*X0.x + P1.y*X0.y + P1.z*X0.z + P1.w*X0.w;
                    a10 += P0.x*X1.x + P0.y*X1.y + P0.z*X1.z + P0.w*X1.w;
                    a11 += P1.x*X1.x + P1.y*X1.y + P1.z*X1.z + P1.w*X1.w;
                }
                {
                    float xa = xs[c0*XPAD+20], xb = xs[c0*XPAD+21];
                    float xc = xs[(c0+1)*XPAD+20], xd = xs[(c0+1)*XPAD+21];
                    float pa = Ps[u0*XPAD+20], pb = Ps[u0*XPAD+21];
                    float pc = Ps[(u0+1)*XPAD+20], pd = Ps[(u0+1)*XPAD+21];
                    a00 += pa*xa + pb*xb;  a01 += pc*xa + pd*xb;
                    a10 += pa*xc + pb*xd;  a11 += pc*xc + pd*xd;
                }
                float2 r0 = {a00, a01}, r1 = {a10, a11};
                *reinterpret_cast<float2*>(&zdst[(size_t)c0 * ZROW + u0]) = r0;
                *reinterpret_cast<float2*>(&zdst[(size_t)(c0 + 1) * ZROW + u0]) = r1;
            }
        }
    }
}

// ===================== Kernel 2: out = relu(Wd @ z + bd) =====================
// One block per (tb, n): 384 threads, all 256 o's. Thread (tx 0..10, ty 0..31): 8o x 8v.
// col0 = 8*tx -> 16B-aligned b128 LDS reads (2 per row) and float4 stores; 88 = 11*8 exact.
// z staged ONCE per tile (was twice with the ob-split).
__global__ __launch_bounds__(384, 3) void agcn_out(
    const float* __restrict__ z, const float* __restrict__ Wd,
    const float* __restrict__ bd, float* __restrict__ out)
{
    const int bxx = blockIdx.x;                  // 0..127
    const int tb  = (bxx & 7) * 16 + (bxx >> 3); // XCD swizzle aligned with k1
    const int n   = blockIdx.y;
    const int tid = threadIdx.x;

    __shared__ __align__(16) float Zs[CIN * ZS + 8];   // 64 x 92 = 23.6 KB

    {
        const float* zsrc = z + (((size_t)n * NTB + tb) * CIN) * ZROW;
        for (int i4 = tid; i4 < (CIN * ZROW) / 4; i4 += 384) {
            float4 val = *reinterpret_cast<const float4*>(zsrc + (size_t)i4 * 4);
            int c = i4 / (ZROW / 4), r4 = (i4 % (ZROW / 4)) * 4;
            *reinterpret_cast<float4*>(&Zs[c * ZS + r4]) = val;
        }
    }
    __syncthreads();

    const int tx = tid % 11;
    const int ty = tid / 11;
    if (ty >= 32) return;            // 352 active; no barriers after this point
    const int o0   = ty * 8;
    const int col0 = tx * 8;

    float acc[8][8];
    #pragma unroll
    for (int j = 0; j < 8; ++j) {
        const float b = bd[o0 + j];
        #pragma unroll
        for (int m = 0; m < 8; ++m) acc[j][m] = b;
    }

    for (int kg = 0; kg < 16; ++kg) {
        const int k = kg * 4;
        float4 w[8];
        #pragma unroll
        for (int j = 0; j < 8; ++j)
            w[j] = *reinterpret_cast<const float4*>(&Wd[(size_t)(o0 + j) * CIN + k]);
        #pragma unroll
        for (int kk = 0; kk < 4; ++kk) {
            const float* zr = &Zs[(k + kk) * ZS + col0];       // 16B-aligned
            float4 z0 = *reinterpret_cast<const float4*>(zr);
            float4 z1 = *reinterpret_cast<const float4*>(zr + 4);
            const float zv[8] = {z0.x, z0.y, z0.z, z0.w, z1.x, z1.y, z1.z, z1.w};
            #pragma unroll
            for (int j = 0; j < 8; ++j) {
                const float wj = (kk == 0) ? w[j].x : (kk == 1) ? w[j].y
                               : (kk == 2) ? w[j].z : w[j].w;
                #pragma unroll
                for (int m = 0; m < 8; ++m)
                    acc[j][m] += wj * zv[m];
            }
        }
    }

    #pragma unroll
    for (int j = 0; j < 8; ++j) {
        float* op = out + ((size_t)(n * COUT + o0 + j)) * (TT * VV) + (size_t)tb * ZROW + col0;
        float4 s0 = {fmaxf(acc[j][0], 0.f), fmaxf(acc[j][1], 0.f),
                     fmaxf(acc[j][2], 0.f), fmaxf(acc[j][3], 0.f)};
        float4 s1 = {fmaxf(acc[j][4], 0.f), fmaxf(acc[j][5], 0.f),
                     fmaxf(acc[j][6], 0.f), fmaxf(acc[j][7], 0.f)};
        *reinterpret_cast<float4*>(op)     = s0;   // (tb*88 + 8tx)*4B is 16B-aligned
        *reinterpret_cast<float4*>(op + 4) = s1;
    }
}

// ===================== Fallback: verified R1 monolithic kernel =====================
__global__ __launch_bounds__(256, 4) void agcn_fused(
    const float* __restrict__ x, const float* __restrict__ A,
    const float* __restrict__ Wa, const float* __restrict__ ba,
    const float* __restrict__ Wb, const float* __restrict__ bb,
    const float* __restrict__ Wd, const float* __restrict__ bd,
    float* __restrict__ out)
{
    const int t   = blockIdx.x;
    const int n   = blockIdx.y;
    const int tid = threadIdx.x;
    __shared__ float smem[7424];
    float* xs   = smem;
    float* A1s  = smem + 1536;
    float* A2s  = smem + 3072;
    float* Ssf  = smem + 4608;
    float* Psf  = smem + 5136;
    float* outs = smem;
    float* zs   = smem + 5888;

    for (int f = tid; f < CIN * VV; f += 256) {
        int c = f / VV, v = f - c * VV;
        xs[c * PAD + v] = x[(((size_t)n * CIN + c) * TT + t) * VV + v];
    }
    {
        const float* Ag = A + (((size_t)n * TT + t) * VV) * VV;
        for (int f = tid; f < VV * VV; f += 256) {
            int u = f / VV, v = f - u * VV;
            Psf[u * PAD + v] = Ag[f] + 1e-6f;
        }
    }
    __syncthreads();
    {
        const int r  = tid & 63;
        const int q  = tid >> 6;
        const int us = (q * VV) >> 2;
        const int ue = ((q + 1) * VV) >> 2;
        const float* War = Wa + r * CIN;
        const float* Wbr = Wb + r * CIN;
        float acc1[6], acc2[6];
        const float b1 = ba[r], b2 = bb[r];
        #pragma unroll
        for (int u = 0; u < 6; ++u) { acc1[u] = b1; acc2[u] = b2; }
        for (int c = 0; c < CIN; c += 4) {
            float4 wa4 = *reinterpret_cast<const float4*>(War + c);
            float4 wb4 = *reinterpret_cast<const float4*>(Wbr + c);
            #pragma unroll
            for (int u = 0; u < 6; ++u) {
                float x0 = xs[(c + 0) * PAD + us + u];
                float x1 = xs[(c + 1) * PAD + us + u];
                float x2 = xs[(c + 2) * PAD + us + u];
                float x3 = xs[(c + 3) * PAD + us + u];
                acc1[u] += wa4.x * x0 + wa4.y * x1 + wa4.z * x2 + wa4.w * x3;
                acc2[u] += wb4.x * x0 + wb4.y * x1 + wb4.z * x2 + wb4.w * x3;
            }
        }
        #pragma unroll
        for (int u = 0; u < 6; ++u) {
            if (us + u < ue) {
                A1s[r * PAD + us + u] = acc1[u];
                A2s[r * PAD + us + u] = acc2[u];
            }
        }
    }
    __syncthreads();
    for (int f = tid; f < VV * VV; f += 256) {
        int u = f / VV, v = f - u * VV;
        float s = 0.f;
        for (int i = 0; i < CIN; ++i)
            s += A1s[i * PAD + u] * A2s[i * PAD + v];
        Ssf[u * PAD + v] = s * (1.0f / 64.0f);
    }
    __syncthreads();
    if (tid < VV) {
        const int v = tid;
        float m = -1e30f;
        #pragma unroll
        for (int u = 0; u < VV; ++u) m = fmaxf(m, Ssf[u * PAD + v]);
        float sum = 0.f;
        #pragma unroll
        for (int u = 0; u < VV; ++u) sum += __expf(Ssf[u * PAD + v] - m);
        const float inv = 1.0f / sum;
        #pragma unroll
        for (int u = 0; u < VV; ++u)
            Psf[u * PAD + v] += __expf(Ssf[u * PAD + v] - m) * inv;
    }
    __syncthreads();
    for (int f = tid; f < CIN * VV; f += 256) {
        int c = f / VV, u = f - c * VV;
        float s = 0.f;
        #pragma unroll
        for (int w = 0; w < VV; ++w)
            s += Psf[u * PAD + w] * xs[c * PAD + w];
        zs[c * PAD + u] = s;
    }
    __syncthreads();
    {
        const int o = tid;
        const float* Wr = Wd + o * CIN;
        float acc[VV];
        const float b = bd[o];
        #pragma unroll
        for (int u = 0; u < VV; ++u) acc[u] = b;
        for (int c = 0; c < CIN; c += 4) {
            float4 w4 = *reinterpret_cast<const float4*>(Wr + c);
            #pragma unroll
            for (int cc = 0; cc < 4; ++cc) {
                const float w = (cc == 0) ? w4.x : (cc == 1) ? w4.y : (cc == 2) ? w4.z : w4.w;
                const float* zr = zs + (c + cc) * PAD;
                #pragma unroll
                for (int uq = 0; uq < 5; ++uq) {
                    float4 zq = *reinterpret_cast<const float4*>(zr + uq * 4);
                    acc[uq * 4 + 0] += w * zq.x;
                    acc[uq * 4 + 1] += w * zq.y;
                    acc[uq * 4 + 2] += w * zq.z;
                    acc[uq * 4 + 3] += w * zq.w;
                }
                float2 zt = *reinterpret_cast<const float2*>(zr + 20);
                acc[20] += w * zt.x;
                acc[21] += w * zt.y;
            }
        }
        #pragma unroll
        for (int u = 0; u < VV; ++u)
            outs[o * OPAD + u] = fmaxf(acc[u], 0.f);
    }
    __syncthreads();
    {
        const size_t obase = (size_t)n * COUT * TT * VV + (size_t)t * VV;
        for (int f = tid; f < COUT * VV; f += 256) {
            int o = f / VV, u = f - o * VV;
            out[obase + (size_t)o * (TT * VV) + u] = outs[o * OPAD + u];
        }
    }
}

extern "C" void kernel_launch(void* const* d_in, const int* in_sizes, int n_in,
                              void* d_out, int out_size, void* d_ws, size_t ws_size,
                              hipStream_t stream) {
    const float* x  = (const float*)d_in[0];
    const float* A  = (const float*)d_in[1];
    const float* Wa = (const float*)d_in[2];
    const float* ba = (const float*)d_in[3];
    const float* Wb = (const float*)d_in[4];
    const float* bb = (const float*)d_in[5];
    const float* Wd = (const float*)d_in[6];
    const float* bd = (const float*)d_in[7];
    float* outp     = (float*)d_out;

    const size_t z_bytes = (size_t)NB * TT * CIN * VV * sizeof(float);  // 46.1 MB
    if (ws_size >= z_bytes) {
        float* zws = (float*)d_ws;
        dim3 g1(TT, NB);
        agcn_attn<<<g1, 256, 0, stream>>>(x, A, Wa, ba, Wb, bb, zws);
        dim3 g2(NTB, NB);
        agcn_out<<<g2, 384, 0, stream>>>(zws, Wd, bd, outp);
    } else {
        dim3 grid(TT, NB);
        agcn_fused<<<grid, 256, 0, stream>>>(x, A, Wa, ba, Wb, bb, Wd, bd, outp);
    }
}

// Round 12
// 176.580 us; speedup vs baseline: 1.7212x; 1.3666x over previous
//
#include <hip/hip_runtime.h>

#define NB    16
#define CIN   64
#define TT    512
#define VV    22
#define COUT  256
#define TBK   4            // t per z tile
#define NTB   (TT / TBK)   // 128
#define ZROW  (TBK * VV)   // 88
#define ZS    92           // k2 Zs row stride (mult of 4 -> b128-aligned rows)
#define XPAD  28           // k1 xs/Ss/Ps row stride (float4-able)
#define AT    68           // A1t/A2t row stride [u][r]
#define PAD   24           // fallback kernel pads
#define OPAD  23

typedef __attribute__((ext_vector_type(8))) short bf16x8;
typedef __attribute__((ext_vector_type(4))) float f32x4;

__device__ __forceinline__ ushort f2bf(float f) {   // RNE fp32 -> bf16
    unsigned u = __float_as_uint(f);
    return (ushort)((u + 0x7FFFu + ((u >> 16) & 1u)) >> 16);
}

// ===================== Prep: Wd -> bf16 (once, into ws tail) =====================
__global__ void wd_to_bf16(const float* __restrict__ Wd, ushort* __restrict__ WdB) {
    int i = blockIdx.x * 256 + threadIdx.x;
    if (i < COUT * CIN) WdB[i] = f2bf(Wd[i]);
}

// ===================== Kernel 1: attention + aggregate (R8/R10/R11-benched: 138us) =====================
__global__ __launch_bounds__(256, 6) void agcn_attn(
    const float* __restrict__ x, const float* __restrict__ A,
    const float* __restrict__ Wa, const float* __restrict__ ba,
    const float* __restrict__ Wb, const float* __restrict__ bb,
    float* __restrict__ z)
{
    const int bx = blockIdx.x;
    const int t  = (bx & 7) * 64 + (bx >> 3);   // XCD swizzle
    const int n  = blockIdx.y;
    const int tid = threadIdx.x;

    __shared__ __align__(16) float xs[CIN * XPAD];   // [c][v]
    __shared__ __align__(16) float A1t[VV * AT];     // [u][r]
    __shared__ __align__(16) float A2t[VV * AT];     // [v][r]
    __shared__ __align__(16) float Ss[VV * XPAD];    // [u][v]
    __shared__ __align__(16) float Ps[VV * XPAD];    // [u][v]

    // ---- P0: stage x tile and A tile ----
    for (int f = tid; f < CIN * VV; f += 256) {
        int c = f / VV, v = f - c * VV;
        xs[c * XPAD + v] = x[(((size_t)n * CIN + c) * TT + t) * VV + v];
    }
    {
        const float* Ag = A + (((size_t)n * TT + t) * VV) * VV;
        for (int f = tid; f < VV * VV; f += 256) {
            int u = f / VV, v = f - u * VV;
            Ps[u * XPAD + v] = Ag[f] + 1e-6f;
        }
    }
    __syncthreads();

    // ---- P1: A1t/A2t[u][r]. Thread (r2, q6): 4 W-rows (2 Wa + 2 Wb) x 4 u's. ----
    {
        const int r2 = tid >> 3;
        const int q6 = tid & 7;
        if (q6 < 6) {
            const int us = q6 * 4;
            const int r0 = r2 * 2;
            const float* Wa0 = Wa + (size_t)r0 * CIN;
            const float* Wa1 = Wa0 + CIN;
            const float* Wb0 = Wb + (size_t)r0 * CIN;
            const float* Wb1 = Wb0 + CIN;
            float acc[4][4];
            {
                const float ba0 = ba[r0], ba1 = ba[r0 + 1];
                const float bb0 = bb[r0], bb1 = bb[r0 + 1];
                #pragma unroll
                for (int j = 0; j < 4; ++j) {
                    acc[0][j] = ba0; acc[1][j] = ba1;
                    acc[2][j] = bb0; acc[3][j] = bb1;
                }
            }
            for (int cg = 0; cg < 16; ++cg) {
                float4 wa0 = *reinterpret_cast<const float4*>(Wa0 + cg * 4);
                float4 wa1 = *reinterpret_cast<const float4*>(Wa1 + cg * 4);
                float4 wb0 = *reinterpret_cast<const float4*>(Wb0 + cg * 4);
                float4 wb1 = *reinterpret_cast<const float4*>(Wb1 + cg * 4);
                const float wv0[4] = {wa0.x, wa0.y, wa0.z, wa0.w};
                const float wv1[4] = {wa1.x, wa1.y, wa1.z, wa1.w};
                const float wv2[4] = {wb0.x, wb0.y, wb0.z, wb0.w};
                const float wv3[4] = {wb1.x, wb1.y, wb1.z, wb1.w};
                #pragma unroll
                for (int c = 0; c < 4; ++c) {
                    float4 xv = *reinterpret_cast<const float4*>(&xs[(cg * 4 + c) * XPAD + us]);
                    const float xj[4] = {xv.x, xv.y, xv.z, xv.w};
                    #pragma unroll
                    for (int j = 0; j < 4; ++j) {
                        acc[0][j] += wv0[c] * xj[j];
                        acc[1][j] += wv1[c] * xj[j];
                        acc[2][j] += wv2[c] * xj[j];
                        acc[3][j] += wv3[c] * xj[j];
                    }
                }
            }
            #pragma unroll
            for (int j = 0; j < 4; ++j) {
                if (us + j < VV) {
                    A1t[(us + j) * AT + r0]     = acc[0][j];
                    A1t[(us + j) * AT + r0 + 1] = acc[1][j];
                    A2t[(us + j) * AT + r0]     = acc[2][j];
                    A2t[(us + j) * AT + r0 + 1] = acc[3][j];
                }
            }
        }
    }
    __syncthreads();

    // ---- P2: 2x2 register tiles ----
    if (tid < 121) {
        const int tu = tid / 11, tv = tid - tu * 11;
        const int u0 = tu * 2, v0 = tv * 2;
        const float4* a0 = reinterpret_cast<const float4*>(&A1t[u0 * AT]);
        const float4* a1 = reinterpret_cast<const float4*>(&A1t[(u0 + 1) * AT]);
        const float4* b0 = reinterpret_cast<const float4*>(&A2t[v0 * AT]);
        const float4* b1 = reinterpret_cast<const float4*>(&A2t[(v0 + 1) * AT]);
        float4 s00 = {0,0,0,0}, s01 = {0,0,0,0}, s10 = {0,0,0,0}, s11 = {0,0,0,0};
        #pragma unroll
        for (int ig = 0; ig < 16; ++ig) {
            float4 A0 = a0[ig], A1v = a1[ig], B0 = b0[ig], B1 = b1[ig];
            s00.x += A0.x*B0.x; s00.y += A0.y*B0.y; s00.z += A0.z*B0.z; s00.w += A0.w*B0.w;
            s01.x += A0.x*B1.x; s01.y += A0.y*B1.y; s01.z += A0.z*B1.z; s01.w += A0.w*B1.w;
            s10.x += A1v.x*B0.x; s10.y += A1v.y*B0.y; s10.z += A1v.z*B0.z; s10.w += A1v.w*B0.w;
            s11.x += A1v.x*B1.x; s11.y += A1v.y*B1.y; s11.z += A1v.z*B1.z; s11.w += A1v.w*B1.w;
        }
        const float k = 1.0f / 64.0f;
        Ss[u0 * XPAD + v0]           = ((s00.x+s00.y)+(s00.z+s00.w)) * k;
        Ss[u0 * XPAD + v0 + 1]       = ((s01.x+s01.y)+(s01.z+s01.w)) * k;
        Ss[(u0+1) * XPAD + v0]       = ((s10.x+s10.y)+(s10.z+s10.w)) * k;
        Ss[(u0+1) * XPAD + v0 + 1]   = ((s11.x+s11.y)+(s11.z+s11.w)) * k;
    }
    __syncthreads();

    // ---- P3: shuffle softmax over u, per column v ----
    if (tid < VV * 8) {
        const int v = tid >> 3, p = tid & 7;
        const int u1 = p + 8, u2 = p + 16;
        float s0 = Ss[p * XPAD + v];
        float s1 = Ss[u1 * XPAD + v];
        float s2 = (u2 < VV) ? Ss[u2 * XPAD + v] : -1e30f;
        float m = fmaxf(s0, fmaxf(s1, s2));
        m = fmaxf(m, __shfl_xor(m, 1, 8));
        m = fmaxf(m, __shfl_xor(m, 2, 8));
        m = fmaxf(m, __shfl_xor(m, 4, 8));
        float e0 = __expf(s0 - m), e1 = __expf(s1 - m);
        float e2 = (u2 < VV) ? __expf(s2 - m) : 0.f;
        float sum = e0 + e1 + e2;
        sum += __shfl_xor(sum, 1, 8);
        sum += __shfl_xor(sum, 2, 8);
        sum += __shfl_xor(sum, 4, 8);
        const float inv = 1.0f / sum;
        Ps[p * XPAD + v]  += e0 * inv;
        Ps[u1 * XPAD + v] += e1 * inv;
        if (u2 < VV) Ps[u2 * XPAD + v] += e2 * inv;
    }
    __syncthreads();

    // ---- P4: 2x2 tiles; z store in TBK=4 layout ----
    {
        const int tb  = t >> 2;
        const int ttl = t & 3;
        float* zdst = z + (((size_t)n * NTB + tb) * CIN) * ZROW + ttl * VV;
        #pragma unroll
        for (int pass = 0; pass < 2; ++pass) {
            const int tt = pass * 256 + tid;
            if (tt < 352) {
                const int cp = tt / 11, up = tt - cp * 11;
                const int c0 = cp * 2, u0 = up * 2;
                const float4* x0 = reinterpret_cast<const float4*>(&xs[c0 * XPAD]);
                const float4* x1 = reinterpret_cast<const float4*>(&xs[(c0 + 1) * XPAD]);
                const float4* p0 = reinterpret_cast<const float4*>(&Ps[u0 * XPAD]);
                const float4* p1 = reinterpret_cast<const float4*>(&Ps[(u0 + 1) * XPAD]);
                float a00 = 0.f, a01 = 0.f, a10 = 0.f, a11 = 0.f;
                #pragma unroll
                for (int wg = 0; wg < 5; ++wg) {
                    float4 X0 = x0[wg], X1 = x1[wg], P0 = p0[wg], P1 = p1[wg];
                    a00 += P0.x*X0.x + P0.y*X0.y + P0.z*X0.z + P0.w*X0.w;
                    a01 += P1.x*X0.x + P1.y*X0.y + P1.z*X0.z + P1.w*X0.w;
                    a10 += P0.x*X1.x + P0.y*X1.y + P0.z*X1.z + P0.w*X1.w;
                    a11 += P1.x*X1.x + P1.y*X1.y + P1.z*X1.z + P1.w*X1.w;
                }
                {
                    float xa = xs[c0*XPAD+20], xb = xs[c0*XPAD+21];
                    float xc = xs[(c0+1)*XPAD+20], xd = xs[(c0+1)*XPAD+21];
                    float pa = Ps[u0*XPAD+20], pb = Ps[u0*XPAD+21];
                    float pc = Ps[(u0+1)*XPAD+20], pd = Ps[(u0+1)*XPAD+21];
                    a00 += pa*xa + pb*xb;  a01 += pc*xa + pd*xb;
                    a10 += pa*xc + pb*xd;  a11 += pc*xc + pd*xd;
                }
                float2 r0 = {a00, a01}, r1 = {a10, a11};
                *reinterpret_cast<float2*>(&zdst[(size_t)c0 * ZROW + u0]) = r0;
                *reinterpret_cast<float2*>(&zdst[(size_t)(c0 + 1) * ZROW + u0]) = r1;
            }
        }
    }
}

// ===================== Kernel 2 (MFMA): out = relu(Wd @ z + bd) =====================
// Block (tb, n): 256 thr = 4 waves x 64 o's. Per wave: 4 M-tiles x 6 N-tiles x 2 K-steps
// of mfma_f32_16x16x32_bf16. B-frags (z) shared across waves via fragment-ordered bf16 LDS.
// A/B both use k = kb*32 + (lane>>4)*8 + j (same bijection -> GEMM exact regardless of HW k-order).
// C/D layout (HW-verified): col = lane&15, row = (lane>>4)*4 + reg.
__global__ __launch_bounds__(256, 3) void agcn_out_mfma(
    const float* __restrict__ z, const ushort* __restrict__ WdB,
    const float* __restrict__ bd, float* __restrict__ out)
{
    const int bxx = blockIdx.x;                  // 0..127
    const int tb  = (bxx & 7) * 16 + (bxx >> 3); // XCD swizzle aligned with k1
    const int n   = blockIdx.y;
    const int tid = threadIdx.x;
    const int lane = tid & 63, wave = tid >> 6;
    const int hi = lane >> 4, lo = lane & 15;

    __shared__ __align__(16) float  Zs[CIN * ZS + 8];        // 23.6 KB fp32 stage
    __shared__ __align__(16) ushort zbf[2 * 6 * 64 * 8];     // 12 KB  [kb][nt][lane][j]

    // ---- stage z tile fp32 (coalesced b128) ----
    {
        const float* zsrc = z + (((size_t)n * NTB + tb) * CIN) * ZROW;
        for (int i4 = tid; i4 < (CIN * ZROW) / 4; i4 += 256) {
            float4 val = *reinterpret_cast<const float4*>(zsrc + (size_t)i4 * 4);
            int c = i4 / (ZROW / 4), r4 = (i4 % (ZROW / 4)) * 4;
            *reinterpret_cast<float4*>(&Zs[c * ZS + r4]) = val;
        }
    }
    __syncthreads();

    // ---- convert to fragment-ordered bf16: item = (kb, nt, ln); one b128 write each ----
    for (int it = tid; it < 768; it += 256) {
        const int kb  = it / 384;
        const int rem = it - kb * 384;
        const int nt  = rem >> 6;
        const int ln  = rem & 63;
        const int tv  = nt * 16 + (ln & 15);
        const int c0  = kb * 32 + (ln >> 4) * 8;
        ushort tmp[8];
        if (tv < ZROW) {
            #pragma unroll
            for (int j = 0; j < 8; ++j) tmp[j] = f2bf(Zs[(c0 + j) * ZS + tv]);
        } else {
            #pragma unroll
            for (int j = 0; j < 8; ++j) tmp[j] = 0;
        }
        *reinterpret_cast<uint4*>(&zbf[(size_t)it * 8]) = *reinterpret_cast<const uint4*>(tmp);
    }
    __syncthreads();

    // ---- MFMA: acc[mt][nt], row-of-C = hi*4+r, col-of-C = lo ----
    const int o0 = wave * 64;
    f32x4 acc[4][6];
    #pragma unroll
    for (int mt = 0; mt < 4; ++mt) {
        #pragma unroll
        for (int r = 0; r < 4; ++r) {
            const float b = bd[o0 + mt * 16 + hi * 4 + r];
            #pragma unroll
            for (int nt = 0; nt < 6; ++nt) acc[mt][nt][r] = b;
        }
    }

    #pragma unroll
    for (int kb = 0; kb < 2; ++kb) {
        bf16x8 bfr[6];
        #pragma unroll
        for (int nt = 0; nt < 6; ++nt)
            bfr[nt] = *reinterpret_cast<const bf16x8*>(&zbf[((kb * 6 + nt) * 64 + lane) * 8]);
        #pragma unroll
        for (int mt = 0; mt < 4; ++mt) {
            bf16x8 aw = *reinterpret_cast<const bf16x8*>(
                &WdB[(size_t)(o0 + mt * 16 + lo) * CIN + kb * 32 + hi * 8]);
            #pragma unroll
            for (int nt = 0; nt < 6; ++nt)
                acc[mt][nt] = __builtin_amdgcn_mfma_f32_16x16x32_bf16(aw, bfr[nt], acc[mt][nt], 0, 0, 0);
        }
    }

    // ---- store with ReLU (mask col >= 88) ----
    #pragma unroll
    for (int mt = 0; mt < 4; ++mt) {
        #pragma unroll
        for (int nt = 0; nt < 6; ++nt) {
            const int col = nt * 16 + lo;
            if (col < ZROW) {
                #pragma unroll
                for (int r = 0; r < 4; ++r) {
                    const int o = o0 + mt * 16 + hi * 4 + r;
                    out[((size_t)(n * COUT + o)) * (TT * VV) + (size_t)tb * ZROW + col]
                        = fmaxf(acc[mt][nt][r], 0.f);
                }
            }
        }
    }
}

// ===================== Kernel 2 (fp32 fallback, R11-benched) =====================
__global__ __launch_bounds__(384, 3) void agcn_out(
    const float* __restrict__ z, const float* __restrict__ Wd,
    const float* __restrict__ bd, float* __restrict__ out)
{
    const int bxx = blockIdx.x;
    const int tb  = (bxx & 7) * 16 + (bxx >> 3);
    const int n   = blockIdx.y;
    const int tid = threadIdx.x;

    __shared__ __align__(16) float Zs[CIN * ZS + 8];

    {
        const float* zsrc = z + (((size_t)n * NTB + tb) * CIN) * ZROW;
        for (int i4 = tid; i4 < (CIN * ZROW) / 4; i4 += 384) {
            float4 val = *reinterpret_cast<const float4*>(zsrc + (size_t)i4 * 4);
            int c = i4 / (ZROW / 4), r4 = (i4 % (ZROW / 4)) * 4;
            *reinterpret_cast<float4*>(&Zs[c * ZS + r4]) = val;
        }
    }
    __syncthreads();

    const int tx = tid % 11;
    const int ty = tid / 11;
    if (ty >= 32) return;
    const int o0   = ty * 8;
    const int col0 = tx * 8;

    float acc[8][8];
    #pragma unroll
    for (int j = 0; j < 8; ++j) {
        const float b = bd[o0 + j];
        #pragma unroll
        for (int m = 0; m < 8; ++m) acc[j][m] = b;
    }

    for (int kg = 0; kg < 16; ++kg) {
        const int k = kg * 4;
        float4 w[8];
        #pragma unroll
        for (int j = 0; j < 8; ++j)
            w[j] = *reinterpret_cast<const float4*>(&Wd[(size_t)(o0 + j) * CIN + k]);
        #pragma unroll
        for (int kk = 0; kk < 4; ++kk) {
            const float* zr = &Zs[(k + kk) * ZS + col0];
            float4 z0 = *reinterpret_cast<const float4*>(zr);
            float4 z1 = *reinterpret_cast<const float4*>(zr + 4);
            const float zv[8] = {z0.x, z0.y, z0.z, z0.w, z1.x, z1.y, z1.z, z1.w};
            #pragma unroll
            for (int j = 0; j < 8; ++j) {
                const float wj = (kk == 0) ? w[j].x : (kk == 1) ? w[j].y
                               : (kk == 2) ? w[j].z : w[j].w;
                #pragma unroll
                for (int m = 0; m < 8; ++m)
                    acc[j][m] += wj * zv[m];
            }
        }
    }

    #pragma unroll
    for (int j = 0; j < 8; ++j) {
        float* op = out + ((size_t)(n * COUT + o0 + j)) * (TT * VV) + (size_t)tb * ZROW + col0;
        float4 s0 = {fmaxf(acc[j][0], 0.f), fmaxf(acc[j][1], 0.f),
                     fmaxf(acc[j][2], 0.f), fmaxf(acc[j][3], 0.f)};
        float4 s1 = {fmaxf(acc[j][4], 0.f), fmaxf(acc[j][5], 0.f),
                     fmaxf(acc[j][6], 0.f), fmaxf(acc[j][7], 0.f)};
        *reinterpret_cast<float4*>(op)     = s0;
        *reinterpret_cast<float4*>(op + 4) = s1;
    }
}

// ===================== Fallback: verified R1 monolithic kernel =====================
__global__ __launch_bounds__(256, 4) void agcn_fused(
    const float* __restrict__ x, const float* __restrict__ A,
    const float* __restrict__ Wa, const float* __restrict__ ba,
    const float* __restrict__ Wb, const float* __restrict__ bb,
    const float* __restrict__ Wd, const float* __restrict__ bd,
    float* __restrict__ out)
{
    const int t   = blockIdx.x;
    const int n   = blockIdx.y;
    const int tid = threadIdx.x;
    __shared__ float smem[7424];
    float* xs   = smem;
    float* A1s  = smem + 1536;
    float* A2s  = smem + 3072;
    float* Ssf  = smem + 4608;
    float* Psf  = smem + 5136;
    float* outs = smem;
    float* zs   = smem + 5888;

    for (int f = tid; f < CIN * VV; f += 256) {
        int c = f / VV, v = f - c * VV;
        xs[c * PAD + v] = x[(((size_t)n * CIN + c) * TT + t) * VV + v];
    }
    {
        const float* Ag = A + (((size_t)n * TT + t) * VV) * VV;
        for (int f = tid; f < VV * VV; f += 256) {
            int u = f / VV, v = f - u * VV;
            Psf[u * PAD + v] = Ag[f] + 1e-6f;
        }
    }
    __syncthreads();
    {
        const int r  = tid & 63;
        const int q  = tid >> 6;
        const int us = (q * VV) >> 2;
        const int ue = ((q + 1) * VV) >> 2;
        const float* War = Wa + r * CIN;
        const float* Wbr = Wb + r * CIN;
        float acc1[6], acc2[6];
        const float b1 = ba[r], b2 = bb[r];
        #pragma unroll
        for (int u = 0; u < 6; ++u) { acc1[u] = b1; acc2[u] = b2; }
        for (int c = 0; c < CIN; c += 4) {
            float4 wa4 = *reinterpret_cast<const float4*>(War + c);
            float4 wb4 = *reinterpret_cast<const float4*>(Wbr + c);
            #pragma unroll
            for (int u = 0; u < 6; ++u) {
                float x0 = xs[(c + 0) * PAD + us + u];
                float x1 = xs[(c + 1) * PAD + us + u];
                float x2 = xs[(c + 2) * PAD + us + u];
                float x3 = xs[(c + 3) * PAD + us + u];
                acc1[u] += wa4.x * x0 + wa4.y * x1 + wa4.z * x2 + wa4.w * x3;
                acc2[u] += wb4.x * x0 + wb4.y * x1 + wb4.z * x2 + wb4.w * x3;
            }
        }
        #pragma unroll
        for (int u = 0; u < 6; ++u) {
            if (us + u < ue) {
                A1s[r * PAD + us + u] = acc1[u];
                A2s[r * PAD + us + u] = acc2[u];
            }
        }
    }
    __syncthreads();
    for (int f = tid; f < VV * VV; f += 256) {
        int u = f / VV, v = f - u * VV;
        float s = 0.f;
        for (int i = 0; i < CIN; ++i)
            s += A1s[i * PAD + u] * A2s[i * PAD + v];
        Ssf[u * PAD + v] = s * (1.0f / 64.0f);
    }
    __syncthreads();
    if (tid < VV) {
        const int v = tid;
        float m = -1e30f;
        #pragma unroll
        for (int u = 0; u < VV; ++u) m = fmaxf(m, Ssf[u * PAD + v]);
        float sum = 0.f;
        #pragma unroll
        for (int u = 0; u < VV; ++u) sum += __expf(Ssf[u * PAD + v] - m);
        const float inv = 1.0f / sum;
        #pragma unroll
        for (int u = 0; u < VV; ++u)
            Psf[u * PAD + v] += __expf(Ssf[u * PAD + v] - m) * inv;
    }
    __syncthreads();
    for (int f = tid; f < CIN * VV; f += 256) {
        int c = f / VV, u = f - c * VV;
        float s = 0.f;
        #pragma unroll
        for (int w = 0; w < VV; ++w)
            s += Psf[u * PAD + w] * xs[c * PAD + w];
        zs[c * PAD + u] = s;
    }
    __syncthreads();
    {
        const int o = tid;
        const float* Wr = Wd + o * CIN;
        float acc[VV];
        const float b = bd[o];
        #pragma unroll
        for (int u = 0; u < VV; ++u) acc[u] = b;
        for (int c = 0; c < CIN; c += 4) {
            float4 w4 = *reinterpret_cast<const float4*>(Wr + c);
            #pragma unroll
            for (int cc = 0; cc < 4; ++cc) {
                const float w = (cc == 0) ? w4.x : (cc == 1) ? w4.y : (cc == 2) ? w4.z : w4.w;
                const float* zr = zs + (c + cc) * PAD;
                #pragma unroll
                for (int uq = 0; uq < 5; ++uq) {
                    float4 zq = *reinterpret_cast<const float4*>(zr + uq * 4);
                    acc[uq * 4 + 0] += w * zq.x;
                    acc[uq * 4 + 1] += w * zq.y;
                    acc[uq * 4 + 2] += w * zq.z;
                    acc[uq * 4 + 3] += w * zq.w;
                }
                float2 zt = *reinterpret_cast<const float2*>(zr + 20);
                acc[20] += w * zt.x;
                acc[21] += w * zt.y;
            }
        }
        #pragma unroll
        for (int u = 0; u < VV; ++u)
            outs[o * OPAD + u] = fmaxf(acc[u], 0.f);
    }
    __syncthreads();
    {
        const size_t obase = (size_t)n * COUT * TT * VV + (size_t)t * VV;
        for (int f = tid; f < COUT * VV; f += 256) {
            int o = f / VV, u = f - o * VV;
            out[obase + (size_t)o * (TT * VV) + u] = outs[o * OPAD + u];
        }
    }
}

extern "C" void kernel_launch(void* const* d_in, const int* in_sizes, int n_in,
                              void* d_out, int out_size, void* d_ws, size_t ws_size,
                              hipStream_t stream) {
    const float* x  = (const float*)d_in[0];
    const float* A  = (const float*)d_in[1];
    const float* Wa = (const float*)d_in[2];
    const float* ba = (const float*)d_in[3];
    const float* Wb = (const float*)d_in[4];
    const float* bb = (const float*)d_in[5];
    const float* Wd = (const float*)d_in[6];
    const float* bd = (const float*)d_in[7];
    float* outp     = (float*)d_out;

    const size_t z_bytes   = (size_t)NB * TT * CIN * VV * sizeof(float);  // 46.1 MB (16B-aligned)
    const size_t wdb_bytes = (size_t)COUT * CIN * sizeof(ushort);         // 32 KB

    if (ws_size >= z_bytes + wdb_bytes) {
        float*  zws = (float*)d_ws;
        ushort* wdb = (ushort*)((char*)d_ws + z_bytes);
        wd_to_bf16<<<(COUT * CIN + 255) / 256, 256, 0, stream>>>(Wd, wdb);
        dim3 g1(TT, NB);
        agcn_attn<<<g1, 256, 0, stream>>>(x, A, Wa, ba, Wb, bb, zws);
        dim3 g2(NTB, NB);
        agcn_out_mfma<<<g2, 256, 0, stream>>>(zws, wdb, bd, outp);
    } else if (ws_size >= z_bytes) {
        float* zws = (float*)d_ws;
        dim3 g1(TT, NB);
        agcn_attn<<<g1, 256, 0, stream>>>(x, A, Wa, ba, Wb, bb, zws);
        dim3 g2(NTB, NB);
        agcn_out<<<g2, 384, 0, stream>>>(zws, Wd, bd, outp);
    } else {
        dim3 grid(TT, NB);
        agcn_fused<<<grid, 256, 0, stream>>>(x, A, Wa, ba, Wb, bb, Wd, bd, outp);
    }
}

// Round 13
// 121.864 us; speedup vs baseline: 2.4940x; 1.4490x over previous
//
#include <hip/hip_runtime.h>

#define NB    16
#define CIN   64
#define TT    512
#define VV    22
#define COUT  256
#define TBK   4            // t per z tile
#define NTB   (TT / TBK)   // 128
#define ZROW  (TBK * VV)   // 88
#define ZS    92           // k2 Zs row stride
#define XPAD  28           // k1 xs/Ss/Ps row stride
#define AT    68           // A1t/A2t row stride [u][r]
#define PAD   24           // fallback kernel pads
#define OPAD  23

typedef __attribute__((ext_vector_type(8))) short bf16x8;
typedef __attribute__((ext_vector_type(4))) float f32x4;

__device__ __forceinline__ ushort f2bf(float f) {   // RNE fp32 -> bf16
    unsigned u = __float_as_uint(f);
    return (ushort)((u + 0x7FFFu + ((u >> 16) & 1u)) >> 16);
}

// ===================== Prep: Wa/Wb/Wd -> bf16 (once, into ws tail) =====================
__global__ void w_to_bf16(const float* __restrict__ Wa, const float* __restrict__ Wb,
                          const float* __restrict__ Wd,
                          ushort* __restrict__ WaB, ushort* __restrict__ WbB,
                          ushort* __restrict__ WdB)
{
    int i = blockIdx.x * 256 + threadIdx.x;
    if (i < CIN * CIN)                 WaB[i] = f2bf(Wa[i]);
    else if (i < 2 * CIN * CIN)        WbB[i - CIN * CIN] = f2bf(Wb[i - CIN * CIN]);
    else if (i < 2 * CIN * CIN + COUT * CIN)
                                       WdB[i - 2 * CIN * CIN] = f2bf(Wd[i - 2 * CIN * CIN]);
}

// ===================== Kernel 1: attention + aggregate (P1 via MFMA) =====================
// P0/P2/P3/P4 byte-identical to the 138us-benched R8 kernel; P1 replaced by
// 32x mfma_f32_16x16x32_bf16 (M=128 stacked Wa|Wb, N=22->2 tiles, K=64->2 steps).
// A/B share the k-bijection k = kb*32 + (lane>>4)*8 + j (HW-validated in R12 k2).
// C/D: col = lane&15 (= u), row = (lane>>4)*4 + reg (= W-row) -> A1t[u][r] float4 stores.
__global__ __launch_bounds__(256, 6) void agcn_attn(
    const float* __restrict__ x, const float* __restrict__ A,
    const ushort* __restrict__ WaB, const float* __restrict__ ba,
    const ushort* __restrict__ WbB, const float* __restrict__ bb,
    float* __restrict__ z)
{
    const int bx = blockIdx.x;
    const int t  = (bx & 7) * 64 + (bx >> 3);   // XCD swizzle
    const int n  = blockIdx.y;
    const int tid = threadIdx.x;
    const int lane = tid & 63, wave = tid >> 6;
    const int hi = lane >> 4, lo = lane & 15;

    __shared__ __align__(16) float xs[CIN * XPAD];   // [c][v]
    __shared__ __align__(16) float A1t[VV * AT];     // [u][r]; xbf (4KB) overlays head
    __shared__ __align__(16) float A2t[VV * AT];     // [v][r]
    __shared__ __align__(16) float Ss[VV * XPAD];    // [u][v]
    __shared__ __align__(16) float Ps[VV * XPAD];    // [u][v]
    ushort* xbf = reinterpret_cast<ushort*>(A1t);    // [kb][nt][lane][j] 2*2*64*8

    // ---- P0: stage x tile and A tile ----
    for (int f = tid; f < CIN * VV; f += 256) {
        int c = f / VV, v = f - c * VV;
        xs[c * XPAD + v] = x[(((size_t)n * CIN + c) * TT + t) * VV + v];
    }
    {
        const float* Ag = A + (((size_t)n * TT + t) * VV) * VV;
        for (int f = tid; f < VV * VV; f += 256) {
            int u = f / VV, v = f - u * VV;
            Ps[u * XPAD + v] = Ag[f] + 1e-6f;
        }
    }
    __syncthreads();

    // ---- conv: xs -> bf16 B-fragments (one item per thread) ----
    {
        const int kb = tid >> 7, rem = tid & 127;
        const int nt = rem >> 6, ln = rem & 63;
        const int tv = nt * 16 + (ln & 15);
        const int c0 = kb * 32 + (ln >> 4) * 8;
        ushort tmp[8];
        if (tv < VV) {
            #pragma unroll
            for (int j = 0; j < 8; ++j) tmp[j] = f2bf(xs[(c0 + j) * XPAD + tv]);
        } else {
            #pragma unroll
            for (int j = 0; j < 8; ++j) tmp[j] = 0;
        }
        *reinterpret_cast<uint4*>(&xbf[(size_t)tid * 8]) = *reinterpret_cast<const uint4*>(tmp);
    }
    __syncthreads();

    // ---- P1 MFMA: wave w handles Wa rows w*16.. and Wb rows w*16.. ----
    f32x4 acc_a[2], acc_b[2];
    {
        const int m0 = wave * 16;
        #pragma unroll
        for (int r = 0; r < 4; ++r) {
            const float bav = ba[m0 + hi * 4 + r];
            const float bbv = bb[m0 + hi * 4 + r];
            acc_a[0][r] = bav; acc_a[1][r] = bav;
            acc_b[0][r] = bbv; acc_b[1][r] = bbv;
        }
        #pragma unroll
        for (int kb = 0; kb < 2; ++kb) {
            bf16x8 bf0 = *reinterpret_cast<const bf16x8*>(&xbf[((kb * 2 + 0) * 64 + lane) * 8]);
            bf16x8 bf1 = *reinterpret_cast<const bf16x8*>(&xbf[((kb * 2 + 1) * 64 + lane) * 8]);
            bf16x8 awa = *reinterpret_cast<const bf16x8*>(&WaB[(size_t)(m0 + lo) * CIN + kb * 32 + hi * 8]);
            bf16x8 awb = *reinterpret_cast<const bf16x8*>(&WbB[(size_t)(m0 + lo) * CIN + kb * 32 + hi * 8]);
            acc_a[0] = __builtin_amdgcn_mfma_f32_16x16x32_bf16(awa, bf0, acc_a[0], 0, 0, 0);
            acc_a[1] = __builtin_amdgcn_mfma_f32_16x16x32_bf16(awa, bf1, acc_a[1], 0, 0, 0);
            acc_b[0] = __builtin_amdgcn_mfma_f32_16x16x32_bf16(awb, bf0, acc_b[0], 0, 0, 0);
            acc_b[1] = __builtin_amdgcn_mfma_f32_16x16x32_bf16(awb, bf1, acc_b[1], 0, 0, 0);
        }
    }
    __syncthreads();   // all xbf reads complete before A1t overlay is written

    {
        const int m0 = wave * 16;
        #pragma unroll
        for (int nt = 0; nt < 2; ++nt) {
            const int u = nt * 16 + lo;
            if (u < VV) {
                float4 va = {acc_a[nt][0], acc_a[nt][1], acc_a[nt][2], acc_a[nt][3]};
                float4 vb = {acc_b[nt][0], acc_b[nt][1], acc_b[nt][2], acc_b[nt][3]};
                *reinterpret_cast<float4*>(&A1t[u * AT + m0 + hi * 4]) = va;
                *reinterpret_cast<float4*>(&A2t[u * AT + m0 + hi * 4]) = vb;
            }
        }
    }
    __syncthreads();

    // ---- P2: 2x2 register tiles (unchanged) ----
    if (tid < 121) {
        const int tu = tid / 11, tv = tid - tu * 11;
        const int u0 = tu * 2, v0 = tv * 2;
        const float4* a0 = reinterpret_cast<const float4*>(&A1t[u0 * AT]);
        const float4* a1 = reinterpret_cast<const float4*>(&A1t[(u0 + 1) * AT]);
        const float4* b0 = reinterpret_cast<const float4*>(&A2t[v0 * AT]);
        const float4* b1 = reinterpret_cast<const float4*>(&A2t[(v0 + 1) * AT]);
        float4 s00 = {0,0,0,0}, s01 = {0,0,0,0}, s10 = {0,0,0,0}, s11 = {0,0,0,0};
        #pragma unroll
        for (int ig = 0; ig < 16; ++ig) {
            float4 A0 = a0[ig], A1v = a1[ig], B0 = b0[ig], B1 = b1[ig];
            s00.x += A0.x*B0.x; s00.y += A0.y*B0.y; s00.z += A0.z*B0.z; s00.w += A0.w*B0.w;
            s01.x += A0.x*B1.x; s01.y += A0.y*B1.y; s01.z += A0.z*B1.z; s01.w += A0.w*B1.w;
            s10.x += A1v.x*B0.x; s10.y += A1v.y*B0.y; s10.z += A1v.z*B0.z; s10.w += A1v.w*B0.w;
            s11.x += A1v.x*B1.x; s11.y += A1v.y*B1.y; s11.z += A1v.z*B1.z; s11.w += A1v.w*B1.w;
        }
        const float k = 1.0f / 64.0f;
        Ss[u0 * XPAD + v0]           = ((s00.x+s00.y)+(s00.z+s00.w)) * k;
        Ss[u0 * XPAD + v0 + 1]       = ((s01.x+s01.y)+(s01.z+s01.w)) * k;
        Ss[(u0+1) * XPAD + v0]       = ((s10.x+s10.y)+(s10.z+s10.w)) * k;
        Ss[(u0+1) * XPAD + v0 + 1]   = ((s11.x+s11.y)+(s11.z+s11.w)) * k;
    }
    __syncthreads();

    // ---- P3: shuffle softmax (unchanged) ----
    if (tid < VV * 8) {
        const int v = tid >> 3, p = tid & 7;
        const int u1 = p + 8, u2 = p + 16;
        float s0 = Ss[p * XPAD + v];
        float s1 = Ss[u1 * XPAD + v];
        float s2 = (u2 < VV) ? Ss[u2 * XPAD + v] : -1e30f;
        float m = fmaxf(s0, fmaxf(s1, s2));
        m = fmaxf(m, __shfl_xor(m, 1, 8));
        m = fmaxf(m, __shfl_xor(m, 2, 8));
        m = fmaxf(m, __shfl_xor(m, 4, 8));
        float e0 = __expf(s0 - m), e1 = __expf(s1 - m);
        float e2 = (u2 < VV) ? __expf(s2 - m) : 0.f;
        float sum = e0 + e1 + e2;
        sum += __shfl_xor(sum, 1, 8);
        sum += __shfl_xor(sum, 2, 8);
        sum += __shfl_xor(sum, 4, 8);
        const float inv = 1.0f / sum;
        Ps[p * XPAD + v]  += e0 * inv;
        Ps[u1 * XPAD + v] += e1 * inv;
        if (u2 < VV) Ps[u2 * XPAD + v] += e2 * inv;
    }
    __syncthreads();

    // ---- P4: 2x2 tiles; z store TBK=4 layout (unchanged) ----
    {
        const int tb  = t >> 2;
        const int ttl = t & 3;
        float* zdst = z + (((size_t)n * NTB + tb) * CIN) * ZROW + ttl * VV;
        #pragma unroll
        for (int pass = 0; pass < 2; ++pass) {
            const int tt = pass * 256 + tid;
            if (tt < 352) {
                const int cp = tt / 11, up = tt - cp * 11;
                const int c0 = cp * 2, u0 = up * 2;
                const float4* x0 = reinterpret_cast<const float4*>(&xs[c0 * XPAD]);
                const float4* x1 = reinterpret_cast<const float4*>(&xs[(c0 + 1) * XPAD]);
                const float4* p0 = reinterpret_cast<const float4*>(&Ps[u0 * XPAD]);
                const float4* p1 = reinterpret_cast<const float4*>(&Ps[(u0 + 1) * XPAD]);
                float a00 = 0.f, a01 = 0.f, a10 = 0.f, a11 = 0.f;
                #pragma unroll
                for (int wg = 0; wg < 5; ++wg) {
                    float4 X0 = x0[wg], X1 = x1[wg], P0 = p0[wg], P1 = p1[wg];
                    a00 += P0.x*X0.x + P0.y*X0.y + P0.z*X0.z + P0.w*X0.w;
                    a01 += P1.x*X0.x + P1.y*X0.y + P1.z*X0.z + P1.w*X0.w;
                    a10 += P0.x*X1.x + P0.y*X1.y + P0.z*X1.z + P0.w*X1.w;
                    a11 += P1.x*X1.x + P1.y*X1.y + P1.z*X1.z + P1.w*X1.w;
                }
                {
                    float xa = xs[c0*XPAD+20], xb = xs[c0*XPAD+21];
                    float xc = xs[(c0+1)*XPAD+20], xd = xs[(c0+1)*XPAD+21];
                    float pa = Ps[u0*XPAD+20], pb = Ps[u0*XPAD+21];
                    float pc = Ps[(u0+1)*XPAD+20], pd = Ps[(u0+1)*XPAD+21];
                    a00 += pa*xa + pb*xb;  a01 += pc*xa + pd*xb;
                    a10 += pa*xc + pb*xd;  a11 += pc*xc + pd*xd;
                }
                float2 r0 = {a00, a01}, r1 = {a10, a11};
                *reinterpret_cast<float2*>(&zdst[(size_t)c0 * ZROW + u0]) = r0;
                *reinterpret_cast<float2*>(&zdst[(size_t)(c0 + 1) * ZROW + u0]) = r1;
            }
        }
    }
}

// ===================== Kernel 1 (fp32 fallback, R8/R10-benched) =====================
__global__ __launch_bounds__(256, 6) void agcn_attn_f32(
    const float* __restrict__ x, const float* __restrict__ A,
    const float* __restrict__ Wa, const float* __restrict__ ba,
    const float* __restrict__ Wb, const float* __restrict__ bb,
    float* __restrict__ z)
{
    const int bx = blockIdx.x;
    const int t  = (bx & 7) * 64 + (bx >> 3);
    const int n  = blockIdx.y;
    const int tid = threadIdx.x;

    __shared__ __align__(16) float xs[CIN * XPAD];
    __shared__ __align__(16) float A1t[VV * AT];
    __shared__ __align__(16) float A2t[VV * AT];
    __shared__ __align__(16) float Ss[VV * XPAD];
    __shared__ __align__(16) float Ps[VV * XPAD];

    for (int f = tid; f < CIN * VV; f += 256) {
        int c = f / VV, v = f - c * VV;
        xs[c * XPAD + v] = x[(((size_t)n * CIN + c) * TT + t) * VV + v];
    }
    {
        const float* Ag = A + (((size_t)n * TT + t) * VV) * VV;
        for (int f = tid; f < VV * VV; f += 256) {
            int u = f / VV, v = f - u * VV;
            Ps[u * XPAD + v] = Ag[f] + 1e-6f;
        }
    }
    __syncthreads();
    {
        const int r2 = tid >> 3;
        const int q6 = tid & 7;
        if (q6 < 6) {
            const int us = q6 * 4;
            const int r0 = r2 * 2;
            const float* Wa0 = Wa + (size_t)r0 * CIN;
            const float* Wa1 = Wa0 + CIN;
            const float* Wb0 = Wb + (size_t)r0 * CIN;
            const float* Wb1 = Wb0 + CIN;
            float acc[4][4];
            {
                const float ba0 = ba[r0], ba1 = ba[r0 + 1];
                const float bb0 = bb[r0], bb1 = bb[r0 + 1];
                #pragma unroll
                for (int j = 0; j < 4; ++j) {
                    acc[0][j] = ba0; acc[1][j] = ba1;
                    acc[2][j] = bb0; acc[3][j] = bb1;
                }
            }
            for (int cg = 0; cg < 16; ++cg) {
                float4 wa0 = *reinterpret_cast<const float4*>(Wa0 + cg * 4);
                float4 wa1 = *reinterpret_cast<const float4*>(Wa1 + cg * 4);
                float4 wb0 = *reinterpret_cast<const float4*>(Wb0 + cg * 4);
                float4 wb1 = *reinterpret_cast<const float4*>(Wb1 + cg * 4);
                const float wv0[4] = {wa0.x, wa0.y, wa0.z, wa0.w};
                const float wv1[4] = {wa1.x, wa1.y, wa1.z, wa1.w};
                const float wv2[4] = {wb0.x, wb0.y, wb0.z, wb0.w};
                const float wv3[4] = {wb1.x, wb1.y, wb1.z, wb1.w};
                #pragma unroll
                for (int c = 0; c < 4; ++c) {
                    float4 xv = *reinterpret_cast<const float4*>(&xs[(cg * 4 + c) * XPAD + us]);
                    const float xj[4] = {xv.x, xv.y, xv.z, xv.w};
                    #pragma unroll
                    for (int j = 0; j < 4; ++j) {
                        acc[0][j] += wv0[c] * xj[j];
                        acc[1][j] += wv1[c] * xj[j];
                        acc[2][j] += wv2[c] * xj[j];
                        acc[3][j] += wv3[c] * xj[j];
                    }
                }
            }
            #pragma unroll
            for (int j = 0; j < 4; ++j) {
                if (us + j < VV) {
                    A1t[(us + j) * AT + r0]     = acc[0][j];
                    A1t[(us + j) * AT + r0 + 1] = acc[1][j];
                    A2t[(us + j) * AT + r0]     = acc[2][j];
                    A2t[(us + j) * AT + r0 + 1] = acc[3][j];
                }
            }
        }
    }
    __syncthreads();
    if (tid < 121) {
        const int tu = tid / 11, tv = tid - tu * 11;
        const int u0 = tu * 2, v0 = tv * 2;
        const float4* a0 = reinterpret_cast<const float4*>(&A1t[u0 * AT]);
        const float4* a1 = reinterpret_cast<const float4*>(&A1t[(u0 + 1) * AT]);
        const float4* b0 = reinterpret_cast<const float4*>(&A2t[v0 * AT]);
        const float4* b1 = reinterpret_cast<const float4*>(&A2t[(v0 + 1) * AT]);
        float4 s00 = {0,0,0,0}, s01 = {0,0,0,0}, s10 = {0,0,0,0}, s11 = {0,0,0,0};
        #pragma unroll
        for (int ig = 0; ig < 16; ++ig) {
            float4 A0 = a0[ig], A1v = a1[ig], B0 = b0[ig], B1 = b1[ig];
            s00.x += A0.x*B0.x; s00.y += A0.y*B0.y; s00.z += A0.z*B0.z; s00.w += A0.w*B0.w;
            s01.x += A0.x*B1.x; s01.y += A0.y*B1.y; s01.z += A0.z*B1.z; s01.w += A0.w*B1.w;
            s10.x += A1v.x*B0.x; s10.y += A1v.y*B0.y; s10.z += A1v.z*B0.z; s10.w += A1v.w*B0.w;
            s11.x += A1v.x*B1.x; s11.y += A1v.y*B1.y; s11.z += A1v.z*B1.z; s11.w += A1v.w*B1.w;
        }
        const float k = 1.0f / 64.0f;
        Ss[u0 * XPAD + v0]           = ((s00.x+s00.y)+(s00.z+s00.w)) * k;
        Ss[u0 * XPAD + v0 + 1]       = ((s01.x+s01.y)+(s01.z+s01.w)) * k;
        Ss[(u0+1) * XPAD + v0]       = ((s10.x+s10.y)+(s10.z+s10.w)) * k;
        Ss[(u0+1) * XPAD + v0 + 1]   = ((s11.x+s11.y)+(s11.z+s11.w)) * k;
    }
    __syncthreads();
    if (tid < VV * 8) {
        const int v = tid >> 3, p = tid & 7;
        const int u1 = p + 8, u2 = p + 16;
        float s0 = Ss[p * XPAD + v];
        float s1 = Ss[u1 * XPAD + v];
        float s2 = (u2 < VV) ? Ss[u2 * XPAD + v] : -1e30f;
        float m = fmaxf(s0, fmaxf(s1, s2));
        m = fmaxf(m, __shfl_xor(m, 1, 8));
        m = fmaxf(m, __shfl_xor(m, 2, 8));
        m = fmaxf(m, __shfl_xor(m, 4, 8));
        float e0 = __expf(s0 - m), e1 = __expf(s1 - m);
        float e2 = (u2 < VV) ? __expf(s2 - m) : 0.f;
        float sum = e0 + e1 + e2;
        sum += __shfl_xor(sum, 1, 8);
        sum += __shfl_xor(sum, 2, 8);
        sum += __shfl_xor(sum, 4, 8);
        const float inv = 1.0f / sum;
        Ps[p * XPAD + v]  += e0 * inv;
        Ps[u1 * XPAD + v] += e1 * inv;
        if (u2 < VV) Ps[u2 * XPAD + v] += e2 * inv;
    }
    __syncthreads();
    {
        const int tb  = t >> 2;
        const int ttl = t & 3;
        float* zdst = z + (((size_t)n * NTB + tb) * CIN) * ZROW + ttl * VV;
        #pragma unroll
        for (int pass = 0; pass < 2; ++pass) {
            const int tt = pass * 256 + tid;
            if (tt < 352) {
                const int cp = tt / 11, up = tt - cp * 11;
                const int c0 = cp * 2, u0 = up * 2;
                const float4* x0 = reinterpret_cast<const float4*>(&xs[c0 * XPAD]);
                const float4* x1 = reinterpret_cast<const float4*>(&xs[(c0 + 1) * XPAD]);
                const float4* p0 = reinterpret_cast<const float4*>(&Ps[u0 * XPAD]);
                const float4* p1 = reinterpret_cast<const float4*>(&Ps[(u0 + 1) * XPAD]);
                float a00 = 0.f, a01 = 0.f, a10 = 0.f, a11 = 0.f;
                #pragma unroll
                for (int wg = 0; wg < 5; ++wg) {
                    float4 X0 = x0[wg], X1 = x1[wg], P0 = p0[wg], P1 = p1[wg];
                    a00 += P0.x*X0.x + P0.y*X0.y + P0.z*X0.z + P0.w*X0.w;
                    a01 += P1.x*X0.x + P1.y*X0.y + P1.z*X0.z + P1.w*X0.w;
                    a10 += P0.x*X1.x + P0.y*X1.y + P0.z*X1.z + P0.w*X1.w;
                    a11 += P1.x*X1.x + P1.y*X1.y + P1.z*X1.z + P1.w*X1.w;
                }
                {
                    float xa = xs[c0*XPAD+20], xb = xs[c0*XPAD+21];
                    float xc = xs[(c0+1)*XPAD+20], xd = xs[(c0+1)*XPAD+21];
                    float pa = Ps[u0*XPAD+20], pb = Ps[u0*XPAD+21];
                    float pc = Ps[(u0+1)*XPAD+20], pd = Ps[(u0+1)*XPAD+21];
                    a00 += pa*xa + pb*xb;  a01 += pc*xa + pd*xb;
                    a10 += pa*xc + pb*xd;  a11 += pc*xc + pd*xd;
                }
                float2 r0 = {a00, a01}, r1 = {a10, a11};
                *reinterpret_cast<float2*>(&zdst[(size_t)c0 * ZROW + u0]) = r0;
                *reinterpret_cast<float2*>(&zdst[(size_t)(c0 + 1) * ZROW + u0]) = r1;
            }
        }
    }
}

// ===================== Kernel 2 (MFMA, R12-benched: ~38us, HBM floor) =====================
__global__ __launch_bounds__(256, 3) void agcn_out_mfma(
    const float* __restrict__ z, const ushort* __restrict__ WdB,
    const float* __restrict__ bd, float* __restrict__ out)
{
    const int bxx = blockIdx.x;
    const int tb  = (bxx & 7) * 16 + (bxx >> 3);
    const int n   = blockIdx.y;
    const int tid = threadIdx.x;
    const int lane = tid & 63, wave = tid >> 6;
    const int hi = lane >> 4, lo = lane & 15;

    __shared__ __align__(16) float  Zs[CIN * ZS + 8];
    __shared__ __align__(16) ushort zbf[2 * 6 * 64 * 8];

    {
        const float* zsrc = z + (((size_t)n * NTB + tb) * CIN) * ZROW;
        for (int i4 = tid; i4 < (CIN * ZROW) / 4; i4 += 256) {
            float4 val = *reinterpret_cast<const float4*>(zsrc + (size_t)i4 * 4);
            int c = i4 / (ZROW / 4), r4 = (i4 % (ZROW / 4)) * 4;
            *reinterpret_cast<float4*>(&Zs[c * ZS + r4]) = val;
        }
    }
    __syncthreads();

    for (int it = tid; it < 768; it += 256) {
        const int kb  = it / 384;
        const int rem = it - kb * 384;
        const int nt  = rem >> 6;
        const int ln  = rem & 63;
        const int tv  = nt * 16 + (ln & 15);
        const int c0  = kb * 32 + (ln >> 4) * 8;
        ushort tmp[8];
        if (tv < ZROW) {
            #pragma unroll
            for (int j = 0; j < 8; ++j) tmp[j] = f2bf(Zs[(c0 + j) * ZS + tv]);
        } else {
            #pragma unroll
            for (int j = 0; j < 8; ++j) tmp[j] = 0;
        }
        *reinterpret_cast<uint4*>(&zbf[(size_t)it * 8]) = *reinterpret_cast<const uint4*>(tmp);
    }
    __syncthreads();

    const int o0 = wave * 64;
    f32x4 acc[4][6];
    #pragma unroll
    for (int mt = 0; mt < 4; ++mt) {
        #pragma unroll
        for (int r = 0; r < 4; ++r) {
            const float b = bd[o0 + mt * 16 + hi * 4 + r];
            #pragma unroll
            for (int nt = 0; nt < 6; ++nt) acc[mt][nt][r] = b;
        }
    }

    #pragma unroll
    for (int kb = 0; kb < 2; ++kb) {
        bf16x8 bfr[6];
        #pragma unroll
        for (int nt = 0; nt < 6; ++nt)
            bfr[nt] = *reinterpret_cast<const bf16x8*>(&zbf[((kb * 6 + nt) * 64 + lane) * 8]);
        #pragma unroll
        for (int mt = 0; mt < 4; ++mt) {
            bf16x8 aw = *reinterpret_cast<const bf16x8*>(
                &WdB[(size_t)(o0 + mt * 16 + lo) * CIN + kb * 32 + hi * 8]);
            #pragma unroll
            for (int nt = 0; nt < 6; ++nt)
                acc[mt][nt] = __builtin_amdgcn_mfma_f32_16x16x32_bf16(aw, bfr[nt], acc[mt][nt], 0, 0, 0);
        }
    }

    #pragma unroll
    for (int mt = 0; mt < 4; ++mt) {
        #pragma unroll
        for (int nt = 0; nt < 6; ++nt) {
            const int col = nt * 16 + lo;
            if (col < ZROW) {
                #pragma unroll
                for (int r = 0; r < 4; ++r) {
                    const int o = o0 + mt * 16 + hi * 4 + r;
                    out[((size_t)(n * COUT + o)) * (TT * VV) + (size_t)tb * ZROW + col]
                        = fmaxf(acc[mt][nt][r], 0.f);
                }
            }
        }
    }
}

// ===================== Kernel 2 (fp32 fallback, R11-benched) =====================
__global__ __launch_bounds__(384, 3) void agcn_out(
    const float* __restrict__ z, const float* __restrict__ Wd,
    const float* __restrict__ bd, float* __restrict__ out)
{
    const int bxx = blockIdx.x;
    const int tb  = (bxx & 7) * 16 + (bxx >> 3);
    const int n   = blockIdx.y;
    const int tid = threadIdx.x;

    __shared__ __align__(16) float Zs[CIN * ZS + 8];

    {
        const float* zsrc = z + (((size_t)n * NTB + tb) * CIN) * ZROW;
        for (int i4 = tid; i4 < (CIN * ZROW) / 4; i4 += 384) {
            float4 val = *reinterpret_cast<const float4*>(zsrc + (size_t)i4 * 4);
            int c = i4 / (ZROW / 4), r4 = (i4 % (ZROW / 4)) * 4;
            *reinterpret_cast<float4*>(&Zs[c * ZS + r4]) = val;
        }
    }
    __syncthreads();

    const int tx = tid % 11;
    const int ty = tid / 11;
    if (ty >= 32) return;
    const int o0   = ty * 8;
    const int col0 = tx * 8;

    float acc[8][8];
    #pragma unroll
    for (int j = 0; j < 8; ++j) {
        const float b = bd[o0 + j];
        #pragma unroll
        for (int m = 0; m < 8; ++m) acc[j][m] = b;
    }

    for (int kg = 0; kg < 16; ++kg) {
        const int k = kg * 4;
        float4 w[8];
        #pragma unroll
        for (int j = 0; j < 8; ++j)
            w[j] = *reinterpret_cast<const float4*>(&Wd[(size_t)(o0 + j) * CIN + k]);
        #pragma unroll
        for (int kk = 0; kk < 4; ++kk) {
            const float* zr = &Zs[(k + kk) * ZS + col0];
            float4 z0 = *reinterpret_cast<const float4*>(zr);
            float4 z1 = *reinterpret_cast<const float4*>(zr + 4);
            const float zv[8] = {z0.x, z0.y, z0.z, z0.w, z1.x, z1.y, z1.z, z1.w};
            #pragma unroll
            for (int j = 0; j < 8; ++j) {
                const float wj = (kk == 0) ? w[j].x : (kk == 1) ? w[j].y
                               : (kk == 2) ? w[j].z : w[j].w;
                #pragma unroll
                for (int m = 0; m < 8; ++m)
                    acc[j][m] += wj * zv[m];
            }
        }
    }

    #pragma unroll
    for (int j = 0; j < 8; ++j) {
        float* op = out + ((size_t)(n * COUT + o0 + j)) * (TT * VV) + (size_t)tb * ZROW + col0;
        float4 s0 = {fmaxf(acc[j][0], 0.f), fmaxf(acc[j][1], 0.f),
                     fmaxf(acc[j][2], 0.f), fmaxf(acc[j][3], 0.f)};
        float4 s1 = {fmaxf(acc[j][4], 0.f), fmaxf(acc[j][5], 0.f),
                     fmaxf(acc[j][6], 0.f), fmaxf(acc[j][7], 0.f)};
        *reinterpret_cast<float4*>(op)     = s0;
        *reinterpret_cast<float4*>(op + 4) = s1;
    }
}

// ===================== Fallback: verified R1 monolithic kernel =====================
__global__ __launch_bounds__(256, 4) void agcn_fused(
    const float* __restrict__ x, const float* __restrict__ A,
    const float* __restrict__ Wa, const float* __restrict__ ba,
    const float* __restrict__ Wb, const float* __restrict__ bb,
    const float* __restrict__ Wd, const float* __restrict__ bd,
    float* __restrict__ out)
{
    const int t   = blockIdx.x;
    const int n   = blockIdx.y;
    const int tid = threadIdx.x;
    __shared__ float smem[7424];
    float* xs   = smem;
    float* A1s  = smem + 1536;
    float* A2s  = smem + 3072;
    float* Ssf  = smem + 4608;
    float* Psf  = smem + 5136;
    float* outs = smem;
    float* zs   = smem + 5888;

    for (int f = tid; f < CIN * VV; f += 256) {
        int c = f / VV, v = f - c * VV;
        xs[c * PAD + v] = x[(((size_t)n * CIN + c) * TT + t) * VV + v];
    }
    {
        const float* Ag = A + (((size_t)n * TT + t) * VV) * VV;
        for (int f = tid; f < VV * VV; f += 256) {
            int u = f / VV, v = f - u * VV;
            Psf[u * PAD + v] = Ag[f] + 1e-6f;
        }
    }
    __syncthreads();
    {
        const int r  = tid & 63;
        const int q  = tid >> 6;
        const int us = (q * VV) >> 2;
        const int ue = ((q + 1) * VV) >> 2;
        const float* War = Wa + r * CIN;
        const float* Wbr = Wb + r * CIN;
        float acc1[6], acc2[6];
        const float b1 = ba[r], b2 = bb[r];
        #pragma unroll
        for (int u = 0; u < 6; ++u) { acc1[u] = b1; acc2[u] = b2; }
        for (int c = 0; c < CIN; c += 4) {
            float4 wa4 = *reinterpret_cast<const float4*>(War + c);
            float4 wb4 = *reinterpret_cast<const float4*>(Wbr + c);
            #pragma unroll
            for (int u = 0; u < 6; ++u) {
                float x0 = xs[(c + 0) * PAD + us + u];
                float x1 = xs[(c + 1) * PAD + us + u];
                float x2 = xs[(c + 2) * PAD + us + u];
                float x3 = xs[(c + 3) * PAD + us + u];
                acc1[u] += wa4.x * x0 + wa4.y * x1 + wa4.z * x2 + wa4.w * x3;
                acc2[u] += wb4.x * x0 + wb4.y * x1 + wb4.z * x2 + wb4.w * x3;
            }
        }
        #pragma unroll
        for (int u = 0; u < 6; ++u) {
            if (us + u < ue) {
                A1s[r * PAD + us + u] = acc1[u];
                A2s[r * PAD + us + u] = acc2[u];
            }
        }
    }
    __syncthreads();
    for (int f = tid; f < VV * VV; f += 256) {
        int u = f / VV, v = f - u * VV;
        float s = 0.f;
        for (int i = 0; i < CIN; ++i)
            s += A1s[i * PAD + u] * A2s[i * PAD + v];
        Ssf[u * PAD + v] = s * (1.0f / 64.0f);
    }
    __syncthreads();
    if (tid < VV) {
        const int v = tid;
        float m = -1e30f;
        #pragma unroll
        for (int u = 0; u < VV; ++u) m = fmaxf(m, Ssf[u * PAD + v]);
        float sum = 0.f;
        #pragma unroll
        for (int u = 0; u < VV; ++u) sum += __expf(Ssf[u * PAD + v] - m);
        const float inv = 1.0f / sum;
        #pragma unroll
        for (int u = 0; u < VV; ++u)
            Psf[u * PAD + v] += __expf(Ssf[u * PAD + v] - m) * inv;
    }
    __syncthreads();
    for (int f = tid; f < CIN * VV; f += 256) {
        int c = f / VV, u = f - c * VV;
        float s = 0.f;
        #pragma unroll
        for (int w = 0; w < VV; ++w)
            s += Psf[u * PAD + w] * xs[c * PAD + w];
        zs[c * PAD + u] = s;
    }
    __syncthreads();
    {
        const int o = tid;
        const float* Wr = Wd + o * CIN;
        float acc[VV];
        const float b = bd[o];
        #pragma unroll
        for (int u = 0; u < VV; ++u) acc[u] = b;
        for (int c = 0; c < CIN; c += 4) {
            float4 w4 = *reinterpret_cast<const float4*>(Wr + c);
            #pragma unroll
            for (int cc = 0; cc < 4; ++cc) {
                const float w = (cc == 0) ? w4.x : (cc == 1) ? w4.y : (cc == 2) ? w4.z : w4.w;
                const float* zr = zs + (c + cc) * PAD;
                #pragma unroll
                for (int uq = 0; uq < 5; ++uq) {
                    float4 zq = *reinterpret_cast<const float4*>(zr + uq * 4);
                    acc[uq * 4 + 0] += w * zq.x;
                    acc[uq * 4 + 1] += w * zq.y;
                    acc[uq * 4 + 2] += w * zq.z;
                    acc[uq * 4 + 3] += w * zq.w;
                }
                float2 zt = *reinterpret_cast<const float2*>(zr + 20);
                acc[20] += w * zt.x;
                acc[21] += w * zt.y;
            }
        }
        #pragma unroll
        for (int u = 0; u < VV; ++u)
            outs[o * OPAD + u] = fmaxf(acc[u], 0.f);
    }
    __syncthreads();
    {
        const size_t obase = (size_t)n * COUT * TT * VV + (size_t)t * VV;
        for (int f = tid; f < COUT * VV; f += 256) {
            int o = f / VV, u = f - o * VV;
            out[obase + (size_t)o * (TT * VV) + u] = outs[o * OPAD + u];
        }
    }
}

extern "C" void kernel_launch(void* const* d_in, const int* in_sizes, int n_in,
                              void* d_out, int out_size, void* d_ws, size_t ws_size,
                              hipStream_t stream) {
    const float* x  = (const float*)d_in[0];
    const float* A  = (const float*)d_in[1];
    const float* Wa = (const float*)d_in[2];
    const float* ba = (const float*)d_in[3];
    const float* Wb = (const float*)d_in[4];
    const float* bb = (const float*)d_in[5];
    const float* Wd = (const float*)d_in[6];
    const float* bd = (const float*)d_in[7];
    float* outp     = (float*)d_out;

    const size_t z_bytes   = (size_t)NB * TT * CIN * VV * sizeof(float);  // 46.1 MB
    const size_t wdb_bytes = (size_t)COUT * CIN * sizeof(ushort);         // 32 KB
    const size_t wab_bytes = (size_t)CIN * CIN * sizeof(ushort);          // 8 KB each

    if (ws_size >= z_bytes + wdb_bytes + 2 * wab_bytes) {
        float*  zws = (float*)d_ws;
        ushort* wdb = (ushort*)((char*)d_ws + z_bytes);
        ushort* wab = (ushort*)((char*)d_ws + z_bytes + wdb_bytes);
        ushort* wbb = (ushort*)((char*)d_ws + z_bytes + wdb_bytes + wab_bytes);
        const int prep_items = 2 * CIN * CIN + COUT * CIN;   // 24576
        w_to_bf16<<<(prep_items + 255) / 256, 256, 0, stream>>>(Wa, Wb, Wd, wab, wbb, wdb);
        dim3 g1(TT, NB);
        agcn_attn<<<g1, 256, 0, stream>>>(x, A, wab, ba, wbb, bb, zws);
        dim3 g2(NTB, NB);
        agcn_out_mfma<<<g2, 256, 0, stream>>>(zws, wdb, bd, outp);
    } else if (ws_size >= z_bytes) {
        float* zws = (float*)d_ws;
        dim3 g1(TT, NB);
        agcn_attn_f32<<<g1, 256, 0, stream>>>(x, A, Wa, ba, Wb, bb, zws);
        dim3 g2(NTB, NB);
        agcn_out<<<g2, 384, 0, stream>>>(zws, Wd, bd, outp);
    } else {
        dim3 grid(TT, NB);
        agcn_fused<<<grid, 256, 0, stream>>>(x, A, Wa, ba, Wb, bb, Wd, bd, outp);
    }
}

// Round 14
// 121.830 us; speedup vs baseline: 2.4947x; 1.0003x over previous
//
#include <hip/hip_runtime.h>

#define NB    16
#define CIN   64
#define TT    512
#define VV    22
#define COUT  256
#define TBK   4            // t per z tile
#define NTB   (TT / TBK)   // 128
#define ZROW  (TBK * VV)   // 88
#define ZS    92           // k2 Zs row stride
#define XPAD  28           // k1 xs/Ss/Ps row stride
#define AT    68           // legacy region size for A1t/A2t (reused as bf16 frag space)
#define PAD   24           // fallback kernel pads
#define OPAD  23

typedef __attribute__((ext_vector_type(8))) short bf16x8;
typedef __attribute__((ext_vector_type(4))) float f32x4;

__device__ __forceinline__ ushort f2bf(float f) {   // RNE fp32 -> bf16
    unsigned u = __float_as_uint(f);
    return (ushort)((u + 0x7FFFu + ((u >> 16) & 1u)) >> 16);
}
__device__ __forceinline__ uint pk2(float a, float b) {
    return (uint)f2bf(a) | ((uint)f2bf(b) << 16);
}

// ===================== Prep: Wa/Wb/Wd -> bf16 (once, into ws tail) =====================
__global__ void w_to_bf16(const float* __restrict__ Wa, const float* __restrict__ Wb,
                          const float* __restrict__ Wd,
                          ushort* __restrict__ WaB, ushort* __restrict__ WbB,
                          ushort* __restrict__ WdB)
{
    int i = blockIdx.x * 256 + threadIdx.x;
    if (i < CIN * CIN)                 WaB[i] = f2bf(Wa[i]);
    else if (i < 2 * CIN * CIN)        WbB[i - CIN * CIN] = f2bf(Wb[i - CIN * CIN]);
    else if (i < 2 * CIN * CIN + COUT * CIN)
                                       WdB[i - 2 * CIN * CIN] = f2bf(Wd[i - 2 * CIN * CIN]);
}

// ===================== Kernel 1: attention + aggregate (P1+P2+P4 via MFMA) =====================
// Fragment conventions (HW-validated in R12/R13):
//   A-operand: lane l holds A[row = tile*16 + (l&15)][k = kb*32 + (l>>4)*8 + j]
//   B-operand: lane l holds B[k = kb*32 + (l>>4)*8 + j][col = tile*16 + (l&15)]
//   C/D:       col = l&15, row = (l>>4)*4 + reg
// A and B share the same k-bijection in every GEMM -> results exact under HW k-permutation.
__global__ __launch_bounds__(256, 6) void agcn_attn(
    const float* __restrict__ x, const float* __restrict__ A,
    const ushort* __restrict__ WaB, const float* __restrict__ ba,
    const ushort* __restrict__ WbB, const float* __restrict__ bb,
    float* __restrict__ z)
{
    const int bx = blockIdx.x;
    const int t  = (bx & 7) * 64 + (bx >> 3);   // XCD swizzle
    const int n  = blockIdx.y;
    const int tid = threadIdx.x;
    const int lane = tid & 63, wave = tid >> 6;
    const int hi = lane >> 4, lo = lane & 15;

    __shared__ __align__(16) float xs[CIN * XPAD];   // [c][v] fp32 (live whole kernel)
    __shared__ __align__(16) float A1t[VV * AT];     // region: xbf -> A1bf -> xabf
    __shared__ __align__(16) float A2t[VV * AT];     // region: A2bf -> pbf
    __shared__ __align__(16) float Ss[VV * XPAD];    // [u][v] scores fp32
    __shared__ __align__(16) float Ps[VV * XPAD];    // [u][v] A + softmax fp32
    ushort* xbf  = reinterpret_cast<ushort*>(A1t);   // P1 B-frags  [kb][nt][lane][j] (4KB)
    ushort* A1bf = reinterpret_cast<ushort*>(A1t);   // P2 A-frags  [u<32][i<64]      (4KB)
    ushort* A2bf = reinterpret_cast<ushort*>(A2t);   // P2 B-frags  [v<32][i<64]      (4KB)
    ushort* xabf = reinterpret_cast<ushort*>(A1t);   // P4 A-frags  [mt<4][lane][j]   (4KB)
    ushort* pbf  = reinterpret_cast<ushort*>(A2t);   // P4 B-frags  [nt<2][lane][j]   (2KB)

    // ---- P0: stage x tile and A tile ----
    for (int f = tid; f < CIN * VV; f += 256) {
        int c = f / VV, v = f - c * VV;
        xs[c * XPAD + v] = x[(((size_t)n * CIN + c) * TT + t) * VV + v];
    }
    {
        const float* Ag = A + (((size_t)n * TT + t) * VV) * VV;
        for (int f = tid; f < VV * VV; f += 256) {
            int u = f / VV, v = f - u * VV;
            Ps[u * XPAD + v] = Ag[f] + 1e-6f;
        }
    }
    __syncthreads();

    // ---- conv1: xs -> bf16 B-frags for P1 (one item/thread) ----
    {
        const int kb = tid >> 7, rem = tid & 127;
        const int nt = rem >> 6, ln = rem & 63;
        const int tv = nt * 16 + (ln & 15);
        const int c0 = kb * 32 + (ln >> 4) * 8;
        ushort tmp[8];
        if (tv < VV) {
            #pragma unroll
            for (int j = 0; j < 8; ++j) tmp[j] = f2bf(xs[(c0 + j) * XPAD + tv]);
        } else {
            #pragma unroll
            for (int j = 0; j < 8; ++j) tmp[j] = 0;
        }
        *reinterpret_cast<uint4*>(&xbf[(size_t)tid * 8]) = *reinterpret_cast<const uint4*>(tmp);
    }
    __syncthreads();

    // ---- P1 MFMA: A1 = Wa@X + ba, A2 = Wb@X + bb (wave w: W-rows w*16..w*16+15) ----
    f32x4 acc_a[2], acc_b[2];
    {
        const int m0 = wave * 16;
        #pragma unroll
        for (int r = 0; r < 4; ++r) {
            const float bav = ba[m0 + hi * 4 + r];
            const float bbv = bb[m0 + hi * 4 + r];
            acc_a[0][r] = bav; acc_a[1][r] = bav;
            acc_b[0][r] = bbv; acc_b[1][r] = bbv;
        }
        #pragma unroll
        for (int kb = 0; kb < 2; ++kb) {
            bf16x8 bf0 = *reinterpret_cast<const bf16x8*>(&xbf[((kb * 2 + 0) * 64 + lane) * 8]);
            bf16x8 bf1 = *reinterpret_cast<const bf16x8*>(&xbf[((kb * 2 + 1) * 64 + lane) * 8]);
            bf16x8 awa = *reinterpret_cast<const bf16x8*>(&WaB[(size_t)(m0 + lo) * CIN + kb * 32 + hi * 8]);
            bf16x8 awb = *reinterpret_cast<const bf16x8*>(&WbB[(size_t)(m0 + lo) * CIN + kb * 32 + hi * 8]);
            acc_a[0] = __builtin_amdgcn_mfma_f32_16x16x32_bf16(awa, bf0, acc_a[0], 0, 0, 0);
            acc_a[1] = __builtin_amdgcn_mfma_f32_16x16x32_bf16(awa, bf1, acc_a[1], 0, 0, 0);
            acc_b[0] = __builtin_amdgcn_mfma_f32_16x16x32_bf16(awb, bf0, acc_b[0], 0, 0, 0);
            acc_b[1] = __builtin_amdgcn_mfma_f32_16x16x32_bf16(awb, bf1, acc_b[1], 0, 0, 0);
        }
    }
    __syncthreads();   // all xbf reads done before A1bf overlays the region

    // ---- store A1/A2 as zero-padded bf16 frags [u<32][i<64] (C/D: row=W-row=i, col=u) ----
    {
        const int m0 = wave * 16;
        #pragma unroll
        for (int nt = 0; nt < 2; ++nt) {
            const int u = nt * 16 + lo;            // u < 32 always; pad rows 22..31 with 0
            uint2 va, vb;
            if (u < VV) {
                va.x = pk2(acc_a[nt][0], acc_a[nt][1]); va.y = pk2(acc_a[nt][2], acc_a[nt][3]);
                vb.x = pk2(acc_b[nt][0], acc_b[nt][1]); vb.y = pk2(acc_b[nt][2], acc_b[nt][3]);
            } else {
                va.x = va.y = vb.x = vb.y = 0u;
            }
            *reinterpret_cast<uint2*>(&A1bf[u * 64 + m0 + hi * 4]) = va;
            *reinterpret_cast<uint2*>(&A2bf[u * 64 + m0 + hi * 4]) = vb;
        }
    }
    __syncthreads();

    // ---- P2 MFMA: S = (1/64) A1^T A2. wave -> (mt,nt); 2 k-steps ----
    {
        const int mt = wave >> 1, nt = wave & 1;
        f32x4 s = {0.f, 0.f, 0.f, 0.f};
        #pragma unroll
        for (int kb = 0; kb < 2; ++kb) {
            bf16x8 a = *reinterpret_cast<const bf16x8*>(&A1bf[(mt * 16 + lo) * 64 + kb * 32 + hi * 8]);
            bf16x8 b = *reinterpret_cast<const bf16x8*>(&A2bf[(nt * 16 + lo) * 64 + kb * 32 + hi * 8]);
            s = __builtin_amdgcn_mfma_f32_16x16x32_bf16(a, b, s, 0, 0, 0);
        }
        const int v = nt * 16 + lo;
        if (v < VV) {
            #pragma unroll
            for (int r = 0; r < 4; ++r) {
                const int u = mt * 16 + hi * 4 + r;
                if (u < VV) Ss[u * XPAD + v] = s[r] * (1.0f / 64.0f);
            }
        }
    }
    __syncthreads();

    // ---- P3: shuffle softmax over u, per column v (unchanged) ----
    if (tid < VV * 8) {
        const int v = tid >> 3, p = tid & 7;
        const int u1 = p + 8, u2 = p + 16;
        float s0 = Ss[p * XPAD + v];
        float s1 = Ss[u1 * XPAD + v];
        float s2 = (u2 < VV) ? Ss[u2 * XPAD + v] : -1e30f;
        float m = fmaxf(s0, fmaxf(s1, s2));
        m = fmaxf(m, __shfl_xor(m, 1, 8));
        m = fmaxf(m, __shfl_xor(m, 2, 8));
        m = fmaxf(m, __shfl_xor(m, 4, 8));
        float e0 = __expf(s0 - m), e1 = __expf(s1 - m);
        float e2 = (u2 < VV) ? __expf(s2 - m) : 0.f;
        float sum = e0 + e1 + e2;
        sum += __shfl_xor(sum, 1, 8);
        sum += __shfl_xor(sum, 2, 8);
        sum += __shfl_xor(sum, 4, 8);
        const float inv = 1.0f / sum;
        Ps[p * XPAD + v]  += e0 * inv;
        Ps[u1 * XPAD + v] += e1 * inv;
        if (u2 < VV) Ps[u2 * XPAD + v] += e2 * inv;
    }
    __syncthreads();

    // ---- conv3: build P4 frags. xabf (all threads), pbf (tid<128) ----
    {
        const int mt = tid >> 6, ln = tid & 63;
        const int c  = mt * 16 + (ln & 15);
        const int w0 = (ln >> 4) * 8;
        ushort tmp[8];
        #pragma unroll
        for (int j = 0; j < 8; ++j)
            tmp[j] = (w0 + j < VV) ? f2bf(xs[c * XPAD + w0 + j]) : (ushort)0;
        *reinterpret_cast<uint4*>(&xabf[(size_t)tid * 8]) = *reinterpret_cast<const uint4*>(tmp);

        if (tid < 128) {
            const int nt = tid >> 6, ln2 = tid & 63;
            const int u  = nt * 16 + (ln2 & 15);
            const int wb = (ln2 >> 4) * 8;
            ushort tp[8];
            #pragma unroll
            for (int j = 0; j < 8; ++j)
                tp[j] = (u < VV && wb + j < VV) ? f2bf(Ps[u * XPAD + wb + j]) : (ushort)0;
            *reinterpret_cast<uint4*>(&pbf[(size_t)tid * 8]) = *reinterpret_cast<const uint4*>(tp);
        }
    }
    __syncthreads();

    // ---- P4 MFMA: z[c][u] = sum_w X[c][w] P[u][w]. wave = mt (c-tile); 1 k-step ----
    {
        const int tb  = t >> 2;
        const int ttl = t & 3;
        float* zdst = z + (((size_t)n * NTB + tb) * CIN) * ZROW + ttl * VV;
        const int mt = wave;
        bf16x8 a = *reinterpret_cast<const bf16x8*>(&xabf[((size_t)mt * 64 + lane) * 8]);
        #pragma unroll
        for (int nt = 0; nt < 2; ++nt) {
            bf16x8 b = *reinterpret_cast<const bf16x8*>(&pbf[((size_t)nt * 64 + lane) * 8]);
            f32x4 acc = {0.f, 0.f, 0.f, 0.f};
            acc = __builtin_amdgcn_mfma_f32_16x16x32_bf16(a, b, acc, 0, 0, 0);
            const int u = nt * 16 + lo;
            if (u < VV) {
                #pragma unroll
                for (int r = 0; r < 4; ++r) {
                    const int c = mt * 16 + hi * 4 + r;
                    zdst[(size_t)c * ZROW + u] = acc[r];
                }
            }
        }
    }
}

// ===================== Kernel 2 (MFMA, R12/R13-benched: ~38us, HBM floor) =====================
__global__ __launch_bounds__(256, 3) void agcn_out_mfma(
    const float* __restrict__ z, const ushort* __restrict__ WdB,
    const float* __restrict__ bd, float* __restrict__ out)
{
    const int bxx = blockIdx.x;
    const int tb  = (bxx & 7) * 16 + (bxx >> 3);
    const int n   = blockIdx.y;
    const int tid = threadIdx.x;
    const int lane = tid & 63, wave = tid >> 6;
    const int hi = lane >> 4, lo = lane & 15;

    __shared__ __align__(16) float  Zs[CIN * ZS + 8];
    __shared__ __align__(16) ushort zbf[2 * 6 * 64 * 8];

    {
        const float* zsrc = z + (((size_t)n * NTB + tb) * CIN) * ZROW;
        for (int i4 = tid; i4 < (CIN * ZROW) / 4; i4 += 256) {
            float4 val = *reinterpret_cast<const float4*>(zsrc + (size_t)i4 * 4);
            int c = i4 / (ZROW / 4), r4 = (i4 % (ZROW / 4)) * 4;
            *reinterpret_cast<float4*>(&Zs[c * ZS + r4]) = val;
        }
    }
    __syncthreads();

    for (int it = tid; it < 768; it += 256) {
        const int kb  = it / 384;
        const int rem = it - kb * 384;
        const int nt  = rem >> 6;
        const int ln  = rem & 63;
        const int tv  = nt * 16 + (ln & 15);
        const int c0  = kb * 32 + (ln >> 4) * 8;
        ushort tmp[8];
        if (tv < ZROW) {
            #pragma unroll
            for (int j = 0; j < 8; ++j) tmp[j] = f2bf(Zs[(c0 + j) * ZS + tv]);
        } else {
            #pragma unroll
            for (int j = 0; j < 8; ++j) tmp[j] = 0;
        }
        *reinterpret_cast<uint4*>(&zbf[(size_t)it * 8]) = *reinterpret_cast<const uint4*>(tmp);
    }
    __syncthreads();

    const int o0 = wave * 64;
    f32x4 acc[4][6];
    #pragma unroll
    for (int mt = 0; mt < 4; ++mt) {
        #pragma unroll
        for (int r = 0; r < 4; ++r) {
            const float b = bd[o0 + mt * 16 + hi * 4 + r];
            #pragma unroll
            for (int nt = 0; nt < 6; ++nt) acc[mt][nt][r] = b;
        }
    }

    #pragma unroll
    for (int kb = 0; kb < 2; ++kb) {
        bf16x8 bfr[6];
        #pragma unroll
        for (int nt = 0; nt < 6; ++nt)
            bfr[nt] = *reinterpret_cast<const bf16x8*>(&zbf[((kb * 6 + nt) * 64 + lane) * 8]);
        #pragma unroll
        for (int mt = 0; mt < 4; ++mt) {
            bf16x8 aw = *reinterpret_cast<const bf16x8*>(
                &WdB[(size_t)(o0 + mt * 16 + lo) * CIN + kb * 32 + hi * 8]);
            #pragma unroll
            for (int nt = 0; nt < 6; ++nt)
                acc[mt][nt] = __builtin_amdgcn_mfma_f32_16x16x32_bf16(aw, bfr[nt], acc[mt][nt], 0, 0, 0);
        }
    }

    #pragma unroll
    for (int mt = 0; mt < 4; ++mt) {
        #pragma unroll
        for (int nt = 0; nt < 6; ++nt) {
            const int col = nt * 16 + lo;
            if (col < ZROW) {
                #pragma unroll
                for (int r = 0; r < 4; ++r) {
                    const int o = o0 + mt * 16 + hi * 4 + r;
                    out[((size_t)(n * COUT + o)) * (TT * VV) + (size_t)tb * ZROW + col]
                        = fmaxf(acc[mt][nt][r], 0.f);
                }
            }
        }
    }
}

// ===================== Fallback: verified R1 monolithic kernel =====================
__global__ __launch_bounds__(256, 4) void agcn_fused(
    const float* __restrict__ x, const float* __restrict__ A,
    const float* __restrict__ Wa, const float* __restrict__ ba,
    const float* __restrict__ Wb, const float* __restrict__ bb,
    const float* __restrict__ Wd, const float* __restrict__ bd,
    float* __restrict__ out)
{
    const int t   = blockIdx.x;
    const int n   = blockIdx.y;
    const int tid = threadIdx.x;
    __shared__ float smem[7424];
    float* xs   = smem;
    float* A1s  = smem + 1536;
    float* A2s  = smem + 3072;
    float* Ssf  = smem + 4608;
    float* Psf  = smem + 5136;
    float* outs = smem;
    float* zs   = smem + 5888;

    for (int f = tid; f < CIN * VV; f += 256) {
        int c = f / VV, v = f - c * VV;
        xs[c * PAD + v] = x[(((size_t)n * CIN + c) * TT + t) * VV + v];
    }
    {
        const float* Ag = A + (((size_t)n * TT + t) * VV) * VV;
        for (int f = tid; f < VV * VV; f += 256) {
            int u = f / VV, v = f - u * VV;
            Psf[u * PAD + v] = Ag[f] + 1e-6f;
        }
    }
    __syncthreads();
    {
        const int r  = tid & 63;
        const int q  = tid >> 6;
        const int us = (q * VV) >> 2;
        const int ue = ((q + 1) * VV) >> 2;
        const float* War = Wa + r * CIN;
        const float* Wbr = Wb + r * CIN;
        float acc1[6], acc2[6];
        const float b1 = ba[r], b2 = bb[r];
        #pragma unroll
        for (int u = 0; u < 6; ++u) { acc1[u] = b1; acc2[u] = b2; }
        for (int c = 0; c < CIN; c += 4) {
            float4 wa4 = *reinterpret_cast<const float4*>(War + c);
            float4 wb4 = *reinterpret_cast<const float4*>(Wbr + c);
            #pragma unroll
            for (int u = 0; u < 6; ++u) {
                float x0 = xs[(c + 0) * PAD + us + u];
                float x1 = xs[(c + 1) * PAD + us + u];
                float x2 = xs[(c + 2) * PAD + us + u];
                float x3 = xs[(c + 3) * PAD + us + u];
                acc1[u] += wa4.x * x0 + wa4.y * x1 + wa4.z * x2 + wa4.w * x3;
                acc2[u] += wb4.x * x0 + wb4.y * x1 + wb4.z * x2 + wb4.w * x3;
            }
        }
        #pragma unroll
        for (int u = 0; u < 6; ++u) {
            if (us + u < ue) {
                A1s[r * PAD + us + u] = acc1[u];
                A2s[r * PAD + us + u] = acc2[u];
            }
        }
    }
    __syncthreads();
    for (int f = tid; f < VV * VV; f += 256) {
        int u = f / VV, v = f - u * VV;
        float s = 0.f;
        for (int i = 0; i < CIN; ++i)
            s += A1s[i * PAD + u] * A2s[i * PAD + v];
        Ssf[u * PAD + v] = s * (1.0f / 64.0f);
    }
    __syncthreads();
    if (tid < VV) {
        const int v = tid;
        float m = -1e30f;
        #pragma unroll
        for (int u = 0; u < VV; ++u) m = fmaxf(m, Ssf[u * PAD + v]);
        float sum = 0.f;
        #pragma unroll
        for (int u = 0; u < VV; ++u) sum += __expf(Ssf[u * PAD + v] - m);
        const float inv = 1.0f / sum;
        #pragma unroll
        for (int u = 0; u < VV; ++u)
            Psf[u * PAD + v] += __expf(Ssf[u * PAD + v] - m) * inv;
    }
    __syncthreads();
    for (int f = tid; f < CIN * VV; f += 256) {
        int c = f / VV, u = f - c * VV;
        float s = 0.f;
        #pragma unroll
        for (int w = 0; w < VV; ++w)
            s += Psf[u * PAD + w] * xs[c * PAD + w];
        zs[c * PAD + u] = s;
    }
    __syncthreads();
    {
        const int o = tid;
        const float* Wr = Wd + o * CIN;
        float acc[VV];
        const float b = bd[o];
        #pragma unroll
        for (int u = 0; u < VV; ++u) acc[u] = b;
        for (int c = 0; c < CIN; c += 4) {
            float4 w4 = *reinterpret_cast<const float4*>(Wr + c);
            #pragma unroll
            for (int cc = 0; cc < 4; ++cc) {
                const float w = (cc == 0) ? w4.x : (cc == 1) ? w4.y : (cc == 2) ? w4.z : w4.w;
                const float* zr = zs + (c + cc) * PAD;
                #pragma unroll
                for (int uq = 0; uq < 5; ++uq) {
                    float4 zq = *reinterpret_cast<const float4*>(zr + uq * 4);
                    acc[uq * 4 + 0] += w * zq.x;
                    acc[uq * 4 + 1] += w * zq.y;
                    acc[uq * 4 + 2] += w * zq.z;
                    acc[uq * 4 + 3] += w * zq.w;
                }
                float2 zt = *reinterpret_cast<const float2*>(zr + 20);
                acc[20] += w * zt.x;
                acc[21] += w * zt.y;
            }
        }
        #pragma unroll
        for (int u = 0; u < VV; ++u)
            outs[o * OPAD + u] = fmaxf(acc[u], 0.f);
    }
    __syncthreads();
    {
        const size_t obase = (size_t)n * COUT * TT * VV + (size_t)t * VV;
        for (int f = tid; f < COUT * VV; f += 256) {
            int o = f / VV, u = f - o * VV;
            out[obase + (size_t)o * (TT * VV) + u] = outs[o * OPAD + u];
        }
    }
}

extern "C" void kernel_launch(void* const* d_in, const int* in_sizes, int n_in,
                              void* d_out, int out_size, void* d_ws, size_t ws_size,
                              hipStream_t stream) {
    const float* x  = (const float*)d_in[0];
    const float* A  = (const float*)d_in[1];
    const float* Wa = (const float*)d_in[2];
    const float* ba = (const float*)d_in[3];
    const float* Wb = (const float*)d_in[4];
    const float* bb = (const float*)d_in[5];
    const float* Wd = (const float*)d_in[6];
    const float* bd = (const float*)d_in[7];
    float* outp     = (float*)d_out;

    const size_t z_bytes   = (size_t)NB * TT * CIN * VV * sizeof(float);  // 46.1 MB
    const size_t wdb_bytes = (size_t)COUT * CIN * sizeof(ushort);         // 32 KB
    const size_t wab_bytes = (size_t)CIN * CIN * sizeof(ushort);          // 8 KB each

    if (ws_size >= z_bytes + wdb_bytes + 2 * wab_bytes) {
        float*  zws = (float*)d_ws;
        ushort* wdb = (ushort*)((char*)d_ws + z_bytes);
        ushort* wab = (ushort*)((char*)d_ws + z_bytes + wdb_bytes);
        ushort* wbb = (ushort*)((char*)d_ws + z_bytes + wdb_bytes + wab_bytes);
        const int prep_items = 2 * CIN * CIN + COUT * CIN;   // 24576
        w_to_bf16<<<(prep_items + 255) / 256, 256, 0, stream>>>(Wa, Wb, Wd, wab, wbb, wdb);
        dim3 g1(TT, NB);
        agcn_attn<<<g1, 256, 0, stream>>>(x, A, wab, ba, wbb, bb, zws);
        dim3 g2(NTB, NB);
        agcn_out_mfma<<<g2, 256, 0, stream>>>(zws, wdb, bd, outp);
    } else {
        dim3 grid(TT, NB);
        agcn_fused<<<grid, 256, 0, stream>>>(x, A, Wa, ba, Wb, bb, Wd, bd, outp);
    }
}

// Round 15
// 107.100 us; speedup vs baseline: 2.8378x; 1.1375x over previous
//
#include <hip/hip_runtime.h>

#define NB    16
#define CIN   64
#define TT    512
#define VV    22
#define COUT  256
#define TBK   4            // t per z tile (and per k1 block)
#define NTB   (TT / TBK)   // 128
#define ZROW  (TBK * VV)   // 88
#define ZS    92           // k2 Zs row stride
#define PAD   24           // fallback kernel pads
#define OPAD  23

typedef __attribute__((ext_vector_type(8))) short bf16x8;
typedef __attribute__((ext_vector_type(4))) float f32x4;

__device__ __forceinline__ ushort f2bf(float f) {   // RNE fp32 -> bf16
    unsigned u = __float_as_uint(f);
    return (ushort)((u + 0x7FFFu + ((u >> 16) & 1u)) >> 16);
}
__device__ __forceinline__ uint pk2(float a, float b) {
    return (uint)f2bf(a) | ((uint)f2bf(b) << 16);
}

// ===================== Prep: Wa/Wb/Wd -> bf16 (once, into ws tail) =====================
__global__ void w_to_bf16(const float* __restrict__ Wa, const float* __restrict__ Wb,
                          const float* __restrict__ Wd,
                          ushort* __restrict__ WaB, ushort* __restrict__ WbB,
                          ushort* __restrict__ WdB)
{
    int i = blockIdx.x * 256 + threadIdx.x;
    if (i < CIN * CIN)                 WaB[i] = f2bf(Wa[i]);
    else if (i < 2 * CIN * CIN)        WbB[i - CIN * CIN] = f2bf(Wb[i - CIN * CIN]);
    else if (i < 2 * CIN * CIN + COUT * CIN)
                                       WdB[i - 2 * CIN * CIN] = f2bf(Wd[i - 2 * CIN * CIN]);
}

// ===================== Kernel 1: attention + aggregate, TQ=4 t's per block =====================
// Fragment conventions (HW-validated R12/R13):
//   A-operand: lane l holds A[row = tile*16 + (l&15)][k = kb*32 + (l>>4)*8 + j]
//   B-operand: lane l holds B[k = kb*32 + (l>>4)*8 + j][col = tile*16 + (l&15)]
//   C/D:       col = l&15, row = (l>>4)*4 + reg
// All GEMMs use the same k-bijection on A and B -> exact under HW k-permutation.
__global__ __launch_bounds__(256, 3) void agcn_attn(
    const float* __restrict__ x, const float* __restrict__ A,
    const ushort* __restrict__ WaB, const float* __restrict__ ba,
    const ushort* __restrict__ WbB, const float* __restrict__ bb,
    float* __restrict__ z)
{
    const int bx = blockIdx.x;                   // 0..127
    const int tq = (bx & 7) * 16 + (bx >> 3);    // XCD swizzle, == k2's tb
    const int n  = blockIdx.y;
    const int tid = threadIdx.x;
    const int lane = tid & 63, wave = tid >> 6;
    const int hi = lane >> 4, lo = lane & 15;
    const int t0 = tq * TBK;

    // LDS: xsb 16384B | regA 22528B (xbf 16384 -> A1bf/A2bf overlay) | psb 5632B = 43.5KB
    __shared__ __align__(16) ushort xsb[TBK * 64 * 32];   // [t][c][w<32], w>=22 zero
    __shared__ __align__(16) ushort regA[11264];          // overlay region
    __shared__ __align__(16) ushort psb[TBK * VV * 32];   // [t][u<22][w<32], pads zero
    ushort* xbf  = regA;          // P1 B-frags [kb2][t4][nt2][lane][8] = 8192 us
    ushort* A1bf = regA;          // [t][u<22][i<64] = 5632 us
    ushort* A2bf = regA + 5632;

    // ---- zero pads (disjoint from staged cells -> no barrier vs staging) ----
    for (int i = tid; i < TBK * 64 * 5; i += 256) {       // xsb cols 22..31
        int row = i / 5, q = i - row * 5;
        reinterpret_cast<uint*>(&xsb[row * 32 + 22])[q] = 0u;
    }
    for (int i = tid; i < (TBK * VV * 32) / 2; i += 256)  // all of psb
        reinterpret_cast<uint*>(psb)[i] = 0u;

    // ---- P0: stage x (352B-contiguous per c) -> bf16 LDS ----
    {
        const float* xsrc = x + ((size_t)n * CIN * TT + t0) * VV;
        for (int i4 = tid; i4 < CIN * 22; i4 += 256) {    // 22 float4 per c
            int c = i4 / 22, q = i4 - c * 22;
            float4 v4 = *reinterpret_cast<const float4*>(xsrc + (size_t)c * (TT * VV) + q * 4);
            #pragma unroll
            for (int j = 0; j < 4; ++j) {
                int e  = q * 4 + j;                       // 0..87
                int tt = e / 22, v = e - tt * 22;
                float val = (j == 0) ? v4.x : (j == 1) ? v4.y : (j == 2) ? v4.z : v4.w;
                xsb[(tt * 64 + c) * 32 + v] = f2bf(val);
            }
        }
    }
    __syncthreads();

    // ---- conv1: P1 B-frags from xsb ----
    for (int it = tid; it < 1024; it += 256) {            // [kb2][t4][nt2][ln64]
        int kb = it >> 9;
        int t  = (it >> 7) & 3;
        int nt = (it >> 6) & 1;
        int ln = it & 63;
        int v  = nt * 16 + (ln & 15);                     // <32, pads zero
        int c0 = kb * 32 + (ln >> 4) * 8;
        ushort tmp[8];
        #pragma unroll
        for (int j = 0; j < 8; ++j) tmp[j] = xsb[(t * 64 + c0 + j) * 32 + v];
        *reinterpret_cast<uint4*>(&xbf[(size_t)it * 8]) = *reinterpret_cast<const uint4*>(tmp);
    }
    __syncthreads();

    // ---- P1 MFMA: A1 = Wa@X+ba, A2 = Wb@X+bb for all 4 t's (wave: W-rows m0..m0+15) ----
    f32x4 acc_a[TBK][2], acc_b[TBK][2];
    {
        const int m0 = wave * 16;
        float bav[4], bbv[4];
        #pragma unroll
        for (int r = 0; r < 4; ++r) { bav[r] = ba[m0 + hi * 4 + r]; bbv[r] = bb[m0 + hi * 4 + r]; }
        #pragma unroll
        for (int t = 0; t < TBK; ++t)
            #pragma unroll
            for (int nt = 0; nt < 2; ++nt)
                #pragma unroll
                for (int r = 0; r < 4; ++r) { acc_a[t][nt][r] = bav[r]; acc_b[t][nt][r] = bbv[r]; }
        #pragma unroll
        for (int kb = 0; kb < 2; ++kb) {
            bf16x8 awa = *reinterpret_cast<const bf16x8*>(&WaB[(size_t)(m0 + lo) * CIN + kb * 32 + hi * 8]);
            bf16x8 awb = *reinterpret_cast<const bf16x8*>(&WbB[(size_t)(m0 + lo) * CIN + kb * 32 + hi * 8]);
            #pragma unroll
            for (int t = 0; t < TBK; ++t) {
                #pragma unroll
                for (int nt = 0; nt < 2; ++nt) {
                    bf16x8 bf = *reinterpret_cast<const bf16x8*>(
                        &xbf[(((size_t)(kb * 4 + t) * 2 + nt) * 64 + lane) * 8]);
                    acc_a[t][nt] = __builtin_amdgcn_mfma_f32_16x16x32_bf16(awa, bf, acc_a[t][nt], 0, 0, 0);
                    acc_b[t][nt] = __builtin_amdgcn_mfma_f32_16x16x32_bf16(awb, bf, acc_b[t][nt], 0, 0, 0);
                }
            }
        }
    }
    __syncthreads();   // all xbf reads done before A1bf overlays the region

    // ---- store A1/A2 bf16 frags [t][u<22][i<64] (C/D: col=u, row=W-row=i) ----
    {
        const int m0 = wave * 16;
        #pragma unroll
        for (int t = 0; t < TBK; ++t) {
            #pragma unroll
            for (int nt = 0; nt < 2; ++nt) {
                const int u = nt * 16 + lo;
                if (u < VV) {
                    uint2 va = {pk2(acc_a[t][nt][0], acc_a[t][nt][1]),
                                pk2(acc_a[t][nt][2], acc_a[t][nt][3])};
                    uint2 vb = {pk2(acc_b[t][nt][0], acc_b[t][nt][1]),
                                pk2(acc_b[t][nt][2], acc_b[t][nt][3])};
                    *reinterpret_cast<uint2*>(&A1bf[((size_t)t * VV + u) * 64 + m0 + hi * 4]) = va;
                    *reinterpret_cast<uint2*>(&A2bf[((size_t)t * VV + u) * 64 + m0 + hi * 4]) = vb;
                }
            }
        }
    }
    __syncthreads();

    // ---- P2 (wave = t): S in registers; softmax in-register; P3 writes psb; P4 MFMA ----
    {
        const int t = wave;
        bf16x8 zfrag;
        #pragma unroll
        for (int j = 0; j < 8; ++j) zfrag[j] = 0;

        f32x4 s[2][2];
        #pragma unroll
        for (int mt = 0; mt < 2; ++mt)
            #pragma unroll
            for (int nt = 0; nt < 2; ++nt)
                #pragma unroll
                for (int r = 0; r < 4; ++r) s[mt][nt][r] = 0.f;

        #pragma unroll
        for (int kb = 0; kb < 2; ++kb) {
            bf16x8 a[2], b2[2];
            #pragma unroll
            for (int mt = 0; mt < 2; ++mt) {
                const int row = mt * 16 + lo;
                a[mt] = (row < VV) ? *reinterpret_cast<const bf16x8*>(
                            &A1bf[((size_t)t * VV + row) * 64 + kb * 32 + hi * 8]) : zfrag;
            }
            #pragma unroll
            for (int nt = 0; nt < 2; ++nt) {
                const int row = nt * 16 + lo;
                b2[nt] = (row < VV) ? *reinterpret_cast<const bf16x8*>(
                            &A2bf[((size_t)t * VV + row) * 64 + kb * 32 + hi * 8]) : zfrag;
            }
            #pragma unroll
            for (int mt = 0; mt < 2; ++mt)
                #pragma unroll
                for (int nt = 0; nt < 2; ++nt)
                    s[mt][nt] = __builtin_amdgcn_mfma_f32_16x16x32_bf16(a[mt], b2[nt], s[mt][nt], 0, 0, 0);
        }

        // scale + column softmax over u (rows). col v = nt*16+lo; u = mt*16+hi*4+r.
        float m[2] = {-1e30f, -1e30f};
        #pragma unroll
        for (int mt = 0; mt < 2; ++mt)
            #pragma unroll
            for (int nt = 0; nt < 2; ++nt)
                #pragma unroll
                for (int r = 0; r < 4; ++r) {
                    s[mt][nt][r] *= (1.0f / 64.0f);
                    const int u = mt * 16 + hi * 4 + r;
                    if (u < VV) m[nt] = fmaxf(m[nt], s[mt][nt][r]);
                }
        #pragma unroll
        for (int nt = 0; nt < 2; ++nt) {
            m[nt] = fmaxf(m[nt], __shfl_xor(m[nt], 16));
            m[nt] = fmaxf(m[nt], __shfl_xor(m[nt], 32));
        }
        float e[2][2][4];
        float sum[2] = {0.f, 0.f};
        #pragma unroll
        for (int mt = 0; mt < 2; ++mt)
            #pragma unroll
            for (int nt = 0; nt < 2; ++nt)
                #pragma unroll
                for (int r = 0; r < 4; ++r) {
                    const int u = mt * 16 + hi * 4 + r;
                    float ev = (u < VV) ? __expf(s[mt][nt][r] - m[nt]) : 0.f;
                    e[mt][nt][r] = ev;
                    sum[nt] += ev;
                }
        #pragma unroll
        for (int nt = 0; nt < 2; ++nt) {
            sum[nt] += __shfl_xor(sum[nt], 16);
            sum[nt] += __shfl_xor(sum[nt], 32);
        }

        // P3: P = A + 1e-6 + softmax, written as bf16 [t][u][v-padded]
        {
            const float* Ag = A + ((size_t)(n * TT + t0 + t) * VV) * VV;
            #pragma unroll
            for (int nt = 0; nt < 2; ++nt) {
                const int v = nt * 16 + lo;
                if (v < VV) {
                    const float inv = 1.0f / sum[nt];
                    #pragma unroll
                    for (int mt = 0; mt < 2; ++mt)
                        #pragma unroll
                        for (int r = 0; r < 4; ++r) {
                            const int u = mt * 16 + hi * 4 + r;
                            if (u < VV)
                                psb[((size_t)t * VV + u) * 32 + v] =
                                    f2bf(Ag[u * VV + v] + 1e-6f + e[mt][nt][r] * inv);
                        }
                }
            }
        }
        // P4: z[c][u] = sum_w X[c][w] P[u][w]; same-wave psb reads (no barrier needed)
        {
            float* zdst = z + (((size_t)n * NTB + tq) * CIN) * ZROW + t * VV;
            bf16x8 bfr[2];
            #pragma unroll
            for (int nt = 0; nt < 2; ++nt) {
                const int u = nt * 16 + lo;
                bfr[nt] = (u < VV) ? *reinterpret_cast<const bf16x8*>(
                              &psb[((size_t)t * VV + u) * 32 + hi * 8]) : zfrag;
            }
            #pragma unroll
            for (int mt = 0; mt < 4; ++mt) {
                bf16x8 a = *reinterpret_cast<const bf16x8*>(
                    &xsb[((size_t)(t * 64 + mt * 16 + lo)) * 32 + hi * 8]);
                #pragma unroll
                for (int nt = 0; nt < 2; ++nt) {
                    f32x4 acc = {0.f, 0.f, 0.f, 0.f};
                    acc = __builtin_amdgcn_mfma_f32_16x16x32_bf16(a, bfr[nt], acc, 0, 0, 0);
                    const int u = nt * 16 + lo;
                    if (u < VV) {
                        #pragma unroll
                        for (int r = 0; r < 4; ++r) {
                            const int c = mt * 16 + hi * 4 + r;
                            zdst[(size_t)c * ZROW + u] = acc[r];
                        }
                    }
                }
            }
        }
    }
}

// ===================== Kernel 2 (MFMA, R12-R14-benched: ~38us, HBM floor) =====================
__global__ __launch_bounds__(256, 3) void agcn_out_mfma(
    const float* __restrict__ z, const ushort* __restrict__ WdB,
    const float* __restrict__ bd, float* __restrict__ out)
{
    const int bxx = blockIdx.x;
    const int tb  = (bxx & 7) * 16 + (bxx >> 3);
    const int n   = blockIdx.y;
    const int tid = threadIdx.x;
    const int lane = tid & 63, wave = tid >> 6;
    const int hi = lane >> 4, lo = lane & 15;

    __shared__ __align__(16) float  Zs[CIN * ZS + 8];
    __shared__ __align__(16) ushort zbf[2 * 6 * 64 * 8];

    {
        const float* zsrc = z + (((size_t)n * NTB + tb) * CIN) * ZROW;
        for (int i4 = tid; i4 < (CIN * ZROW) / 4; i4 += 256) {
            float4 val = *reinterpret_cast<const float4*>(zsrc + (size_t)i4 * 4);
            int c = i4 / (ZROW / 4), r4 = (i4 % (ZROW / 4)) * 4;
            *reinterpret_cast<float4*>(&Zs[c * ZS + r4]) = val;
        }
    }
    __syncthreads();

    for (int it = tid; it < 768; it += 256) {
        const int kb  = it / 384;
        const int rem = it - kb * 384;
        const int nt  = rem >> 6;
        const int ln  = rem & 63;
        const int tv  = nt * 16 + (ln & 15);
        const int c0  = kb * 32 + (ln >> 4) * 8;
        ushort tmp[8];
        if (tv < ZROW) {
            #pragma unroll
            for (int j = 0; j < 8; ++j) tmp[j] = f2bf(Zs[(c0 + j) * ZS + tv]);
        } else {
            #pragma unroll
            for (int j = 0; j < 8; ++j) tmp[j] = 0;
        }
        *reinterpret_cast<uint4*>(&zbf[(size_t)it * 8]) = *reinterpret_cast<const uint4*>(tmp);
    }
    __syncthreads();

    const int o0 = wave * 64;
    f32x4 acc[4][6];
    #pragma unroll
    for (int mt = 0; mt < 4; ++mt) {
        #pragma unroll
        for (int r = 0; r < 4; ++r) {
            const float b = bd[o0 + mt * 16 + hi * 4 + r];
            #pragma unroll
            for (int nt = 0; nt < 6; ++nt) acc[mt][nt][r] = b;
        }
    }

    #pragma unroll
    for (int kb = 0; kb < 2; ++kb) {
        bf16x8 bfr[6];
        #pragma unroll
        for (int nt = 0; nt < 6; ++nt)
            bfr[nt] = *reinterpret_cast<const bf16x8*>(&zbf[((kb * 6 + nt) * 64 + lane) * 8]);
        #pragma unroll
        for (int mt = 0; mt < 4; ++mt) {
            bf16x8 aw = *reinterpret_cast<const bf16x8*>(
                &WdB[(size_t)(o0 + mt * 16 + lo) * CIN + kb * 32 + hi * 8]);
            #pragma unroll
            for (int nt = 0; nt < 6; ++nt)
                acc[mt][nt] = __builtin_amdgcn_mfma_f32_16x16x32_bf16(aw, bfr[nt], acc[mt][nt], 0, 0, 0);
        }
    }

    #pragma unroll
    for (int mt = 0; mt < 4; ++mt) {
        #pragma unroll
        for (int nt = 0; nt < 6; ++nt) {
            const int col = nt * 16 + lo;
            if (col < ZROW) {
                #pragma unroll
                for (int r = 0; r < 4; ++r) {
                    const int o = o0 + mt * 16 + hi * 4 + r;
                    out[((size_t)(n * COUT + o)) * (TT * VV) + (size_t)tb * ZROW + col]
                        = fmaxf(acc[mt][nt][r], 0.f);
                }
            }
        }
    }
}

// ===================== Fallback: verified R1 monolithic kernel =====================
__global__ __launch_bounds__(256, 4) void agcn_fused(
    const float* __restrict__ x, const float* __restrict__ A,
    const float* __restrict__ Wa, const float* __restrict__ ba,
    const float* __restrict__ Wb, const float* __restrict__ bb,
    const float* __restrict__ Wd, const float* __restrict__ bd,
    float* __restrict__ out)
{
    const int t   = blockIdx.x;
    const int n   = blockIdx.y;
    const int tid = threadIdx.x;
    __shared__ float smem[7424];
    float* xs   = smem;
    float* A1s  = smem + 1536;
    float* A2s  = smem + 3072;
    float* Ssf  = smem + 4608;
    float* Psf  = smem + 5136;
    float* outs = smem;
    float* zs   = smem + 5888;

    for (int f = tid; f < CIN * VV; f += 256) {
        int c = f / VV, v = f - c * VV;
        xs[c * PAD + v] = x[(((size_t)n * CIN + c) * TT + t) * VV + v];
    }
    {
        const float* Ag = A + (((size_t)n * TT + t) * VV) * VV;
        for (int f = tid; f < VV * VV; f += 256) {
            int u = f / VV, v = f - u * VV;
            Psf[u * PAD + v] = Ag[f] + 1e-6f;
        }
    }
    __syncthreads();
    {
        const int r  = tid & 63;
        const int q  = tid >> 6;
        const int us = (q * VV) >> 2;
        const int ue = ((q + 1) * VV) >> 2;
        const float* War = Wa + r * CIN;
        const float* Wbr = Wb + r * CIN;
        float acc1[6], acc2[6];
        const float b1 = ba[r], b2 = bb[r];
        #pragma unroll
        for (int u = 0; u < 6; ++u) { acc1[u] = b1; acc2[u] = b2; }
        for (int c = 0; c < CIN; c += 4) {
            float4 wa4 = *reinterpret_cast<const float4*>(War + c);
            float4 wb4 = *reinterpret_cast<const float4*>(Wbr + c);
            #pragma unroll
            for (int u = 0; u < 6; ++u) {
                float x0 = xs[(c + 0) * PAD + us + u];
                float x1 = xs[(c + 1) * PAD + us + u];
                float x2 = xs[(c + 2) * PAD + us + u];
                float x3 = xs[(c + 3) * PAD + us + u];
                acc1[u] += wa4.x * x0 + wa4.y * x1 + wa4.z * x2 + wa4.w * x3;
                acc2[u] += wb4.x * x0 + wb4.y * x1 + wb4.z * x2 + wb4.w * x3;
            }
        }
        #pragma unroll
        for (int u = 0; u < 6; ++u) {
            if (us + u < ue) {
                A1s[r * PAD + us + u] = acc1[u];
                A2s[r * PAD + us + u] = acc2[u];
            }
        }
    }
    __syncthreads();
    for (int f = tid; f < VV * VV; f += 256) {
        int u = f / VV, v = f - u * VV;
        float s = 0.f;
        for (int i = 0; i < CIN; ++i)
            s += A1s[i * PAD + u] * A2s[i * PAD + v];
        Ssf[u * PAD + v] = s * (1.0f / 64.0f);
    }
    __syncthreads();
    if (tid < VV) {
        const int v = tid;
        float m = -1e30f;
        #pragma unroll
        for (int u = 0; u < VV; ++u) m = fmaxf(m, Ssf[u * PAD + v]);
        float sum = 0.f;
        #pragma unroll
        for (int u = 0; u < VV; ++u) sum += __expf(Ssf[u * PAD + v] - m);
        const float inv = 1.0f / sum;
        #pragma unroll
        for (int u = 0; u < VV; ++u)
            Psf[u * PAD + v] += __expf(Ssf[u * PAD + v] - m) * inv;
    }
    __syncthreads();
    for (int f = tid; f < CIN * VV; f += 256) {
        int c = f / VV, u = f - c * VV;
        float s = 0.f;
        #pragma unroll
        for (int w = 0; w < VV; ++w)
            s += Psf[u * PAD + w] * xs[c * PAD + w];
        zs[c * PAD + u] = s;
    }
    __syncthreads();
    {
        const int o = tid;
        const float* Wr = Wd + o * CIN;
        float acc[VV];
        const float b = bd[o];
        #pragma unroll
        for (int u = 0; u < VV; ++u) acc[u] = b;
        for (int c = 0; c < CIN; c += 4) {
            float4 w4 = *reinterpret_cast<const float4*>(Wr + c);
            #pragma unroll
            for (int cc = 0; cc < 4; ++cc) {
                const float w = (cc == 0) ? w4.x : (cc == 1) ? w4.y : (cc == 2) ? w4.z : w4.w;
                const float* zr = zs + (c + cc) * PAD;
                #pragma unroll
                for (int uq = 0; uq < 5; ++uq) {
                    float4 zq = *reinterpret_cast<const float4*>(zr + uq * 4);
                    acc[uq * 4 + 0] += w * zq.x;
                    acc[uq * 4 + 1] += w * zq.y;
                    acc[uq * 4 + 2] += w * zq.z;
                    acc[uq * 4 + 3] += w * zq.w;
                }
                float2 zt = *reinterpret_cast<const float2*>(zr + 20);
                acc[20] += w * zt.x;
                acc[21] += w * zt.y;
            }
        }
        #pragma unroll
        for (int u = 0; u < VV; ++u)
            outs[o * OPAD + u] = fmaxf(acc[u], 0.f);
    }
    __syncthreads();
    {
        const size_t obase = (size_t)n * COUT * TT * VV + (size_t)t * VV;
        for (int f = tid; f < COUT * VV; f += 256) {
            int o = f / VV, u = f - o * VV;
            out[obase + (size_t)o * (TT * VV) + u] = outs[o * OPAD + u];
        }
    }
}

extern "C" void kernel_launch(void* const* d_in, const int* in_sizes, int n_in,
                              void* d_out, int out_size, void* d_ws, size_t ws_size,
                              hipStream_t stream) {
    const float* x  = (const float*)d_in[0];
    const float* A  = (const float*)d_in[1];
    const float* Wa = (const float*)d_in[2];
    const float* ba = (const float*)d_in[3];
    const float* Wb = (const float*)d_in[4];
    const float* bb = (const float*)d_in[5];
    const float* Wd = (const float*)d_in[6];
    const float* bd = (const float*)d_in[7];
    float* outp     = (float*)d_out;

    const size_t z_bytes   = (size_t)NB * TT * CIN * VV * sizeof(float);  // 46.1 MB
    const size_t wdb_bytes = (size_t)COUT * CIN * sizeof(ushort);         // 32 KB
    const size_t wab_bytes = (size_t)CIN * CIN * sizeof(ushort);          // 8 KB each

    if (ws_size >= z_bytes + wdb_bytes + 2 * wab_bytes) {
        float*  zws = (float*)d_ws;
        ushort* wdb = (ushort*)((char*)d_ws + z_bytes);
        ushort* wab = (ushort*)((char*)d_ws + z_bytes + wdb_bytes);
        ushort* wbb = (ushort*)((char*)d_ws + z_bytes + wdb_bytes + wab_bytes);
        const int prep_items = 2 * CIN * CIN + COUT * CIN;   // 24576
        w_to_bf16<<<(prep_items + 255) / 256, 256, 0, stream>>>(Wa, Wb, Wd, wab, wbb, wdb);
        dim3 g1(NTB, NB);
        agcn_attn<<<g1, 256, 0, stream>>>(x, A, wab, ba, wbb, bb, zws);
        dim3 g2(NTB, NB);
        agcn_out_mfma<<<g2, 256, 0, stream>>>(zws, wdb, bd, outp);
    } else {
        dim3 grid(TT, NB);
        agcn_fused<<<grid, 256, 0, stream>>>(x, A, Wa, ba, Wb, bb, Wd, bd, outp);
    }
}

// Round 16
// 76.893 us; speedup vs baseline: 3.9527x; 1.3929x over previous
//
#include <hip/hip_runtime.h>

#define NB    16
#define CIN   64
#define TT    512
#define VV    22
#define COUT  256
#define TBK   4            // t per block/tile
#define NTB   (TT / TBK)   // 128
#define ZROW  (TBK * VV)   // 88
#define PAD   24           // fallback kernel pads
#define OPAD  23

typedef __attribute__((ext_vector_type(8))) short bf16x8;
typedef __attribute__((ext_vector_type(4))) float f32x4;

__device__ __forceinline__ ushort f2bf(float f) {   // RNE fp32 -> bf16
    unsigned u = __float_as_uint(f);
    return (ushort)((u + 0x7FFFu + ((u >> 16) & 1u)) >> 16);
}
__device__ __forceinline__ uint pk2(float a, float b) {
    return (uint)f2bf(a) | ((uint)f2bf(b) << 16);
}

// ===================== Prep: Wa/Wb/Wd -> bf16 (once, into ws) =====================
__global__ void w_to_bf16(const float* __restrict__ Wa, const float* __restrict__ Wb,
                          const float* __restrict__ Wd,
                          ushort* __restrict__ WaB, ushort* __restrict__ WbB,
                          ushort* __restrict__ WdB)
{
    int i = blockIdx.x * 256 + threadIdx.x;
    if (i < CIN * CIN)                 WaB[i] = f2bf(Wa[i]);
    else if (i < 2 * CIN * CIN)        WbB[i - CIN * CIN] = f2bf(Wb[i - CIN * CIN]);
    else if (i < 2 * CIN * CIN + COUT * CIN)
                                       WdB[i - 2 * CIN * CIN] = f2bf(Wd[i - 2 * CIN * CIN]);
}

// ===================== Fused kernel: attention + aggregate + out GEMM (all MFMA) =====================
// Per block (tq, n): 4 t's end-to-end; z never leaves LDS.
// Fragment conventions (HW-validated R12/R13):
//   A-op: lane l holds A[row = tile*16 + (l&15)][k = kb*32 + (l>>4)*8 + j]
//   B-op: lane l holds B[k][col = tile*16 + (l&15)],  C/D: col = l&15, row = (l>>4)*4 + reg
__global__ __launch_bounds__(256, 3) void agcn_fused_mfma(
    const float* __restrict__ x, const float* __restrict__ A,
    const ushort* __restrict__ WaB, const float* __restrict__ ba,
    const ushort* __restrict__ WbB, const float* __restrict__ bb,
    const ushort* __restrict__ WdB, const float* __restrict__ bd,
    float* __restrict__ out)
{
    const int bx = blockIdx.x;                   // 0..127
    const int tq = (bx & 7) * 16 + (bx >> 3);    // XCD swizzle
    const int n  = blockIdx.y;
    const int tid = threadIdx.x;
    const int lane = tid & 63, wave = tid >> 6;
    const int hi = lane >> 4, lo = lane & 15;
    const int t0 = tq * TBK;

    // LDS 44544B total.
    __shared__ __align__(16) ushort xsb[TBK * 64 * 32];   // [t][c][w<32]; zbf overlays [0..6144)
    __shared__ __align__(16) ushort frag[11264];          // xbf -> A1bf/A2bf -> z_lds
    __shared__ __align__(16) ushort psb[TBK * VV * 32];   // [t][u][w<32]
    ushort* xbf   = frag;            // P1 B-frags [kb2][t4][nt2][ln64][8] = 8192 us
    ushort* A1bf  = frag;            // [t][u<22][i<64] = 5632 us
    ushort* A2bf  = frag + 5632;
    ushort* z_lds = frag;            // bf16 [c<64][96] = 6144 us (phase B)
    ushort* zbf   = xsb;             // [kb2][nt6][ln64][8] = 6144 us (phase B)

    // ---- zero pads ----
    for (int i = tid; i < TBK * 64 * 5; i += 256) {       // xsb cols 22..31
        int row = i / 5, q = i - row * 5;
        reinterpret_cast<uint*>(&xsb[row * 32 + 22])[q] = 0u;
    }
    for (int i = tid; i < (TBK * VV * 32) / 2; i += 256)  // all of psb
        reinterpret_cast<uint*>(psb)[i] = 0u;

    // ---- P0: stage x (352B-contiguous per c) -> bf16 LDS ----
    {
        const float* xsrc = x + ((size_t)n * CIN * TT + t0) * VV;
        for (int i4 = tid; i4 < CIN * 22; i4 += 256) {
            int c = i4 / 22, q = i4 - c * 22;
            float4 v4 = *reinterpret_cast<const float4*>(xsrc + (size_t)c * (TT * VV) + q * 4);
            #pragma unroll
            for (int j = 0; j < 4; ++j) {
                int e  = q * 4 + j;
                int tt = e / 22, v = e - tt * 22;
                float val = (j == 0) ? v4.x : (j == 1) ? v4.y : (j == 2) ? v4.z : v4.w;
                xsb[(tt * 64 + c) * 32 + v] = f2bf(val);
            }
        }
    }
    __syncthreads();

    // ---- conv1: P1 B-frags from xsb ----
    for (int it = tid; it < 1024; it += 256) {
        int kb = it >> 9;
        int t  = (it >> 7) & 3;
        int nt = (it >> 6) & 1;
        int ln = it & 63;
        int v  = nt * 16 + (ln & 15);
        int c0 = kb * 32 + (ln >> 4) * 8;
        ushort tmp[8];
        #pragma unroll
        for (int j = 0; j < 8; ++j) tmp[j] = xsb[(t * 64 + c0 + j) * 32 + v];
        *reinterpret_cast<uint4*>(&xbf[(size_t)it * 8]) = *reinterpret_cast<const uint4*>(tmp);
    }
    __syncthreads();

    // ---- P1 MFMA: A1 = Wa@X+ba, A2 = Wb@X+bb for all 4 t's ----
    f32x4 acc_a[TBK][2], acc_b[TBK][2];
    {
        const int m0 = wave * 16;
        float bav[4], bbv[4];
        #pragma unroll
        for (int r = 0; r < 4; ++r) { bav[r] = ba[m0 + hi * 4 + r]; bbv[r] = bb[m0 + hi * 4 + r]; }
        #pragma unroll
        for (int t = 0; t < TBK; ++t)
            #pragma unroll
            for (int nt = 0; nt < 2; ++nt)
                #pragma unroll
                for (int r = 0; r < 4; ++r) { acc_a[t][nt][r] = bav[r]; acc_b[t][nt][r] = bbv[r]; }
        #pragma unroll
        for (int kb = 0; kb < 2; ++kb) {
            bf16x8 awa = *reinterpret_cast<const bf16x8*>(&WaB[(size_t)(m0 + lo) * CIN + kb * 32 + hi * 8]);
            bf16x8 awb = *reinterpret_cast<const bf16x8*>(&WbB[(size_t)(m0 + lo) * CIN + kb * 32 + hi * 8]);
            #pragma unroll
            for (int t = 0; t < TBK; ++t) {
                #pragma unroll
                for (int nt = 0; nt < 2; ++nt) {
                    bf16x8 bf = *reinterpret_cast<const bf16x8*>(
                        &xbf[(((size_t)(kb * 4 + t) * 2 + nt) * 64 + lane) * 8]);
                    acc_a[t][nt] = __builtin_amdgcn_mfma_f32_16x16x32_bf16(awa, bf, acc_a[t][nt], 0, 0, 0);
                    acc_b[t][nt] = __builtin_amdgcn_mfma_f32_16x16x32_bf16(awb, bf, acc_b[t][nt], 0, 0, 0);
                }
            }
        }
    }
    __syncthreads();   // xbf reads done; A1bf overlay

    // ---- store A1/A2 bf16 frags [t][u<22][i<64] ----
    {
        const int m0 = wave * 16;
        #pragma unroll
        for (int t = 0; t < TBK; ++t) {
            #pragma unroll
            for (int nt = 0; nt < 2; ++nt) {
                const int u = nt * 16 + lo;
                if (u < VV) {
                    uint2 va = {pk2(acc_a[t][nt][0], acc_a[t][nt][1]),
                                pk2(acc_a[t][nt][2], acc_a[t][nt][3])};
                    uint2 vb = {pk2(acc_b[t][nt][0], acc_b[t][nt][1]),
                                pk2(acc_b[t][nt][2], acc_b[t][nt][3])};
                    *reinterpret_cast<uint2*>(&A1bf[((size_t)t * VV + u) * 64 + m0 + hi * 4]) = va;
                    *reinterpret_cast<uint2*>(&A2bf[((size_t)t * VV + u) * 64 + m0 + hi * 4]) = vb;
                }
            }
        }
    }
    __syncthreads();

    // ---- P2 MFMA (wave = t): S in registers ----
    f32x4 s[2][2];
    {
        const int t = wave;
        bf16x8 zfrag;
        #pragma unroll
        for (int j = 0; j < 8; ++j) zfrag[j] = 0;
        #pragma unroll
        for (int mt = 0; mt < 2; ++mt)
            #pragma unroll
            for (int nt = 0; nt < 2; ++nt)
                #pragma unroll
                for (int r = 0; r < 4; ++r) s[mt][nt][r] = 0.f;
        #pragma unroll
        for (int kb = 0; kb < 2; ++kb) {
            bf16x8 a[2], b2[2];
            #pragma unroll
            for (int mt = 0; mt < 2; ++mt) {
                const int row = mt * 16 + lo;
                a[mt] = (row < VV) ? *reinterpret_cast<const bf16x8*>(
                            &A1bf[((size_t)t * VV + row) * 64 + kb * 32 + hi * 8]) : zfrag;
            }
            #pragma unroll
            for (int nt = 0; nt < 2; ++nt) {
                const int row = nt * 16 + lo;
                b2[nt] = (row < VV) ? *reinterpret_cast<const bf16x8*>(
                            &A2bf[((size_t)t * VV + row) * 64 + kb * 32 + hi * 8]) : zfrag;
            }
            #pragma unroll
            for (int mt = 0; mt < 2; ++mt)
                #pragma unroll
                for (int nt = 0; nt < 2; ++nt)
                    s[mt][nt] = __builtin_amdgcn_mfma_f32_16x16x32_bf16(a[mt], b2[nt], s[mt][nt], 0, 0, 0);
        }
    }
    __syncthreads();   // A1bf/A2bf reads done everywhere; z_lds may now overlay

    // ---- softmax (in-register) + P3 (psb) + P4 MFMA -> z_lds (bf16) ----
    {
        const int t = wave;
        bf16x8 zfrag;
        #pragma unroll
        for (int j = 0; j < 8; ++j) zfrag[j] = 0;

        float m[2] = {-1e30f, -1e30f};
        #pragma unroll
        for (int mt = 0; mt < 2; ++mt)
            #pragma unroll
            for (int nt = 0; nt < 2; ++nt)
                #pragma unroll
                for (int r = 0; r < 4; ++r) {
                    s[mt][nt][r] *= (1.0f / 64.0f);
                    const int u = mt * 16 + hi * 4 + r;
                    if (u < VV) m[nt] = fmaxf(m[nt], s[mt][nt][r]);
                }
        #pragma unroll
        for (int nt = 0; nt < 2; ++nt) {
            m[nt] = fmaxf(m[nt], __shfl_xor(m[nt], 16));
            m[nt] = fmaxf(m[nt], __shfl_xor(m[nt], 32));
        }
        float e[2][2][4];
        float sum[2] = {0.f, 0.f};
        #pragma unroll
        for (int mt = 0; mt < 2; ++mt)
            #pragma unroll
            for (int nt = 0; nt < 2; ++nt)
                #pragma unroll
                for (int r = 0; r < 4; ++r) {
                    const int u = mt * 16 + hi * 4 + r;
                    float ev = (u < VV) ? __expf(s[mt][nt][r] - m[nt]) : 0.f;
                    e[mt][nt][r] = ev;
                    sum[nt] += ev;
                }
        #pragma unroll
        for (int nt = 0; nt < 2; ++nt) {
            sum[nt] += __shfl_xor(sum[nt], 16);
            sum[nt] += __shfl_xor(sum[nt], 32);
        }

        // P3: P = A + 1e-6 + softmax -> psb bf16
        {
            const float* Ag = A + ((size_t)(n * TT + t0 + t) * VV) * VV;
            #pragma unroll
            for (int nt = 0; nt < 2; ++nt) {
                const int v = nt * 16 + lo;
                if (v < VV) {
                    const float inv = 1.0f / sum[nt];
                    #pragma unroll
                    for (int mt = 0; mt < 2; ++mt)
                        #pragma unroll
                        for (int r = 0; r < 4; ++r) {
                            const int u = mt * 16 + hi * 4 + r;
                            if (u < VV)
                                psb[((size_t)t * VV + u) * 32 + v] =
                                    f2bf(Ag[u * VV + v] + 1e-6f + e[mt][nt][r] * inv);
                        }
                }
            }
        }
        // P4 MFMA: z[c][tv] -> z_lds bf16 [c][96] (tv = t*22 + u)
        {
            bf16x8 bfr[2];
            #pragma unroll
            for (int nt = 0; nt < 2; ++nt) {
                const int u = nt * 16 + lo;
                bfr[nt] = (u < VV) ? *reinterpret_cast<const bf16x8*>(
                              &psb[((size_t)t * VV + u) * 32 + hi * 8]) : zfrag;
            }
            #pragma unroll
            for (int mt = 0; mt < 4; ++mt) {
                bf16x8 a = *reinterpret_cast<const bf16x8*>(
                    &xsb[((size_t)(t * 64 + mt * 16 + lo)) * 32 + hi * 8]);
                #pragma unroll
                for (int nt = 0; nt < 2; ++nt) {
                    f32x4 acc = {0.f, 0.f, 0.f, 0.f};
                    acc = __builtin_amdgcn_mfma_f32_16x16x32_bf16(a, bfr[nt], acc, 0, 0, 0);
                    const int u = nt * 16 + lo;
                    if (u < VV) {
                        #pragma unroll
                        for (int r = 0; r < 4; ++r) {
                            const int c = mt * 16 + hi * 4 + r;
                            z_lds[(size_t)c * 96 + t * VV + u] = f2bf(acc[r]);
                        }
                    }
                }
            }
        }
    }
    __syncthreads();   // z_lds complete; xsb reads done -> zbf may overlay

    // ---- conv: z_lds -> zbf B-frags ----
    for (int it = tid; it < 768; it += 256) {
        const int kb  = it / 384;
        const int rem = it - kb * 384;
        const int nt  = rem >> 6;
        const int ln  = rem & 63;
        const int tv  = nt * 16 + (ln & 15);
        const int c0  = kb * 32 + (ln >> 4) * 8;
        ushort tmp[8];
        if (tv < ZROW) {
            #pragma unroll
            for (int j = 0; j < 8; ++j) tmp[j] = z_lds[(size_t)(c0 + j) * 96 + tv];
        } else {
            #pragma unroll
            for (int j = 0; j < 8; ++j) tmp[j] = 0;
        }
        *reinterpret_cast<uint4*>(&zbf[(size_t)it * 8]) = *reinterpret_cast<const uint4*>(tmp);
    }
    __syncthreads();

    // ---- Phase B: out = relu(Wd @ z + bd) (k2's MFMA block) ----
    {
        const int o0 = wave * 64;
        f32x4 acc[4][6];
        #pragma unroll
        for (int mt = 0; mt < 4; ++mt) {
            #pragma unroll
            for (int r = 0; r < 4; ++r) {
                const float b = bd[o0 + mt * 16 + hi * 4 + r];
                #pragma unroll
                for (int nt = 0; nt < 6; ++nt) acc[mt][nt][r] = b;
            }
        }
        #pragma unroll
        for (int kb = 0; kb < 2; ++kb) {
            bf16x8 bfr[6];
            #pragma unroll
            for (int nt = 0; nt < 6; ++nt)
                bfr[nt] = *reinterpret_cast<const bf16x8*>(&zbf[((kb * 6 + nt) * 64 + lane) * 8]);
            #pragma unroll
            for (int mt = 0; mt < 4; ++mt) {
                bf16x8 aw = *reinterpret_cast<const bf16x8*>(
                    &WdB[(size_t)(o0 + mt * 16 + lo) * CIN + kb * 32 + hi * 8]);
                #pragma unroll
                for (int nt = 0; nt < 6; ++nt)
                    acc[mt][nt] = __builtin_amdgcn_mfma_f32_16x16x32_bf16(aw, bfr[nt], acc[mt][nt], 0, 0, 0);
            }
        }
        #pragma unroll
        for (int mt = 0; mt < 4; ++mt) {
            #pragma unroll
            for (int nt = 0; nt < 6; ++nt) {
                const int col = nt * 16 + lo;
                if (col < ZROW) {
                    #pragma unroll
                    for (int r = 0; r < 4; ++r) {
                        const int o = o0 + mt * 16 + hi * 4 + r;
                        out[((size_t)(n * COUT + o)) * (TT * VV) + (size_t)tq * ZROW + col]
                            = fmaxf(acc[mt][nt][r], 0.f);
                    }
                }
            }
        }
    }
}

// ===================== Fallback: verified R1 monolithic kernel =====================
__global__ __launch_bounds__(256, 4) void agcn_fused(
    const float* __restrict__ x, const float* __restrict__ A,
    const float* __restrict__ Wa, const float* __restrict__ ba,
    const float* __restrict__ Wb, const float* __restrict__ bb,
    const float* __restrict__ Wd, const float* __restrict__ bd,
    float* __restrict__ out)
{
    const int t   = blockIdx.x;
    const int n   = blockIdx.y;
    const int tid = threadIdx.x;
    __shared__ float smem[7424];
    float* xs   = smem;
    float* A1s  = smem + 1536;
    float* A2s  = smem + 3072;
    float* Ssf  = smem + 4608;
    float* Psf  = smem + 5136;
    float* outs = smem;
    float* zs   = smem + 5888;

    for (int f = tid; f < CIN * VV; f += 256) {
        int c = f / VV, v = f - c * VV;
        xs[c * PAD + v] = x[(((size_t)n * CIN + c) * TT + t) * VV + v];
    }
    {
        const float* Ag = A + (((size_t)n * TT + t) * VV) * VV;
        for (int f = tid; f < VV * VV; f += 256) {
            int u = f / VV, v = f - u * VV;
            Psf[u * PAD + v] = Ag[f] + 1e-6f;
        }
    }
    __syncthreads();
    {
        const int r  = tid & 63;
        const int q  = tid >> 6;
        const int us = (q * VV) >> 2;
        const int ue = ((q + 1) * VV) >> 2;
        const float* War = Wa + r * CIN;
        const float* Wbr = Wb + r * CIN;
        float acc1[6], acc2[6];
        const float b1 = ba[r], b2 = bb[r];
        #pragma unroll
        for (int u = 0; u < 6; ++u) { acc1[u] = b1; acc2[u] = b2; }
        for (int c = 0; c < CIN; c += 4) {
            float4 wa4 = *reinterpret_cast<const float4*>(War + c);
            float4 wb4 = *reinterpret_cast<const float4*>(Wbr + c);
            #pragma unroll
            for (int u = 0; u < 6; ++u) {
                float x0 = xs[(c + 0) * PAD + us + u];
                float x1 = xs[(c + 1) * PAD + us + u];
                float x2 = xs[(c + 2) * PAD + us + u];
                float x3 = xs[(c + 3) * PAD + us + u];
                acc1[u] += wa4.x * x0 + wa4.y * x1 + wa4.z * x2 + wa4.w * x3;
                acc2[u] += wb4.x * x0 + wb4.y * x1 + wb4.z * x2 + wb4.w * x3;
            }
        }
        #pragma unroll
        for (int u = 0; u < 6; ++u) {
            if (us + u < ue) {
                A1s[r * PAD + us + u] = acc1[u];
                A2s[r * PAD + us + u] = acc2[u];
            }
        }
    }
    __syncthreads();
    for (int f = tid; f < VV * VV; f += 256) {
        int u = f / VV, v = f - u * VV;
        float s = 0.f;
        for (int i = 0; i < CIN; ++i)
            s += A1s[i * PAD + u] * A2s[i * PAD + v];
        Ssf[u * PAD + v] = s * (1.0f / 64.0f);
    }
    __syncthreads();
    if (tid < VV) {
        const int v = tid;
        float m = -1e30f;
        #pragma unroll
        for (int u = 0; u < VV; ++u) m = fmaxf(m, Ssf[u * PAD + v]);
        float sum = 0.f;
        #pragma unroll
        for (int u = 0; u < VV; ++u) sum += __expf(Ssf[u * PAD + v] - m);
        const float inv = 1.0f / sum;
        #pragma unroll
        for (int u = 0; u < VV; ++u)
            Psf[u * PAD + v] += __expf(Ssf[u * PAD + v] - m) * inv;
    }
    __syncthreads();
    for (int f = tid; f < CIN * VV; f += 256) {
        int c = f / VV, u = f - c * VV;
        float s = 0.f;
        #pragma unroll
        for (int w = 0; w < VV; ++w)
            s += Psf[u * PAD + w] * xs[c * PAD + w];
        zs[c * PAD + u] = s;
    }
    __syncthreads();
    {
        const int o = tid;
        const float* Wr = Wd + o * CIN;
        float acc[VV];
        const float b = bd[o];
        #pragma unroll
        for (int u = 0; u < VV; ++u) acc[u] = b;
        for (int c = 0; c < CIN; c += 4) {
            float4 w4 = *reinterpret_cast<const float4*>(Wr + c);
            #pragma unroll
            for (int cc = 0; cc < 4; ++cc) {
                const float w = (cc == 0) ? w4.x : (cc == 1) ? w4.y : (cc == 2) ? w4.z : w4.w;
                const float* zr = zs + (c + cc) * PAD;
                #pragma unroll
                for (int uq = 0; uq < 5; ++uq) {
                    float4 zq = *reinterpret_cast<const float4*>(zr + uq * 4);
                    acc[uq * 4 + 0] += w * zq.x;
                    acc[uq * 4 + 1] += w * zq.y;
                    acc[uq * 4 + 2] += w * zq.z;
                    acc[uq * 4 + 3] += w * zq.w;
                }
                float2 zt = *reinterpret_cast<const float2*>(zr + 20);
                acc[20] += w * zt.x;
                acc[21] += w * zt.y;
            }
        }
        #pragma unroll
        for (int u = 0; u < VV; ++u)
            outs[o * OPAD + u] = fmaxf(acc[u], 0.f);
    }
    __syncthreads();
    {
        const size_t obase = (size_t)n * COUT * TT * VV + (size_t)t * VV;
        for (int f = tid; f < COUT * VV; f += 256) {
            int o = f / VV, u = f - o * VV;
            out[obase + (size_t)o * (TT * VV) + u] = outs[o * OPAD + u];
        }
    }
}

extern "C" void kernel_launch(void* const* d_in, const int* in_sizes, int n_in,
                              void* d_out, int out_size, void* d_ws, size_t ws_size,
                              hipStream_t stream) {
    const float* x  = (const float*)d_in[0];
    const float* A  = (const float*)d_in[1];
    const float* Wa = (const float*)d_in[2];
    const float* ba = (const float*)d_in[3];
    const float* Wb = (const float*)d_in[4];
    const float* bb = (const float*)d_in[5];
    const float* Wd = (const float*)d_in[6];
    const float* bd = (const float*)d_in[7];
    float* outp     = (float*)d_out;

    const size_t wab_bytes = (size_t)CIN * CIN * sizeof(ushort);    // 8 KB each
    const size_t wdb_bytes = (size_t)COUT * CIN * sizeof(ushort);   // 32 KB

    if (ws_size >= 2 * wab_bytes + wdb_bytes) {
        ushort* wab = (ushort*)d_ws;
        ushort* wbb = (ushort*)((char*)d_ws + wab_bytes);
        ushort* wdb = (ushort*)((char*)d_ws + 2 * wab_bytes);
        const int prep_items = 2 * CIN * CIN + COUT * CIN;   // 24576
        w_to_bf16<<<(prep_items + 255) / 256, 256, 0, stream>>>(Wa, Wb, Wd, wab, wbb, wdb);
        dim3 g(NTB, NB);
        agcn_fused_mfma<<<g, 256, 0, stream>>>(x, A, wab, ba, wbb, bb, wdb, bd, outp);
    } else {
        dim3 grid(TT, NB);
        agcn_fused<<<grid, 256, 0, stream>>>(x, A, Wa, ba, Wb, bb, Wd, bd, outp);
    }
}